// Round 2
// baseline (290.871 us; speedup 1.0000x reference)
//
#include <hip/hip_runtime.h>
#include <hip/hip_bf16.h>
#include <math.h>

#define N_PANO 50000
#define N_FP   10000
#define N_UNI  60000   // unified dst id-space: pano [0,50000), fp mapped to 50000+d
#define HID    128
#define OUT_C  64
#define E_PP   800000
#define E_PF   50000
#define E_UNI  850000
#define NBKT   235     // cdiv(N_UNI, 256) coarse buckets
#define EPB    16384   // edges per tile in count/scatter (big tiles: short prefix chain)
#define NT_CNT 52      // cdiv(E_UNI, EPB)
#define NT_GEMM 391    // cdiv(N_PANO, 128)

typedef unsigned short ushort_t;
typedef unsigned int uint_t;
typedef __attribute__((ext_vector_type(8))) short short8;
typedef __attribute__((ext_vector_type(4))) float f32x4;

static inline int cdiv(int a, int b) { return (a + b - 1) / b; }

__device__ inline ushort_t f2bf(float x) {
    __hip_bfloat16 h = __float2bfloat16(x);   // RNE
    return *reinterpret_cast<ushort_t*>(&h);
}
__device__ inline float bfu2f(ushort_t u) {
    return __uint_as_float(((uint_t)u) << 16);
}
__device__ inline float bflo(uint_t u) { return __uint_as_float((u & 0xffffu) << 16); }
__device__ inline float bfhi(uint_t u) { return __uint_as_float(u & 0xffff0000u); }
__device__ inline f32x4 mfma16(short8 a, short8 b, f32x4 c) {
    return __builtin_amdgcn_mfma_f32_16x16x32_bf16(a, b, c, 0, 0, 0);
}

// ---------------- CSR stage 1: per-tile partial counts + weight prep (merged) ----------------
// pcnt layout: tile-major pcnt[tile*NBKT + bucket] (coalesced write here, coalesced
// batch-read in scatter_body's prefix).
__global__ __launch_bounds__(256) void csr_count_prep(
        const int* __restrict__ pp_dst, const int* __restrict__ pf_dst,
        int* __restrict__ pcnt,
        const float* __restrict__ Ws0, const float* __restrict__ Lw0,
        const float* __restrict__ Ws1, const float* __restrict__ Lw1,
        const float* __restrict__ Wts,
        const float* __restrict__ Wd0, const float* __restrict__ ad0,
        const float* __restrict__ Wd1, const float* __restrict__ ad1,
        const float* __restrict__ Wtd, const float* __restrict__ atd,
        ushort_t* s0, ushort_t* l0, ushort_t* s1, ushort_t* l1, ushort_t* ts,
        float* wed0, float* wed1, float* wedt) {
    __shared__ int hist[NBKT];
    const int tile = blockIdx.x, tid = threadIdx.x;
    if (tile < NT_CNT) {
        for (int t = tid; t < NBKT; t += 256) hist[t] = 0;
        __syncthreads();
        const int e0 = tile * EPB;
        #pragma unroll 8
        for (int u = 0; u < 64; ++u) {
            int e = e0 + u * 256 + tid;
            int d = -1;
            if (e < E_PP) d = pp_dst[e];
            else if (e < E_UNI) d = N_PANO + pf_dst[e - E_PP];
            if (d >= 0) atomicAdd(&hist[d >> 8], 1);
        }
        __syncthreads();
        for (int t = tid; t < NBKT; t += 256) pcnt[tile * NBKT + t] = hist[t];
    } else if (tile < NT_CNT + 288) {
        int i = (tile - NT_CNT) * 256 + tid;
        const float* W; ushort_t* oh;
        int d, NIc, Cc;
        if (i < 65536) {
            int m = i >> 14; d = i & 16383;
            W = (m == 0) ? Ws0 : (m == 1) ? Lw0 : (m == 2) ? Ws1 : Lw1;
            oh = (m == 0) ? s0 : (m == 1) ? l0 : (m == 2) ? s1 : l1;
            NIc = 8; Cc = 128;
        } else if (i < 73728) {
            d = i - 65536; W = Wts; oh = ts;
            NIc = 4; Cc = 64;
        } else return;
        int j = d & 7, l = (d >> 3) & 63;
        int kcl = (d >> 9) & 1;
        int ni = (d >> 10) & (NIc - 1);
        int p = d >> (10 + (NIc == 8 ? 3 : 2));
        int kc = p * 2 + kcl;
        int n = ni * 16 + (l & 15);
        int k = kc * 32 + (l >> 4) * 8 + j;
        oh[d] = f2bf(W[k * Cc + n]);
    } else {
        int r = (tile - NT_CNT - 288) * 4 + (tid >> 6);
        int lane = tid & 63;
        const float* W; const float* a; float* o; int rr, C;
        if (r < 128)      { W = Wd0; a = ad0; o = wed0; rr = r;       C = 128; }
        else if (r < 256) { W = Wd1; a = ad1; o = wed1; rr = r - 128; C = 128; }
        else if (r < 320) { W = Wtd; a = atd; o = wedt; rr = r - 256; C = 64;  }
        else return;
        float s = 0.f;
        for (int j = lane; j < C; j += 64) s += W[rr * C + j] * a[j];
        #pragma unroll
        for (int off = 32; off; off >>= 1) s += __shfl_down(s, off, 64);
        if (lane == 0) o[rr] = s;
    }
}

// ---------------- GEMM body (bf16 MFMA, LDS-staged fragment-order weights) ----------------
template <int CN, bool DUAL, bool FP32IN>
__device__ void gemm_body(int tile, char* smem,
                          const float* __restrict__ Xf, const ushort_t* __restrict__ Xh,
                          const ushort_t* __restrict__ W1, const ushort_t* __restrict__ W2,
                          ushort_t* __restrict__ Y1, ushort_t* __restrict__ Y2,
                          const float* __restrict__ avec, float* __restrict__ evec,
                          const float* __restrict__ wed, float* __restrict__ edv, int N) {
    constexpr int NI = CN / 16;
    constexpr int SLAB = NI * 1024;
    ushort_t* Bsh = (ushort_t*)smem;
    const int tid = threadIdx.x;
    const int w = tid >> 6, l = tid & 63;
    const int col = l & 15, q = l >> 4;
    const int row0 = tile * 128 + w * 32;
    f32x4 acc1[2][NI];
    f32x4 acc2[2][DUAL ? NI : 1];
    #pragma unroll
    for (int m = 0; m < 2; ++m)
        #pragma unroll
        for (int ni = 0; ni < NI; ++ni)
            #pragma unroll
            for (int r = 0; r < 4; ++r) acc1[m][ni][r] = 0.f;
    if (DUAL) {
        #pragma unroll
        for (int m = 0; m < 2; ++m)
            #pragma unroll
            for (int ni = 0; ni < NI; ++ni)
                #pragma unroll
                for (int r = 0; r < 4; ++r) acc2[m][ni][r] = 0.f;
    }
    float ped[2] = {0.f, 0.f};

    #pragma unroll
    for (int p = 0; p < 2; ++p) {
        if (p) __syncthreads();
        {
            const uint4* src1 = (const uint4*)W1 + p * (SLAB / 8);
            uint4* dst1 = (uint4*)&Bsh[0];
            #pragma unroll
            for (int f = tid; f < SLAB / 8; f += 256) dst1[f] = src1[f];
            if (DUAL) {
                const uint4* src2 = (const uint4*)W2 + p * (SLAB / 8);
                uint4* dst2 = (uint4*)&Bsh[SLAB];
                #pragma unroll
                for (int f = tid; f < SLAB / 8; f += 256) dst2[f] = src2[f];
            }
        }
        __syncthreads();
        #pragma unroll
        for (int kcl = 0; kcl < 2; ++kcl) {
            const int kc = p * 2 + kcl;
            const int k0 = kc * 32 + q * 8;
            short8 Ah[2];
            #pragma unroll
            for (int m = 0; m < 2; ++m) {
                const int arow = row0 + m * 16 + col;
                if (FP32IN) {
                    float xv[8];
                    if (arow < N) {
                        float4 a0 = *(const float4*)&Xf[(size_t)arow * 128 + k0];
                        float4 a1 = *(const float4*)&Xf[(size_t)arow * 128 + k0 + 4];
                        xv[0] = a0.x; xv[1] = a0.y; xv[2] = a0.z; xv[3] = a0.w;
                        xv[4] = a1.x; xv[5] = a1.y; xv[6] = a1.z; xv[7] = a1.w;
                    } else {
                        #pragma unroll
                        for (int j = 0; j < 8; ++j) xv[j] = 0.f;
                    }
                    #pragma unroll
                    for (int j = 0; j < 8; ++j) Ah[m][j] = (short)f2bf(xv[j]);
                    if (wed) {
                        float4 w0 = *(const float4*)&wed[k0];
                        float4 w1 = *(const float4*)&wed[k0 + 4];
                        ped[m] += xv[0] * w0.x + xv[1] * w0.y + xv[2] * w0.z + xv[3] * w0.w
                                + xv[4] * w1.x + xv[5] * w1.y + xv[6] * w1.z + xv[7] * w1.w;
                    }
                } else {
                    if (arow < N) {
                        Ah[m] = *(const short8*)&Xh[(size_t)arow * 128 + k0];
                    } else {
                        #pragma unroll
                        for (int j = 0; j < 8; ++j) Ah[m][j] = 0;
                    }
                    if (wed) {
                        float4 w0 = *(const float4*)&wed[k0];
                        float4 w1 = *(const float4*)&wed[k0 + 4];
                        float wv[8] = {w0.x, w0.y, w0.z, w0.w, w1.x, w1.y, w1.z, w1.w};
                        #pragma unroll
                        for (int j = 0; j < 8; ++j)
                            ped[m] += bfu2f((ushort_t)Ah[m][j]) * wv[j];
                    }
                }
            }
            #pragma unroll
            for (int ni = 0; ni < NI; ++ni) {
                const int lb = ((ni * 2 + kcl) * 64 + l) * 8;
                short8 B1 = *(const short8*)&Bsh[lb];
                #pragma unroll
                for (int m = 0; m < 2; ++m) acc1[m][ni] = mfma16(Ah[m], B1, acc1[m][ni]);
                if (DUAL) {
                    short8 B2 = *(const short8*)&Bsh[SLAB + lb];
                    #pragma unroll
                    for (int m = 0; m < 2; ++m) acc2[m][ni] = mfma16(Ah[m], B2, acc2[m][ni]);
                }
            }
        }
    }

    #pragma unroll
    for (int m = 0; m < 2; ++m) {
        #pragma unroll
        for (int ni = 0; ni < NI; ++ni) {
            #pragma unroll
            for (int r = 0; r < 4; ++r) {
                int mrow = row0 + m * 16 + q * 4 + r;
                if (mrow < N) {
                    Y1[(size_t)mrow * CN + ni * 16 + col] = f2bf(acc1[m][ni][r]);
                    if (DUAL) Y2[(size_t)mrow * CN + ni * 16 + col] = f2bf(acc2[m][ni][r]);
                }
            }
        }
    }
    float av[NI];
    #pragma unroll
    for (int ni = 0; ni < NI; ++ni) av[ni] = avec[ni * 16 + col];
    #pragma unroll
    for (int m = 0; m < 2; ++m) {
        #pragma unroll
        for (int r = 0; r < 4; ++r) {
            float pp = 0.f;
            #pragma unroll
            for (int ni = 0; ni < NI; ++ni) pp += acc1[m][ni][r] * av[ni];
            pp += __shfl_xor(pp, 1, 64);
            pp += __shfl_xor(pp, 2, 64);
            pp += __shfl_xor(pp, 4, 64);
            pp += __shfl_xor(pp, 8, 64);
            int mrow = row0 + m * 16 + q * 4 + r;
            if (col == 0 && mrow < N) evec[mrow] = pp;
        }
    }
    if (wed) {
        #pragma unroll
        for (int m = 0; m < 2; ++m) {
            ped[m] += __shfl_xor(ped[m], 16, 64);
            ped[m] += __shfl_xor(ped[m], 32, 64);
            int arow = row0 + m * 16 + col;
            if (q == 0 && arow < N) edv[arow] = ped[m];
        }
    }
}

// ---------------- scatter body: inline 2D prefix, batch-8 ILP on the pcnt chain ----------------
__device__ void scatter_body(int tile, char* smem,
                             const int* __restrict__ pp_src, const int* __restrict__ pp_dst,
                             const int* __restrict__ pf_src, const int* __restrict__ pf_dst,
                             const int* __restrict__ pcnt, int* __restrict__ bbase_out,
                             int2* __restrict__ tmp) {
    int* base2 = (int*)smem;            // [NBKT]
    int* cur   = base2 + NBKT;          // [NBKT]
    int* wsum  = cur + NBKT;            // [4]
    const int tid = threadIdx.x, lane = tid & 63, wv = tid >> 6;
    // thread tid owns bucket tid. Loads batched 8-wide so 8 are in flight per wait
    // (the old 1-load-per-trip loop was ~NT_CNT x 250cy of serial L2 latency).
    int rowsum = 0, myprefix = 0;
    if (tid < NBKT) {
        const int* pb = pcnt + tid;
        int t = 0;
        for (; t + 8 <= NT_CNT; t += 8) {
            int c0 = pb[(t + 0) * NBKT], c1 = pb[(t + 1) * NBKT];
            int c2 = pb[(t + 2) * NBKT], c3 = pb[(t + 3) * NBKT];
            int c4 = pb[(t + 4) * NBKT], c5 = pb[(t + 5) * NBKT];
            int c6 = pb[(t + 6) * NBKT], c7 = pb[(t + 7) * NBKT];
            rowsum += c0 + c1 + c2 + c3 + c4 + c5 + c6 + c7;
            myprefix += ((t + 0 < tile) ? c0 : 0) + ((t + 1 < tile) ? c1 : 0)
                      + ((t + 2 < tile) ? c2 : 0) + ((t + 3 < tile) ? c3 : 0)
                      + ((t + 4 < tile) ? c4 : 0) + ((t + 5 < tile) ? c5 : 0)
                      + ((t + 6 < tile) ? c6 : 0) + ((t + 7 < tile) ? c7 : 0);
        }
        for (; t < NT_CNT; ++t) {
            int c = pb[t * NBKT];
            rowsum += c;
            if (t < tile) myprefix += c;
        }
    }
    // exclusive scan of rowsum over buckets -> bucket base
    int v = (tid < NBKT) ? rowsum : 0;
    int incl = v;
    #pragma unroll
    for (int off = 1; off < 64; off <<= 1) {
        int t = __shfl_up(incl, off, 64);
        if (lane >= off) incl += t;
    }
    if (lane == 63) wsum[wv] = incl;
    __syncthreads();
    if (tid == 0) {
        int run = 0;
        #pragma unroll
        for (int w = 0; w < 4; ++w) { int t = wsum[w]; wsum[w] = run; run += t; }
    }
    __syncthreads();
    int bexcl = wsum[wv] + incl - v;
    if (tid < NBKT) {
        base2[tid] = bexcl + myprefix;
        cur[tid] = 0;
        if (tile == 0) bbase_out[tid] = bexcl;
    }
    if (tile == 0 && tid == 0) bbase_out[NBKT] = E_UNI;
    __syncthreads();
    const int e0 = tile * EPB;
    #pragma unroll 8
    for (int u = 0; u < 64; ++u) {
        int e = e0 + u * 256 + tid;
        int d = -1, s = 0;
        if (e < E_PP)       { d = pp_dst[e];                 s = pp_src[e]; }
        else if (e < E_UNI) { d = N_PANO + pf_dst[e - E_PP]; s = pf_src[e - E_PP]; }
        if (d >= 0) {
            int b = d >> 8;
            int p = base2[b] + atomicAdd(&cur[b], 1);
            tmp[p] = make_int2(s, d);
        }
    }
}

// ---------------- merged launch: scatter (tiles 0..51) || layer-0 dual GEMM ----------------
__global__ __launch_bounds__(256, 2) void scatter_gemm0(
        const int* __restrict__ pp_src, const int* __restrict__ pp_dst,
        const int* __restrict__ pf_src, const int* __restrict__ pf_dst,
        const int* __restrict__ pcnt, int* __restrict__ bbase_out, int2* __restrict__ tmp,
        const float* __restrict__ x_pano,
        const ushort_t* __restrict__ s0, const ushort_t* __restrict__ l0,
        ushort_t* __restrict__ hsb, ushort_t* __restrict__ linb,
        const float* __restrict__ as0, float* __restrict__ es,
        const float* __restrict__ wed0, float* __restrict__ ed) {
    __shared__ __align__(16) char smem[32768];
    if (blockIdx.x < NT_CNT)
        scatter_body(blockIdx.x, smem, pp_src, pp_dst, pf_src, pf_dst, pcnt, bbase_out, tmp);
    else
        gemm_body<128, true, true>(blockIdx.x - NT_CNT, smem, x_pano, nullptr, s0, l0,
                                   hsb, linb, as0, es, wed0, ed, N_PANO);
}

// ---------------- standalone GEMM kernel (layers 1 and translate) ----------------
template <int CN, bool DUAL, bool FP32IN>
__global__ __launch_bounds__(256, 2) void gemm_mfma(const float* __restrict__ Xf,
                                                 const ushort_t* __restrict__ Xh,
                                                 const ushort_t* __restrict__ W1, const ushort_t* __restrict__ W2,
                                                 ushort_t* __restrict__ Y1, ushort_t* __restrict__ Y2,
                                                 const float* __restrict__ avec, float* __restrict__ evec,
                                                 const float* __restrict__ wed, float* __restrict__ edv,
                                                 int N) {
    __shared__ __align__(16) char smem[(DUAL ? 2 : 1) * (CN / 16) * 2048];
    gemm_body<CN, DUAL, FP32IN>(blockIdx.x, smem, Xf, Xh, W1, W2, Y1, Y2, avec, evec, wed, edv, N);
}

// ---------------- CSR stage 4: per-bucket counting sort in LDS -> P, col ----------------
__global__ __launch_bounds__(256) void csr_sort(const int2* __restrict__ tmp,
                                                const int* __restrict__ bbase,
                                                int* __restrict__ ptr, int* __restrict__ col) {
    __shared__ int hist[256];
    __shared__ int wsum[4];
    const int b = blockIdx.x, tid = threadIdx.x, lane = tid & 63, wv = tid >> 6;
    const int B0 = bbase[b], B1 = bbase[b + 1];
    hist[tid] = 0;
    __syncthreads();
    for (int e = B0 + tid; e < B1; e += 256) atomicAdd(&hist[tmp[e].y & 255], 1);
    __syncthreads();
    int v = hist[tid];
    int incl = v;
    #pragma unroll
    for (int off = 1; off < 64; off <<= 1) {
        int t = __shfl_up(incl, off, 64);
        if (lane >= off) incl += t;
    }
    if (lane == 63) wsum[wv] = incl;
    __syncthreads();
    if (tid == 0) {
        int run = 0;
        #pragma unroll
        for (int w = 0; w < 4; ++w) { int t = wsum[w]; wsum[w] = run; run += t; }
    }
    __syncthreads();
    int excl = wsum[wv] + incl - v;
    int dg = b * 256 + tid;
    if (dg < N_UNI) ptr[dg] = B0 + excl;
    if (b == NBKT - 1 && tid == 0) ptr[N_UNI] = E_UNI;
    hist[tid] = excl;
    __syncthreads();
    for (int e = B0 + tid; e < B1; e += 256) {
        int2 ed2 = tmp[e];
        int p = B0 + atomicAdd(&hist[ed2.y & 255], 1);
        col[p] = ed2.x;
    }
}

// ---------------- GAT aggregate (pano): two nodes per wave, pair-packed ----------------
__global__ __launch_bounds__(256) void agg_pano7(const int* __restrict__ ptr, const int* __restrict__ col,
                                                 const float* __restrict__ es, const float* __restrict__ ed,
                                                 const ushort_t* __restrict__ hsb, const ushort_t* __restrict__ linb,
                                                 const float* __restrict__ b, const float* __restrict__ Lb,
                                                 uint_t* __restrict__ hh, int N) {
    int lane = threadIdx.x & 63, wid = threadIdx.x >> 6;
    int nodeA = blockIdx.x * 8 + wid * 2;
    if (nodeA >= N) return;
    int nodeB = nodeA + 1;
    bool hasB = nodeB < N;
    int begA = ptr[nodeA], endA = ptr[nodeA + 1];
    int endB = hasB ? ptr[nodeB + 1] : endA;
    int begB = endA;   // contiguous CSR
    float ednA = ed[nodeA];
    float ednB = hasB ? ed[nodeB] : 0.f;
    const int half = lane >> 5, hl = lane & 31;
    float aA0 = 0.f, aA1 = 0.f, aA2 = 0.f, aA3 = 0.f, dA = 0.f;
    float aB0 = 0.f, aB1 = 0.f, aB2 = 0.f, aB3 = 0.f, dB = 0.f;
    int baseA = begA, baseB = begB;
    while (baseA < endA || baseB < endB) {
        int mA = endA - baseA; mA = mA < 0 ? 0 : (mA > 64 ? 64 : mA);
        int mB = endB - baseB; mB = mB < 0 ? 0 : (mB > 64 ? 64 : mB);
        int sA = 0, sB = 0;
        float wA = 0.f, wB = 0.f;
        if (lane < mA) {
            sA = col[baseA + lane];
            float e = es[sA] + ednA;
            e = fmaxf(e, 0.2f * e);
            wA = __expf(e);
        }
        if (lane < mB) {
            sB = col[baseB + lane];
            float e = es[sB] + ednB;
            e = fmaxf(e, 0.2f * e);
            wB = __expf(e);
        }
        dA += wA; dB += wB;
        {
            int mp = (mA + 1) & ~1;
            int t = 0;
            for (; t + 8 <= mp; t += 8) {
                int i0 = t + half, i1 = t + 2 + half, i2 = t + 4 + half, i3 = t + 6 + half;
                int s0 = __shfl(sA, i0, 64), s1 = __shfl(sA, i1, 64);
                int s2 = __shfl(sA, i2, 64), s3 = __shfl(sA, i3, 64);
                float w0 = __shfl(wA, i0, 64), w1 = __shfl(wA, i1, 64);
                float w2 = __shfl(wA, i2, 64), w3 = __shfl(wA, i3, 64);
                uint2 h0 = *(const uint2*)&hsb[(size_t)s0 * 128 + hl * 4];
                uint2 h1 = *(const uint2*)&hsb[(size_t)s1 * 128 + hl * 4];
                uint2 h2 = *(const uint2*)&hsb[(size_t)s2 * 128 + hl * 4];
                uint2 h3 = *(const uint2*)&hsb[(size_t)s3 * 128 + hl * 4];
                aA0 += w0 * bflo(h0.x) + w1 * bflo(h1.x) + w2 * bflo(h2.x) + w3 * bflo(h3.x);
                aA1 += w0 * bfhi(h0.x) + w1 * bfhi(h1.x) + w2 * bfhi(h2.x) + w3 * bfhi(h3.x);
                aA2 += w0 * bflo(h0.y) + w1 * bflo(h1.y) + w2 * bflo(h2.y) + w3 * bflo(h3.y);
                aA3 += w0 * bfhi(h0.y) + w1 * bfhi(h1.y) + w2 * bfhi(h2.y) + w3 * bfhi(h3.y);
            }
            for (; t < mp; t += 2) {
                int i0 = t + half;
                int s0 = __shfl(sA, i0, 64);
                float w0 = __shfl(wA, i0, 64);
                uint2 h0 = *(const uint2*)&hsb[(size_t)s0 * 128 + hl * 4];
                aA0 += w0 * bflo(h0.x);
                aA1 += w0 * bfhi(h0.x);
                aA2 += w0 * bflo(h0.y);
                aA3 += w0 * bfhi(h0.y);
            }
        }
        {
            int mp = (mB + 1) & ~1;
            int t = 0;
            for (; t + 8 <= mp; t += 8) {
                int i0 = t + half, i1 = t + 2 + half, i2 = t + 4 + half, i3 = t + 6 + half;
                int s0 = __shfl(sB, i0, 64), s1 = __shfl(sB, i1, 64);
                int s2 = __shfl(sB, i2, 64), s3 = __shfl(sB, i3, 64);
                float w0 = __shfl(wB, i0, 64), w1 = __shfl(wB, i1, 64);
                float w2 = __shfl(wB, i2, 64), w3 = __shfl(wB, i3, 64);
                uint2 h0 = *(const uint2*)&hsb[(size_t)s0 * 128 + hl * 4];
                uint2 h1 = *(const uint2*)&hsb[(size_t)s1 * 128 + hl * 4];
                uint2 h2 = *(const uint2*)&hsb[(size_t)s2 * 128 + hl * 4];
                uint2 h3 = *(const uint2*)&hsb[(size_t)s3 * 128 + hl * 4];
                aB0 += w0 * bflo(h0.x) + w1 * bflo(h1.x) + w2 * bflo(h2.x) + w3 * bflo(h3.x);
                aB1 += w0 * bfhi(h0.x) + w1 * bfhi(h1.x) + w2 * bfhi(h2.x) + w3 * bfhi(h3.x);
                aB2 += w0 * bflo(h0.y) + w1 * bflo(h1.y) + w2 * bflo(h2.y) + w3 * bflo(h3.y);
                aB3 += w0 * bfhi(h0.y) + w1 * bfhi(h1.y) + w2 * bfhi(h2.y) + w3 * bfhi(h3.y);
            }
            for (; t < mp; t += 2) {
                int i0 = t + half;
                int s0 = __shfl(sB, i0, 64);
                float w0 = __shfl(wB, i0, 64);
                uint2 h0 = *(const uint2*)&hsb[(size_t)s0 * 128 + hl * 4];
                aB0 += w0 * bflo(h0.x);
                aB1 += w0 * bfhi(h0.x);
                aB2 += w0 * bflo(h0.y);
                aB3 += w0 * bfhi(h0.y);
            }
        }
        baseA += 64; baseB += 64;
    }
    aA0 += __shfl_xor(aA0, 32, 64); aA1 += __shfl_xor(aA1, 32, 64);
    aA2 += __shfl_xor(aA2, 32, 64); aA3 += __shfl_xor(aA3, 32, 64);
    aB0 += __shfl_xor(aB0, 32, 64); aB1 += __shfl_xor(aB1, 32, 64);
    aB2 += __shfl_xor(aB2, 32, 64); aB3 += __shfl_xor(aB3, 32, 64);
    #pragma unroll
    for (int off = 1; off < 64; off <<= 1) dA += __shfl_xor(dA, off, 64);
    #pragma unroll
    for (int off = 1; off < 64; off <<= 1) dB += __shfl_xor(dB, off, 64);
    float invA = (endA > begA) ? (1.f / dA) : 0.f;
    float invB = (endB > begB) ? (1.f / dB) : 0.f;
    int node = half ? nodeB : nodeA;
    if (half == 0 || hasB) {
        float v0 = half ? aB0 : aA0, v1 = half ? aB1 : aA1;
        float v2 = half ? aB2 : aA2, v3 = half ? aB3 : aA3;
        float inv = half ? invB : invA;
        uint2 lv = *(const uint2*)&linb[(size_t)node * 128 + hl * 4];
        float4 bb = *(const float4*)&b[hl * 4];
        float4 lb4 = *(const float4*)&Lb[hl * 4];
        float o0 = fmaxf(v0 * inv + bb.x + bflo(lv.x) + lb4.x, 0.f);
        float o1 = fmaxf(v1 * inv + bb.y + bfhi(lv.x) + lb4.y, 0.f);
        float o2 = fmaxf(v2 * inv + bb.z + bflo(lv.y) + lb4.z, 0.f);
        float o3 = fmaxf(v3 * inv + bb.w + bfhi(lv.y) + lb4.w, 0.f);
        uint2 ov;
        ov.x = (uint_t)f2bf(o0) | ((uint_t)f2bf(o1) << 16);
        ov.y = (uint_t)f2bf(o2) | ((uint_t)f2bf(o3) << 16);
        *(uint2*)&hh[(size_t)node * 64 + hl * 2] = ov;
    }
}

// ---------------- translate aggregate (C=64), fused ed matvec ----------------
__global__ __launch_bounds__(256) void agg_fp5(const int* __restrict__ ptr, const int* __restrict__ col,
                                               const float* __restrict__ es, const float* __restrict__ x_fp,
                                               const float* __restrict__ wedt,
                                               const ushort_t* __restrict__ hsb, const float* __restrict__ bt,
                                               float* __restrict__ out, int N) {
    int lane = threadIdx.x & 63, wid = threadIdx.x >> 6;
    int node = blockIdx.x * 4 + wid;
    if (node >= N) return;
    int beg = ptr[node], end = ptr[node + 1];
    float edn = x_fp[(size_t)node * 64 + lane] * wedt[lane];
    #pragma unroll
    for (int off = 1; off < 64; off <<= 1) edn += __shfl_xor(edn, off, 64);
    float acc = 0.f, denp = 0.f;
    for (int base = beg; base < end; base += 64) {
        int m = min(64, end - base);
        int s = 0;
        float wgt = 0.f;
        if (lane < m) {
            s = col[base + lane];
            float e = es[s] + edn;
            e = fmaxf(e, 0.2f * e);
            wgt = __expf(e);
        }
        denp += wgt;
        int u = 0;
        for (; u + 4 <= m; u += 4) {
            int s0 = __shfl(s, u, 64), s1 = __shfl(s, u + 1, 64);
            int s2 = __shfl(s, u + 2, 64), s3 = __shfl(s, u + 3, 64);
            float w0 = __shfl(wgt, u, 64), w1 = __shfl(wgt, u + 1, 64);
            float w2 = __shfl(wgt, u + 2, 64), w3 = __shfl(wgt, u + 3, 64);
            float h0 = bfu2f(hsb[(size_t)s0 * 64 + lane]);
            float h1 = bfu2f(hsb[(size_t)s1 * 64 + lane]);
            float h2 = bfu2f(hsb[(size_t)s2 * 64 + lane]);
            float h3 = bfu2f(hsb[(size_t)s3 * 64 + lane]);
            acc += w0 * h0 + w1 * h1 + w2 * h2 + w3 * h3;
        }
        for (; u < m; ++u) {
            int su = __shfl(s, u, 64);
            float wu = __shfl(wgt, u, 64);
            acc += wu * bfu2f(hsb[(size_t)su * 64 + lane]);
        }
    }
    float den = denp;
    #pragma unroll
    for (int off = 1; off < 64; off <<= 1) den += __shfl_xor(den, off, 64);
    float inv = (end > beg) ? (1.f / den) : 0.f;
    out[(size_t)node * 64 + lane] = acc * inv + bt[lane];
}

extern "C" void kernel_launch(void* const* d_in, const int* in_sizes, int n_in,
                              void* d_out, int out_size, void* d_ws, size_t ws_size,
                              hipStream_t stream) {
    const float* x_pano = (const float*)d_in[0];
    const float* x_fp   = (const float*)d_in[1];
    const float* Ws0 = (const float*)d_in[2];
    const float* Wd0 = (const float*)d_in[3];
    const float* as0 = (const float*)d_in[4];
    const float* ad0 = (const float*)d_in[5];
    const float* b0  = (const float*)d_in[6];
    const float* Lw0 = (const float*)d_in[7];
    const float* Lb0 = (const float*)d_in[8];
    const float* Ws1 = (const float*)d_in[9];
    const float* Wd1 = (const float*)d_in[10];
    const float* as1 = (const float*)d_in[11];
    const float* ad1 = (const float*)d_in[12];
    const float* b1  = (const float*)d_in[13];
    const float* Lw1 = (const float*)d_in[14];
    const float* Lb1 = (const float*)d_in[15];
    const float* Wts = (const float*)d_in[16];
    const float* Wtd = (const float*)d_in[17];
    const float* ats = (const float*)d_in[18];
    const float* atd = (const float*)d_in[19];
    const float* bt  = (const float*)d_in[20];
    const int* pp_src = (const int*)d_in[21];
    const int* pp_dst = (const int*)d_in[21] + E_PP;
    const int* pf_src = (const int*)d_in[22];
    const int* pf_dst = (const int*)d_in[23];
    float* out = (float*)d_out;

    char* wsp = (char*)d_ws;
    size_t off = 0;
    auto alloc = [&](size_t bytes) -> char* {
        char* p = wsp + off;
        off += (bytes + 255) & ~(size_t)255;
        return p;
    };
    ushort_t* hsb  = (ushort_t*)alloc(sizeof(ushort_t) * N_PANO * HID);
    ushort_t* linb = (ushort_t*)alloc(sizeof(ushort_t) * N_PANO * HID);
    uint_t* hh     = (uint_t*)alloc(sizeof(uint_t) * N_PANO * 64);
    ushort_t* hstb = (ushort_t*)alloc(sizeof(ushort_t) * N_PANO * OUT_C);
    int2* tmp_e    = (int2*)alloc(sizeof(int2) * E_UNI);
    float* es   = (float*)alloc(sizeof(float) * N_PANO);
    float* ed   = (float*)alloc(sizeof(float) * N_PANO);
    float* wed0 = (float*)alloc(sizeof(float) * HID);
    float* wed1 = (float*)alloc(sizeof(float) * HID);
    float* wedt = (float*)alloc(sizeof(float) * OUT_C);
    ushort_t* s0 = (ushort_t*)alloc(sizeof(ushort_t) * 128 * 128);
    ushort_t* l0 = (ushort_t*)alloc(sizeof(ushort_t) * 128 * 128);
    ushort_t* s1 = (ushort_t*)alloc(sizeof(ushort_t) * 128 * 128);
    ushort_t* l1 = (ushort_t*)alloc(sizeof(ushort_t) * 128 * 128);
    ushort_t* ts = (ushort_t*)alloc(sizeof(ushort_t) * 64 * 128);
    int* pcnt  = (int*)alloc(sizeof(int) * NBKT * NT_CNT);
    int* bbase = (int*)alloc(sizeof(int) * (NBKT + 1));
    int* P     = (int*)alloc(sizeof(int) * (N_UNI + 1));
    int* col_u = (int*)alloc(sizeof(int) * E_UNI);

    // L1: per-tile bucket counts + weight fragment-permute + wed matvecs
    csr_count_prep<<<NT_CNT + 288 + 80, 256, 0, stream>>>(
        pp_dst, pf_dst, pcnt, Ws0, Lw0, Ws1, Lw1, Wts,
        Wd0, ad0, Wd1, ad1, Wtd, atd, s0, l0, s1, l1, ts, wed0, wed1, wedt);

    // L2: coarse scatter (inline 2D prefix) || layer-0 dual GEMM
    scatter_gemm0<<<NT_CNT + NT_GEMM, 256, 0, stream>>>(
        pp_src, pp_dst, pf_src, pf_dst, pcnt, bbase, tmp_e,
        x_pano, s0, l0, hsb, linb, as0, es, wed0, ed);

    // L3: per-bucket counting sort -> P, col
    csr_sort<<<NBKT, 256, 0, stream>>>(tmp_e, bbase, P, col_u);

    // L4: layer-0 aggregate
    agg_pano7<<<cdiv(N_PANO, 8), 256, 0, stream>>>(P, col_u, es, ed, hsb, linb, b0, Lb0, hh, N_PANO);

    // L5: layer-1 dual GEMM (bf16 input = hh)
    gemm_mfma<128, true, false><<<NT_GEMM, 256, 0, stream>>>(
        nullptr, (const ushort_t*)hh, s1, l1, hsb, linb, as1, es, wed1, ed, N_PANO);

    // L6: layer-1 aggregate
    agg_pano7<<<cdiv(N_PANO, 8), 256, 0, stream>>>(P, col_u, es, ed, hsb, linb, b1, Lb1, hh, N_PANO);

    // L7: translate GEMM (C=64)
    gemm_mfma<64, false, false><<<NT_GEMM, 256, 0, stream>>>(
        nullptr, (const ushort_t*)hh, ts, nullptr, hstb, nullptr, ats, es, nullptr, nullptr, N_PANO);

    // L8: translate aggregate (pf ptr = P+50000, absolute into col_u)
    agg_fp5<<<cdiv(N_FP, 4), 256, 0, stream>>>(P + N_PANO, col_u, es, x_fp, wedt, hstb, bt, out, N_FP);
}

// Round 4
// 268.446 us; speedup vs baseline: 1.0835x; 1.0835x over previous
//
#include <hip/hip_runtime.h>
#include <hip/hip_bf16.h>
#include <math.h>

#define N_PANO 50000
#define N_FP   10000
#define N_UNI  60000   // unified dst id-space: pano [0,50000), fp mapped to 50000+d
#define HID    128
#define OUT_C  64
#define E_PP   800000
#define E_PF   50000
#define E_UNI  850000
#define NBKT   235     // cdiv(N_UNI, 256) coarse buckets
#define EPB    4096    // edges per tile in count/scatter (measured-best)
#define NT_CNT 208     // cdiv(E_UNI, EPB)
#define NT_GEMM 391    // cdiv(N_PANO, 128)

typedef unsigned short ushort_t;
typedef unsigned int uint_t;
typedef __attribute__((ext_vector_type(8))) short short8;
typedef __attribute__((ext_vector_type(4))) float f32x4;

static inline int cdiv(int a, int b) { return (a + b - 1) / b; }

__device__ inline ushort_t f2bf(float x) {
    __hip_bfloat16 h = __float2bfloat16(x);   // RNE
    return *reinterpret_cast<ushort_t*>(&h);
}
__device__ inline float bfu2f(ushort_t u) {
    return __uint_as_float(((uint_t)u) << 16);
}
__device__ inline float bflo(uint_t u) { return __uint_as_float((u & 0xffffu) << 16); }
__device__ inline float bfhi(uint_t u) { return __uint_as_float(u & 0xffff0000u); }
__device__ inline f32x4 mfma16(short8 a, short8 b, f32x4 c) {
    return __builtin_amdgcn_mfma_f32_16x16x32_bf16(a, b, c, 0, 0, 0);
}

// ---------------- CSR stage 1: per-tile partial counts + weight prep (merged) ----------------
// pcnt layout: tile-major pcnt[tile*NBKT + bucket] (coalesced write here, coalesced
// batch-read in scatter_body's prefix).
__global__ __launch_bounds__(256) void csr_count_prep(
        const int* __restrict__ pp_dst, const int* __restrict__ pf_dst,
        int* __restrict__ pcnt,
        const float* __restrict__ Ws0, const float* __restrict__ Lw0,
        const float* __restrict__ Ws1, const float* __restrict__ Lw1,
        const float* __restrict__ Wts,
        const float* __restrict__ Wd0, const float* __restrict__ ad0,
        const float* __restrict__ Wd1, const float* __restrict__ ad1,
        const float* __restrict__ Wtd, const float* __restrict__ atd,
        ushort_t* s0, ushort_t* l0, ushort_t* s1, ushort_t* l1, ushort_t* ts,
        float* wed0, float* wed1, float* wedt) {
    __shared__ int hist[NBKT];
    const int tile = blockIdx.x, tid = threadIdx.x;
    if (tile < NT_CNT) {
        for (int t = tid; t < NBKT; t += 256) hist[t] = 0;
        __syncthreads();
        const int e0 = tile * EPB;
        #pragma unroll
        for (int u = 0; u < 16; ++u) {
            int e = e0 + u * 256 + tid;
            int d = -1;
            if (e < E_PP) d = pp_dst[e];
            else if (e < E_UNI) d = N_PANO + pf_dst[e - E_PP];
            if (d >= 0) atomicAdd(&hist[d >> 8], 1);
        }
        __syncthreads();
        for (int t = tid; t < NBKT; t += 256) pcnt[tile * NBKT + t] = hist[t];
    } else if (tile < NT_CNT + 288) {
        int i = (tile - NT_CNT) * 256 + tid;
        const float* W; ushort_t* oh;
        int d, NIc, Cc;
        if (i < 65536) {
            int m = i >> 14; d = i & 16383;
            W = (m == 0) ? Ws0 : (m == 1) ? Lw0 : (m == 2) ? Ws1 : Lw1;
            oh = (m == 0) ? s0 : (m == 1) ? l0 : (m == 2) ? s1 : l1;
            NIc = 8; Cc = 128;
        } else if (i < 73728) {
            d = i - 65536; W = Wts; oh = ts;
            NIc = 4; Cc = 64;
        } else return;
        int j = d & 7, l = (d >> 3) & 63;
        int kcl = (d >> 9) & 1;
        int ni = (d >> 10) & (NIc - 1);
        int p = d >> (10 + (NIc == 8 ? 3 : 2));
        int kc = p * 2 + kcl;
        int n = ni * 16 + (l & 15);
        int k = kc * 32 + (l >> 4) * 8 + j;
        oh[d] = f2bf(W[k * Cc + n]);
    } else {
        int r = (tile - NT_CNT - 288) * 4 + (tid >> 6);
        int lane = tid & 63;
        const float* W; const float* a; float* o; int rr, C;
        if (r < 128)      { W = Wd0; a = ad0; o = wed0; rr = r;       C = 128; }
        else if (r < 256) { W = Wd1; a = ad1; o = wed1; rr = r - 128; C = 128; }
        else if (r < 320) { W = Wtd; a = atd; o = wedt; rr = r - 256; C = 64;  }
        else return;
        float s = 0.f;
        for (int j = lane; j < C; j += 64) s += W[rr * C + j] * a[j];
        #pragma unroll
        for (int off = 32; off; off >>= 1) s += __shfl_down(s, off, 64);
        if (lane == 0) o[rr] = s;
    }
}

// ---------------- GEMM body (bf16 MFMA, barrier-free: B fragments loaded straight ----------------
// from global in fragment order; weights are L2-resident and identical across blocks,
// so the LDS staging + 2 barriers per phase were pure overhead on a grid-limited kernel).
template <int CN, bool DUAL, bool FP32IN>
__device__ void gemm_body(int tile,
                          const float* __restrict__ Xf, const ushort_t* __restrict__ Xh,
                          const ushort_t* __restrict__ W1, const ushort_t* __restrict__ W2,
                          ushort_t* __restrict__ Y1, ushort_t* __restrict__ Y2,
                          const float* __restrict__ avec, float* __restrict__ evec,
                          const float* __restrict__ wed, float* __restrict__ edv, int N) {
    constexpr int NI = CN / 16;
    constexpr int SLAB = NI * 1024;
    const int tid = threadIdx.x;
    const int w = tid >> 6, l = tid & 63;
    const int col = l & 15, q = l >> 4;
    const int row0 = tile * 128 + w * 32;
    f32x4 acc1[2][NI];
    f32x4 acc2[2][DUAL ? NI : 1];
    #pragma unroll
    for (int m = 0; m < 2; ++m)
        #pragma unroll
        for (int ni = 0; ni < NI; ++ni)
            #pragma unroll
            for (int r = 0; r < 4; ++r) acc1[m][ni][r] = 0.f;
    if (DUAL) {
        #pragma unroll
        for (int m = 0; m < 2; ++m)
            #pragma unroll
            for (int ni = 0; ni < NI; ++ni)
                #pragma unroll
                for (int r = 0; r < 4; ++r) acc2[m][ni][r] = 0.f;
    }
    float ped[2] = {0.f, 0.f};

    #pragma unroll
    for (int p = 0; p < 2; ++p) {
        #pragma unroll
        for (int kcl = 0; kcl < 2; ++kcl) {
            const int kc = p * 2 + kcl;
            const int k0 = kc * 32 + q * 8;
            short8 Ah[2];
            #pragma unroll
            for (int m = 0; m < 2; ++m) {
                const int arow = row0 + m * 16 + col;
                if (FP32IN) {
                    float xv[8];
                    if (arow < N) {
                        float4 a0 = *(const float4*)&Xf[(size_t)arow * 128 + k0];
                        float4 a1 = *(const float4*)&Xf[(size_t)arow * 128 + k0 + 4];
                        xv[0] = a0.x; xv[1] = a0.y; xv[2] = a0.z; xv[3] = a0.w;
                        xv[4] = a1.x; xv[5] = a1.y; xv[6] = a1.z; xv[7] = a1.w;
                    } else {
                        #pragma unroll
                        for (int j = 0; j < 8; ++j) xv[j] = 0.f;
                    }
                    #pragma unroll
                    for (int j = 0; j < 8; ++j) Ah[m][j] = (short)f2bf(xv[j]);
                    if (wed) {
                        float4 w0 = *(const float4*)&wed[k0];
                        float4 w1 = *(const float4*)&wed[k0 + 4];
                        ped[m] += xv[0] * w0.x + xv[1] * w0.y + xv[2] * w0.z + xv[3] * w0.w
                                + xv[4] * w1.x + xv[5] * w1.y + xv[6] * w1.z + xv[7] * w1.w;
                    }
                } else {
                    if (arow < N) {
                        Ah[m] = *(const short8*)&Xh[(size_t)arow * 128 + k0];
                    } else {
                        #pragma unroll
                        for (int j = 0; j < 8; ++j) Ah[m][j] = 0;
                    }
                    if (wed) {
                        float4 w0 = *(const float4*)&wed[k0];
                        float4 w1 = *(const float4*)&wed[k0 + 4];
                        float wv[8] = {w0.x, w0.y, w0.z, w0.w, w1.x, w1.y, w1.z, w1.w};
                        #pragma unroll
                        for (int j = 0; j < 8; ++j)
                            ped[m] += bfu2f((ushort_t)Ah[m][j]) * wv[j];
                    }
                }
            }
            #pragma unroll
            for (int ni = 0; ni < NI; ++ni) {
                const int gb = p * SLAB + ((ni * 2 + kcl) * 64 + l) * 8;
                short8 B1 = *(const short8*)&W1[gb];
                #pragma unroll
                for (int m = 0; m < 2; ++m) acc1[m][ni] = mfma16(Ah[m], B1, acc1[m][ni]);
                if (DUAL) {
                    short8 B2 = *(const short8*)&W2[gb];
                    #pragma unroll
                    for (int m = 0; m < 2; ++m) acc2[m][ni] = mfma16(Ah[m], B2, acc2[m][ni]);
                }
            }
        }
    }

    #pragma unroll
    for (int m = 0; m < 2; ++m) {
        #pragma unroll
        for (int ni = 0; ni < NI; ++ni) {
            #pragma unroll
            for (int r = 0; r < 4; ++r) {
                int mrow = row0 + m * 16 + q * 4 + r;
                if (mrow < N) {
                    Y1[(size_t)mrow * CN + ni * 16 + col] = f2bf(acc1[m][ni][r]);
                    if (DUAL) Y2[(size_t)mrow * CN + ni * 16 + col] = f2bf(acc2[m][ni][r]);
                }
            }
        }
    }
    float av[NI];
    #pragma unroll
    for (int ni = 0; ni < NI; ++ni) av[ni] = avec[ni * 16 + col];
    #pragma unroll
    for (int m = 0; m < 2; ++m) {
        #pragma unroll
        for (int r = 0; r < 4; ++r) {
            float pp = 0.f;
            #pragma unroll
            for (int ni = 0; ni < NI; ++ni) pp += acc1[m][ni][r] * av[ni];
            pp += __shfl_xor(pp, 1, 64);
            pp += __shfl_xor(pp, 2, 64);
            pp += __shfl_xor(pp, 4, 64);
            pp += __shfl_xor(pp, 8, 64);
            int mrow = row0 + m * 16 + q * 4 + r;
            if (col == 0 && mrow < N) evec[mrow] = pp;
        }
    }
    if (wed) {
        #pragma unroll
        for (int m = 0; m < 2; ++m) {
            ped[m] += __shfl_xor(ped[m], 16, 64);
            ped[m] += __shfl_xor(ped[m], 32, 64);
            int arow = row0 + m * 16 + col;
            if (q == 0 && arow < N) edv[arow] = ped[m];
        }
    }
}

// ---------------- scatter body: inline 2D prefix, batch-8 ILP on the pcnt chain ----------------
__device__ void scatter_body(int tile, char* smem,
                             const int* __restrict__ pp_src, const int* __restrict__ pp_dst,
                             const int* __restrict__ pf_src, const int* __restrict__ pf_dst,
                             const int* __restrict__ pcnt, int* __restrict__ bbase_out,
                             int2* __restrict__ tmp) {
    int* base2 = (int*)smem;            // [NBKT]
    int* cur   = base2 + NBKT;          // [NBKT]
    int* wsum  = cur + NBKT;            // [4]
    const int tid = threadIdx.x, lane = tid & 63, wv = tid >> 6;
    // thread tid owns bucket tid. Loads batched 8-wide so 8 are in flight per wait.
    int rowsum = 0, myprefix = 0;
    if (tid < NBKT) {
        const int* pb = pcnt + tid;
        int t = 0;
        for (; t + 8 <= NT_CNT; t += 8) {
            int c0 = pb[(t + 0) * NBKT], c1 = pb[(t + 1) * NBKT];
            int c2 = pb[(t + 2) * NBKT], c3 = pb[(t + 3) * NBKT];
            int c4 = pb[(t + 4) * NBKT], c5 = pb[(t + 5) * NBKT];
            int c6 = pb[(t + 6) * NBKT], c7 = pb[(t + 7) * NBKT];
            rowsum += c0 + c1 + c2 + c3 + c4 + c5 + c6 + c7;
            myprefix += ((t + 0 < tile) ? c0 : 0) + ((t + 1 < tile) ? c1 : 0)
                      + ((t + 2 < tile) ? c2 : 0) + ((t + 3 < tile) ? c3 : 0)
                      + ((t + 4 < tile) ? c4 : 0) + ((t + 5 < tile) ? c5 : 0)
                      + ((t + 6 < tile) ? c6 : 0) + ((t + 7 < tile) ? c7 : 0);
        }
        for (; t < NT_CNT; ++t) {
            int c = pb[t * NBKT];
            rowsum += c;
            if (t < tile) myprefix += c;
        }
    }
    // exclusive scan of rowsum over buckets -> bucket base
    int v = (tid < NBKT) ? rowsum : 0;
    int incl = v;
    #pragma unroll
    for (int off = 1; off < 64; off <<= 1) {
        int t = __shfl_up(incl, off, 64);
        if (lane >= off) incl += t;
    }
    if (lane == 63) wsum[wv] = incl;
    __syncthreads();
    if (tid == 0) {
        int run = 0;
        #pragma unroll
        for (int w = 0; w < 4; ++w) { int t = wsum[w]; wsum[w] = run; run += t; }
    }
    __syncthreads();
    int bexcl = wsum[wv] + incl - v;
    if (tid < NBKT) {
        base2[tid] = bexcl + myprefix;
        cur[tid] = 0;
        if (tile == 0) bbase_out[tid] = bexcl;
    }
    if (tile == 0 && tid == 0) bbase_out[NBKT] = E_UNI;
    __syncthreads();
    const int e0 = tile * EPB;
    #pragma unroll
    for (int u = 0; u < 16; ++u) {
        int e = e0 + u * 256 + tid;
        int d = -1, s = 0;
        if (e < E_PP)       { d = pp_dst[e];                 s = pp_src[e]; }
        else if (e < E_UNI) { d = N_PANO + pf_dst[e - E_PP]; s = pf_src[e - E_PP]; }
        if (d >= 0) {
            int b = d >> 8;
            int p = base2[b] + atomicAdd(&cur[b], 1);
            tmp[p] = make_int2(s, d);
        }
    }
}

// ---------------- merged launch: scatter (tiles 0..207) || layer-0 dual GEMM ----------------
__global__ __launch_bounds__(256, 2) void scatter_gemm0(
        const int* __restrict__ pp_src, const int* __restrict__ pp_dst,
        const int* __restrict__ pf_src, const int* __restrict__ pf_dst,
        const int* __restrict__ pcnt, int* __restrict__ bbase_out, int2* __restrict__ tmp,
        const float* __restrict__ x_pano,
        const ushort_t* __restrict__ s0, const ushort_t* __restrict__ l0,
        ushort_t* __restrict__ hsb, ushort_t* __restrict__ linb,
        const float* __restrict__ as0, float* __restrict__ es,
        const float* __restrict__ wed0, float* __restrict__ ed) {
    __shared__ __align__(16) char smem[(2 * NBKT + 4) * 4];
    if (blockIdx.x < NT_CNT)
        scatter_body(blockIdx.x, smem, pp_src, pp_dst, pf_src, pf_dst, pcnt, bbase_out, tmp);
    else
        gemm_body<128, true, true>(blockIdx.x - NT_CNT, x_pano, nullptr, s0, l0,
                                   hsb, linb, as0, es, wed0, ed, N_PANO);
}

// ---------------- standalone GEMM kernel (layers 1 and translate), barrier-free ----------------
template <int CN, bool DUAL, bool FP32IN>
__global__ __launch_bounds__(256, 2) void gemm_mfma(const float* __restrict__ Xf,
                                                 const ushort_t* __restrict__ Xh,
                                                 const ushort_t* __restrict__ W1, const ushort_t* __restrict__ W2,
                                                 ushort_t* __restrict__ Y1, ushort_t* __restrict__ Y2,
                                                 const float* __restrict__ avec, float* __restrict__ evec,
                                                 const float* __restrict__ wed, float* __restrict__ edv,
                                                 int N) {
    gemm_body<CN, DUAL, FP32IN>(blockIdx.x, Xf, Xh, W1, W2, Y1, Y2, avec, evec, wed, edv, N);
}

// ---------------- CSR stage 4: per-bucket counting sort in LDS -> P, col ----------------
__global__ __launch_bounds__(256) void csr_sort(const int2* __restrict__ tmp,
                                                const int* __restrict__ bbase,
                                                int* __restrict__ ptr, int* __restrict__ col) {
    __shared__ int hist[256];
    __shared__ int wsum[4];
    const int b = blockIdx.x, tid = threadIdx.x, lane = tid & 63, wv = tid >> 6;
    const int B0 = bbase[b], B1 = bbase[b + 1];
    hist[tid] = 0;
    __syncthreads();
    for (int e = B0 + tid; e < B1; e += 256) atomicAdd(&hist[tmp[e].y & 255], 1);
    __syncthreads();
    int v = hist[tid];
    int incl = v;
    #pragma unroll
    for (int off = 1; off < 64; off <<= 1) {
        int t = __shfl_up(incl, off, 64);
        if (lane >= off) incl += t;
    }
    if (lane == 63) wsum[wv] = incl;
    __syncthreads();
    if (tid == 0) {
        int run = 0;
        #pragma unroll
        for (int w = 0; w < 4; ++w) { int t = wsum[w]; wsum[w] = run; run += t; }
    }
    __syncthreads();
    int excl = wsum[wv] + incl - v;
    int dg = b * 256 + tid;
    if (dg < N_UNI) ptr[dg] = B0 + excl;
    if (b == NBKT - 1 && tid == 0) ptr[N_UNI] = E_UNI;
    hist[tid] = excl;
    __syncthreads();
    for (int e = B0 + tid; e < B1; e += 256) {
        int2 ed2 = tmp[e];
        int p = B0 + atomicAdd(&hist[ed2.y & 255], 1);
        col[p] = ed2.x;
    }
}

// ---------------- GAT aggregate (pano): two nodes per wave, pair-packed ----------------
__global__ __launch_bounds__(256) void agg_pano7(const int* __restrict__ ptr, const int* __restrict__ col,
                                                 const float* __restrict__ es, const float* __restrict__ ed,
                                                 const ushort_t* __restrict__ hsb, const ushort_t* __restrict__ linb,
                                                 const float* __restrict__ b, const float* __restrict__ Lb,
                                                 uint_t* __restrict__ hh, int N) {
    int lane = threadIdx.x & 63, wid = threadIdx.x >> 6;
    int nodeA = blockIdx.x * 8 + wid * 2;
    if (nodeA >= N) return;
    int nodeB = nodeA + 1;
    bool hasB = nodeB < N;
    int begA = ptr[nodeA], endA = ptr[nodeA + 1];
    int endB = hasB ? ptr[nodeB + 1] : endA;
    int begB = endA;   // contiguous CSR
    float ednA = ed[nodeA];
    float ednB = hasB ? ed[nodeB] : 0.f;
    const int half = lane >> 5, hl = lane & 31;
    float aA0 = 0.f, aA1 = 0.f, aA2 = 0.f, aA3 = 0.f, dA = 0.f;
    float aB0 = 0.f, aB1 = 0.f, aB2 = 0.f, aB3 = 0.f, dB = 0.f;
    int baseA = begA, baseB = begB;
    while (baseA < endA || baseB < endB) {
        int mA = endA - baseA; mA = mA < 0 ? 0 : (mA > 64 ? 64 : mA);
        int mB = endB - baseB; mB = mB < 0 ? 0 : (mB > 64 ? 64 : mB);
        int sA = 0, sB = 0;
        float wA = 0.f, wB = 0.f;
        if (lane < mA) {
            sA = col[baseA + lane];
            float e = es[sA] + ednA;
            e = fmaxf(e, 0.2f * e);
            wA = __expf(e);
        }
        if (lane < mB) {
            sB = col[baseB + lane];
            float e = es[sB] + ednB;
            e = fmaxf(e, 0.2f * e);
            wB = __expf(e);
        }
        dA += wA; dB += wB;
        {
            int mp = (mA + 1) & ~1;
            int t = 0;
            for (; t + 8 <= mp; t += 8) {
                int i0 = t + half, i1 = t + 2 + half, i2 = t + 4 + half, i3 = t + 6 + half;
                int s0 = __shfl(sA, i0, 64), s1 = __shfl(sA, i1, 64);
                int s2 = __shfl(sA, i2, 64), s3 = __shfl(sA, i3, 64);
                float w0 = __shfl(wA, i0, 64), w1 = __shfl(wA, i1, 64);
                float w2 = __shfl(wA, i2, 64), w3 = __shfl(wA, i3, 64);
                uint2 h0 = *(const uint2*)&hsb[(size_t)s0 * 128 + hl * 4];
                uint2 h1 = *(const uint2*)&hsb[(size_t)s1 * 128 + hl * 4];
                uint2 h2 = *(const uint2*)&hsb[(size_t)s2 * 128 + hl * 4];
                uint2 h3 = *(const uint2*)&hsb[(size_t)s3 * 128 + hl * 4];
                aA0 += w0 * bflo(h0.x) + w1 * bflo(h1.x) + w2 * bflo(h2.x) + w3 * bflo(h3.x);
                aA1 += w0 * bfhi(h0.x) + w1 * bfhi(h1.x) + w2 * bfhi(h2.x) + w3 * bfhi(h3.x);
                aA2 += w0 * bflo(h0.y) + w1 * bflo(h1.y) + w2 * bflo(h2.y) + w3 * bflo(h3.y);
                aA3 += w0 * bfhi(h0.y) + w1 * bfhi(h1.y) + w2 * bfhi(h2.y) + w3 * bfhi(h3.y);
            }
            for (; t < mp; t += 2) {
                int i0 = t + half;
                int s0 = __shfl(sA, i0, 64);
                float w0 = __shfl(wA, i0, 64);
                uint2 h0 = *(const uint2*)&hsb[(size_t)s0 * 128 + hl * 4];
                aA0 += w0 * bflo(h0.x);
                aA1 += w0 * bfhi(h0.x);
                aA2 += w0 * bflo(h0.y);
                aA3 += w0 * bfhi(h0.y);
            }
        }
        {
            int mp = (mB + 1) & ~1;
            int t = 0;
            for (; t + 8 <= mp; t += 8) {
                int i0 = t + half, i1 = t + 2 + half, i2 = t + 4 + half, i3 = t + 6 + half;
                int s0 = __shfl(sB, i0, 64), s1 = __shfl(sB, i1, 64);
                int s2 = __shfl(sB, i2, 64), s3 = __shfl(sB, i3, 64);
                float w0 = __shfl(wB, i0, 64), w1 = __shfl(wB, i1, 64);
                float w2 = __shfl(wB, i2, 64), w3 = __shfl(wB, i3, 64);
                uint2 h0 = *(const uint2*)&hsb[(size_t)s0 * 128 + hl * 4];
                uint2 h1 = *(const uint2*)&hsb[(size_t)s1 * 128 + hl * 4];
                uint2 h2 = *(const uint2*)&hsb[(size_t)s2 * 128 + hl * 4];
                uint2 h3 = *(const uint2*)&hsb[(size_t)s3 * 128 + hl * 4];
                aB0 += w0 * bflo(h0.x) + w1 * bflo(h1.x) + w2 * bflo(h2.x) + w3 * bflo(h3.x);
                aB1 += w0 * bfhi(h0.x) + w1 * bfhi(h1.x) + w2 * bfhi(h2.x) + w3 * bfhi(h3.x);
                aB2 += w0 * bflo(h0.y) + w1 * bflo(h1.y) + w2 * bflo(h2.y) + w3 * bflo(h3.y);
                aB3 += w0 * bfhi(h0.y) + w1 * bfhi(h1.y) + w2 * bfhi(h2.y) + w3 * bfhi(h3.y);
            }
            for (; t < mp; t += 2) {
                int i0 = t + half;
                int s0 = __shfl(sB, i0, 64);
                float w0 = __shfl(wB, i0, 64);
                uint2 h0 = *(const uint2*)&hsb[(size_t)s0 * 128 + hl * 4];
                aB0 += w0 * bflo(h0.x);
                aB1 += w0 * bfhi(h0.x);
                aB2 += w0 * bflo(h0.y);
                aB3 += w0 * bfhi(h0.y);
            }
        }
        baseA += 64; baseB += 64;
    }
    aA0 += __shfl_xor(aA0, 32, 64); aA1 += __shfl_xor(aA1, 32, 64);
    aA2 += __shfl_xor(aA2, 32, 64); aA3 += __shfl_xor(aA3, 32, 64);
    aB0 += __shfl_xor(aB0, 32, 64); aB1 += __shfl_xor(aB1, 32, 64);
    aB2 += __shfl_xor(aB2, 32, 64); aB3 += __shfl_xor(aB3, 32, 64);
    #pragma unroll
    for (int off = 1; off < 64; off <<= 1) dA += __shfl_xor(dA, off, 64);
    #pragma unroll
    for (int off = 1; off < 64; off <<= 1) dB += __shfl_xor(dB, off, 64);
    float invA = (endA > begA) ? (1.f / dA) : 0.f;
    float invB = (endB > begB) ? (1.f / dB) : 0.f;
    int node = half ? nodeB : nodeA;
    if (half == 0 || hasB) {
        float v0 = half ? aB0 : aA0, v1 = half ? aB1 : aA1;
        float v2 = half ? aB2 : aA2, v3 = half ? aB3 : aA3;
        float inv = half ? invB : invA;
        uint2 lv = *(const uint2*)&linb[(size_t)node * 128 + hl * 4];
        float4 bb = *(const float4*)&b[hl * 4];
        float4 lb4 = *(const float4*)&Lb[hl * 4];
        float o0 = fmaxf(v0 * inv + bb.x + bflo(lv.x) + lb4.x, 0.f);
        float o1 = fmaxf(v1 * inv + bb.y + bfhi(lv.x) + lb4.y, 0.f);
        float o2 = fmaxf(v2 * inv + bb.z + bflo(lv.y) + lb4.z, 0.f);
        float o3 = fmaxf(v3 * inv + bb.w + bfhi(lv.y) + lb4.w, 0.f);
        uint2 ov;
        ov.x = (uint_t)f2bf(o0) | ((uint_t)f2bf(o1) << 16);
        ov.y = (uint_t)f2bf(o2) | ((uint_t)f2bf(o3) << 16);
        *(uint2*)&hh[(size_t)node * 64 + hl * 2] = ov;
    }
}

// ---------------- translate aggregate (C=64), fused ed matvec ----------------
__global__ __launch_bounds__(256) void agg_fp5(const int* __restrict__ ptr, const int* __restrict__ col,
                                               const float* __restrict__ es, const float* __restrict__ x_fp,
                                               const float* __restrict__ wedt,
                                               const ushort_t* __restrict__ hsb, const float* __restrict__ bt,
                                               float* __restrict__ out, int N) {
    int lane = threadIdx.x & 63, wid = threadIdx.x >> 6;
    int node = blockIdx.x * 4 + wid;
    if (node >= N) return;
    int beg = ptr[node], end = ptr[node + 1];
    float edn = x_fp[(size_t)node * 64 + lane] * wedt[lane];
    #pragma unroll
    for (int off = 1; off < 64; off <<= 1) edn += __shfl_xor(edn, off, 64);
    float acc = 0.f, denp = 0.f;
    for (int base = beg; base < end; base += 64) {
        int m = min(64, end - base);
        int s = 0;
        float wgt = 0.f;
        if (lane < m) {
            s = col[base + lane];
            float e = es[s] + edn;
            e = fmaxf(e, 0.2f * e);
            wgt = __expf(e);
        }
        denp += wgt;
        int u = 0;
        for (; u + 4 <= m; u += 4) {
            int s0 = __shfl(s, u, 64), s1 = __shfl(s, u + 1, 64);
            int s2 = __shfl(s, u + 2, 64), s3 = __shfl(s, u + 3, 64);
            float w0 = __shfl(wgt, u, 64), w1 = __shfl(wgt, u + 1, 64);
            float w2 = __shfl(wgt, u + 2, 64), w3 = __shfl(wgt, u + 3, 64);
            float h0 = bfu2f(hsb[(size_t)s0 * 64 + lane]);
            float h1 = bfu2f(hsb[(size_t)s1 * 64 + lane]);
            float h2 = bfu2f(hsb[(size_t)s2 * 64 + lane]);
            float h3 = bfu2f(hsb[(size_t)s3 * 64 + lane]);
            acc += w0 * h0 + w1 * h1 + w2 * h2 + w3 * h3;
        }
        for (; u < m; ++u) {
            int su = __shfl(s, u, 64);
            float wu = __shfl(wgt, u, 64);
            acc += wu * bfu2f(hsb[(size_t)su * 64 + lane]);
        }
    }
    float den = denp;
    #pragma unroll
    for (int off = 1; off < 64; off <<= 1) den += __shfl_xor(den, off, 64);
    float inv = (end > beg) ? (1.f / den) : 0.f;
    out[(size_t)node * 64 + lane] = acc * inv + bt[lane];
}

extern "C" void kernel_launch(void* const* d_in, const int* in_sizes, int n_in,
                              void* d_out, int out_size, void* d_ws, size_t ws_size,
                              hipStream_t stream) {
    const float* x_pano = (const float*)d_in[0];
    const float* x_fp   = (const float*)d_in[1];
    const float* Ws0 = (const float*)d_in[2];
    const float* Wd0 = (const float*)d_in[3];
    const float* as0 = (const float*)d_in[4];
    const float* ad0 = (const float*)d_in[5];
    const float* b0  = (const float*)d_in[6];
    const float* Lw0 = (const float*)d_in[7];
    const float* Lb0 = (const float*)d_in[8];
    const float* Ws1 = (const float*)d_in[9];
    const float* Wd1 = (const float*)d_in[10];
    const float* as1 = (const float*)d_in[11];
    const float* ad1 = (const float*)d_in[12];
    const float* b1  = (const float*)d_in[13];
    const float* Lw1 = (const float*)d_in[14];
    const float* Lb1 = (const float*)d_in[15];
    const float* Wts = (const float*)d_in[16];
    const float* Wtd = (const float*)d_in[17];
    const float* ats = (const float*)d_in[18];
    const float* atd = (const float*)d_in[19];
    const float* bt  = (const float*)d_in[20];
    const int* pp_src = (const int*)d_in[21];
    const int* pp_dst = (const int*)d_in[21] + E_PP;
    const int* pf_src = (const int*)d_in[22];
    const int* pf_dst = (const int*)d_in[23];
    float* out = (float*)d_out;

    char* wsp = (char*)d_ws;
    size_t off = 0;
    auto alloc = [&](size_t bytes) -> char* {
        char* p = wsp + off;
        off += (bytes + 255) & ~(size_t)255;
        return p;
    };
    ushort_t* hsb  = (ushort_t*)alloc(sizeof(ushort_t) * N_PANO * HID);
    ushort_t* linb = (ushort_t*)alloc(sizeof(ushort_t) * N_PANO * HID);
    uint_t* hh     = (uint_t*)alloc(sizeof(uint_t) * N_PANO * 64);
    ushort_t* hstb = (ushort_t*)alloc(sizeof(ushort_t) * N_PANO * OUT_C);
    int2* tmp_e    = (int2*)alloc(sizeof(int2) * E_UNI);
    float* es   = (float*)alloc(sizeof(float) * N_PANO);
    float* ed   = (float*)alloc(sizeof(float) * N_PANO);
    float* wed0 = (float*)alloc(sizeof(float) * HID);
    float* wed1 = (float*)alloc(sizeof(float) * HID);
    float* wedt = (float*)alloc(sizeof(float) * OUT_C);
    ushort_t* s0 = (ushort_t*)alloc(sizeof(ushort_t) * 128 * 128);
    ushort_t* l0 = (ushort_t*)alloc(sizeof(ushort_t) * 128 * 128);
    ushort_t* s1 = (ushort_t*)alloc(sizeof(ushort_t) * 128 * 128);
    ushort_t* l1 = (ushort_t*)alloc(sizeof(ushort_t) * 128 * 128);
    ushort_t* ts = (ushort_t*)alloc(sizeof(ushort_t) * 64 * 128);
    int* pcnt  = (int*)alloc(sizeof(int) * NBKT * NT_CNT);
    int* bbase = (int*)alloc(sizeof(int) * (NBKT + 1));
    int* P     = (int*)alloc(sizeof(int) * (N_UNI + 1));
    int* col_u = (int*)alloc(sizeof(int) * E_UNI);

    // L1: per-tile bucket counts + weight fragment-permute + wed matvecs
    csr_count_prep<<<NT_CNT + 288 + 80, 256, 0, stream>>>(
        pp_dst, pf_dst, pcnt, Ws0, Lw0, Ws1, Lw1, Wts,
        Wd0, ad0, Wd1, ad1, Wtd, atd, s0, l0, s1, l1, ts, wed0, wed1, wedt);

    // L2: coarse scatter (inline 2D prefix) || layer-0 dual GEMM
    scatter_gemm0<<<NT_CNT + NT_GEMM, 256, 0, stream>>>(
        pp_src, pp_dst, pf_src, pf_dst, pcnt, bbase, tmp_e,
        x_pano, s0, l0, hsb, linb, as0, es, wed0, ed);

    // L3: per-bucket counting sort -> P, col
    csr_sort<<<NBKT, 256, 0, stream>>>(tmp_e, bbase, P, col_u);

    // L4: layer-0 aggregate
    agg_pano7<<<cdiv(N_PANO, 8), 256, 0, stream>>>(P, col_u, es, ed, hsb, linb, b0, Lb0, hh, N_PANO);

    // L5: layer-1 dual GEMM (bf16 input = hh)
    gemm_mfma<128, true, false><<<NT_GEMM, 256, 0, stream>>>(
        nullptr, (const ushort_t*)hh, s1, l1, hsb, linb, as1, es, wed1, ed, N_PANO);

    // L6: layer-1 aggregate
    agg_pano7<<<cdiv(N_PANO, 8), 256, 0, stream>>>(P, col_u, es, ed, hsb, linb, b1, Lb1, hh, N_PANO);

    // L7: translate GEMM (C=64)
    gemm_mfma<64, false, false><<<NT_GEMM, 256, 0, stream>>>(
        nullptr, (const ushort_t*)hh, ts, nullptr, hstb, nullptr, ats, es, nullptr, nullptr, N_PANO);

    // L8: translate aggregate (pf ptr = P+50000, absolute into col_u)
    agg_fp5<<<cdiv(N_FP, 4), 256, 0, stream>>>(P + N_PANO, col_u, es, x_fp, wedt, hstb, bt, out, N_FP);
}

// Round 5
// 259.128 us; speedup vs baseline: 1.1225x; 1.0360x over previous
//
#include <hip/hip_runtime.h>
#include <hip/hip_bf16.h>
#include <math.h>

#define N_PANO 50000
#define N_FP   10000
#define N_UNI  60000   // unified dst id-space: pano [0,50000), fp mapped to 50000+d
#define HID    128
#define OUT_C  64
#define E_PP   800000
#define E_PF   50000
#define E_UNI  850000
#define NBKT   235     // cdiv(N_UNI, 256) coarse buckets
#define EPB    4096    // edges per tile in count/scatter (measured-best)
#define NT_CNT 208     // cdiv(E_UNI, EPB)
#define NT_GEMM 782    // cdiv(N_PANO, 64) -- 64-row tiles: 2x blocks for occupancy

typedef unsigned short ushort_t;
typedef unsigned int uint_t;
typedef __attribute__((ext_vector_type(8))) short short8;
typedef __attribute__((ext_vector_type(4))) float f32x4;

static inline int cdiv(int a, int b) { return (a + b - 1) / b; }

__device__ inline ushort_t f2bf(float x) {
    __hip_bfloat16 h = __float2bfloat16(x);   // RNE
    return *reinterpret_cast<ushort_t*>(&h);
}
__device__ inline float bfu2f(ushort_t u) {
    return __uint_as_float(((uint_t)u) << 16);
}
__device__ inline float bflo(uint_t u) { return __uint_as_float((u & 0xffffu) << 16); }
__device__ inline float bfhi(uint_t u) { return __uint_as_float(u & 0xffff0000u); }
__device__ inline f32x4 mfma16(short8 a, short8 b, f32x4 c) {
    return __builtin_amdgcn_mfma_f32_16x16x32_bf16(a, b, c, 0, 0, 0);
}

// ---------------- CSR stage 1: per-tile partial counts + weight prep (merged) ----------------
__global__ __launch_bounds__(256) void csr_count_prep(
        const int* __restrict__ pp_dst, const int* __restrict__ pf_dst,
        int* __restrict__ pcnt,
        const float* __restrict__ Ws0, const float* __restrict__ Lw0,
        const float* __restrict__ Ws1, const float* __restrict__ Lw1,
        const float* __restrict__ Wts,
        const float* __restrict__ Wd0, const float* __restrict__ ad0,
        const float* __restrict__ Wd1, const float* __restrict__ ad1,
        const float* __restrict__ Wtd, const float* __restrict__ atd,
        ushort_t* s0, ushort_t* l0, ushort_t* s1, ushort_t* l1, ushort_t* ts,
        float* wed0, float* wed1, float* wedt) {
    __shared__ int hist[NBKT];
    const int tile = blockIdx.x, tid = threadIdx.x;
    if (tile < NT_CNT) {
        for (int t = tid; t < NBKT; t += 256) hist[t] = 0;
        __syncthreads();
        const int e0 = tile * EPB;
        #pragma unroll
        for (int u = 0; u < 16; ++u) {
            int e = e0 + u * 256 + tid;
            int d = -1;
            if (e < E_PP) d = pp_dst[e];
            else if (e < E_UNI) d = N_PANO + pf_dst[e - E_PP];
            if (d >= 0) atomicAdd(&hist[d >> 8], 1);
        }
        __syncthreads();
        for (int t = tid; t < NBKT; t += 256) pcnt[tile * NBKT + t] = hist[t];
    } else if (tile < NT_CNT + 288) {
        int i = (tile - NT_CNT) * 256 + tid;
        const float* W; ushort_t* oh;
        int d, NIc, Cc;
        if (i < 65536) {
            int m = i >> 14; d = i & 16383;
            W = (m == 0) ? Ws0 : (m == 1) ? Lw0 : (m == 2) ? Ws1 : Lw1;
            oh = (m == 0) ? s0 : (m == 1) ? l0 : (m == 2) ? s1 : l1;
            NIc = 8; Cc = 128;
        } else if (i < 73728) {
            d = i - 65536; W = Wts; oh = ts;
            NIc = 4; Cc = 64;
        } else return;
        int j = d & 7, l = (d >> 3) & 63;
        int kcl = (d >> 9) & 1;
        int ni = (d >> 10) & (NIc - 1);
        int p = d >> (10 + (NIc == 8 ? 3 : 2));
        int kc = p * 2 + kcl;
        int n = ni * 16 + (l & 15);
        int k = kc * 32 + (l >> 4) * 8 + j;
        oh[d] = f2bf(W[k * Cc + n]);
    } else {
        int r = (tile - NT_CNT - 288) * 4 + (tid >> 6);
        int lane = tid & 63;
        const float* W; const float* a; float* o; int rr, C;
        if (r < 128)      { W = Wd0; a = ad0; o = wed0; rr = r;       C = 128; }
        else if (r < 256) { W = Wd1; a = ad1; o = wed1; rr = r - 128; C = 128; }
        else if (r < 320) { W = Wtd; a = atd; o = wedt; rr = r - 256; C = 64;  }
        else return;
        float s = 0.f;
        for (int j = lane; j < C; j += 64) s += W[rr * C + j] * a[j];
        #pragma unroll
        for (int off = 32; off; off >>= 1) s += __shfl_down(s, off, 64);
        if (lane == 0) o[rr] = s;
    }
}

// ---------------- GEMM body: 64-row tiles, one 16-row MFMA strip per wave, ----------------
// barrier-free (B fragments loaded straight from global in fragment order; L2-resident).
// Smaller tiles double the grid (782 blocks) and halve per-wave acc VGPRs -> higher
// occupancy on a latency-bound kernel (R4: Occ 12.7%, all pipes <7% busy).
template <int CN, bool DUAL, bool FP32IN>
__device__ void gemm_body(int tile,
                          const float* __restrict__ Xf, const ushort_t* __restrict__ Xh,
                          const ushort_t* __restrict__ W1, const ushort_t* __restrict__ W2,
                          ushort_t* __restrict__ Y1, ushort_t* __restrict__ Y2,
                          const float* __restrict__ avec, float* __restrict__ evec,
                          const float* __restrict__ wed, float* __restrict__ edv, int N) {
    constexpr int NI = CN / 16;
    constexpr int SLAB = NI * 1024;
    const int tid = threadIdx.x;
    const int w = tid >> 6, l = tid & 63;
    const int col = l & 15, q = l >> 4;
    const int row0 = tile * 64 + w * 16;
    f32x4 acc1[NI];
    f32x4 acc2[DUAL ? NI : 1];
    #pragma unroll
    for (int ni = 0; ni < NI; ++ni)
        #pragma unroll
        for (int r = 0; r < 4; ++r) acc1[ni][r] = 0.f;
    if (DUAL) {
        #pragma unroll
        for (int ni = 0; ni < NI; ++ni)
            #pragma unroll
            for (int r = 0; r < 4; ++r) acc2[ni][r] = 0.f;
    }
    float ped = 0.f;

    #pragma unroll
    for (int p = 0; p < 2; ++p) {
        #pragma unroll
        for (int kcl = 0; kcl < 2; ++kcl) {
            const int kc = p * 2 + kcl;
            const int k0 = kc * 32 + q * 8;
            short8 Ah;
            const int arow = row0 + col;
            if (FP32IN) {
                float xv[8];
                if (arow < N) {
                    float4 a0 = *(const float4*)&Xf[(size_t)arow * 128 + k0];
                    float4 a1 = *(const float4*)&Xf[(size_t)arow * 128 + k0 + 4];
                    xv[0] = a0.x; xv[1] = a0.y; xv[2] = a0.z; xv[3] = a0.w;
                    xv[4] = a1.x; xv[5] = a1.y; xv[6] = a1.z; xv[7] = a1.w;
                } else {
                    #pragma unroll
                    for (int j = 0; j < 8; ++j) xv[j] = 0.f;
                }
                #pragma unroll
                for (int j = 0; j < 8; ++j) Ah[j] = (short)f2bf(xv[j]);
                if (wed) {
                    float4 w0 = *(const float4*)&wed[k0];
                    float4 w1 = *(const float4*)&wed[k0 + 4];
                    ped += xv[0] * w0.x + xv[1] * w0.y + xv[2] * w0.z + xv[3] * w0.w
                         + xv[4] * w1.x + xv[5] * w1.y + xv[6] * w1.z + xv[7] * w1.w;
                }
            } else {
                if (arow < N) {
                    Ah = *(const short8*)&Xh[(size_t)arow * 128 + k0];
                } else {
                    #pragma unroll
                    for (int j = 0; j < 8; ++j) Ah[j] = 0;
                }
                if (wed) {
                    float4 w0 = *(const float4*)&wed[k0];
                    float4 w1 = *(const float4*)&wed[k0 + 4];
                    float wv[8] = {w0.x, w0.y, w0.z, w0.w, w1.x, w1.y, w1.z, w1.w};
                    #pragma unroll
                    for (int j = 0; j < 8; ++j)
                        ped += bfu2f((ushort_t)Ah[j]) * wv[j];
                }
            }
            #pragma unroll
            for (int ni = 0; ni < NI; ++ni) {
                const int gb = p * SLAB + ((ni * 2 + kcl) * 64 + l) * 8;
                short8 B1 = *(const short8*)&W1[gb];
                acc1[ni] = mfma16(Ah, B1, acc1[ni]);
                if (DUAL) {
                    short8 B2 = *(const short8*)&W2[gb];
                    acc2[ni] = mfma16(Ah, B2, acc2[ni]);
                }
            }
        }
    }

    #pragma unroll
    for (int ni = 0; ni < NI; ++ni) {
        #pragma unroll
        for (int r = 0; r < 4; ++r) {
            int mrow = row0 + q * 4 + r;
            if (mrow < N) {
                Y1[(size_t)mrow * CN + ni * 16 + col] = f2bf(acc1[ni][r]);
                if (DUAL) Y2[(size_t)mrow * CN + ni * 16 + col] = f2bf(acc2[ni][r]);
            }
        }
    }
    float av[NI];
    #pragma unroll
    for (int ni = 0; ni < NI; ++ni) av[ni] = avec[ni * 16 + col];
    #pragma unroll
    for (int r = 0; r < 4; ++r) {
        float pp = 0.f;
        #pragma unroll
        for (int ni = 0; ni < NI; ++ni) pp += acc1[ni][r] * av[ni];
        pp += __shfl_xor(pp, 1, 64);
        pp += __shfl_xor(pp, 2, 64);
        pp += __shfl_xor(pp, 4, 64);
        pp += __shfl_xor(pp, 8, 64);
        int mrow = row0 + q * 4 + r;
        if (col == 0 && mrow < N) evec[mrow] = pp;
    }
    if (wed) {
        ped += __shfl_xor(ped, 16, 64);
        ped += __shfl_xor(ped, 32, 64);
        const int arow = row0 + col;
        if (q == 0 && arow < N) edv[arow] = ped;
    }
}

// ---------------- scatter body: inline 2D prefix, batch-8 ILP on the pcnt chain ----------------
__device__ void scatter_body(int tile, char* smem,
                             const int* __restrict__ pp_src, const int* __restrict__ pp_dst,
                             const int* __restrict__ pf_src, const int* __restrict__ pf_dst,
                             const int* __restrict__ pcnt, int* __restrict__ bbase_out,
                             int2* __restrict__ tmp) {
    int* base2 = (int*)smem;            // [NBKT]
    int* cur   = base2 + NBKT;          // [NBKT]
    int* wsum  = cur + NBKT;            // [4]
    const int tid = threadIdx.x, lane = tid & 63, wv = tid >> 6;
    int rowsum = 0, myprefix = 0;
    if (tid < NBKT) {
        const int* pb = pcnt + tid;
        int t = 0;
        for (; t + 8 <= NT_CNT; t += 8) {
            int c0 = pb[(t + 0) * NBKT], c1 = pb[(t + 1) * NBKT];
            int c2 = pb[(t + 2) * NBKT], c3 = pb[(t + 3) * NBKT];
            int c4 = pb[(t + 4) * NBKT], c5 = pb[(t + 5) * NBKT];
            int c6 = pb[(t + 6) * NBKT], c7 = pb[(t + 7) * NBKT];
            rowsum += c0 + c1 + c2 + c3 + c4 + c5 + c6 + c7;
            myprefix += ((t + 0 < tile) ? c0 : 0) + ((t + 1 < tile) ? c1 : 0)
                      + ((t + 2 < tile) ? c2 : 0) + ((t + 3 < tile) ? c3 : 0)
                      + ((t + 4 < tile) ? c4 : 0) + ((t + 5 < tile) ? c5 : 0)
                      + ((t + 6 < tile) ? c6 : 0) + ((t + 7 < tile) ? c7 : 0);
        }
        for (; t < NT_CNT; ++t) {
            int c = pb[t * NBKT];
            rowsum += c;
            if (t < tile) myprefix += c;
        }
    }
    // exclusive scan of rowsum over buckets -> bucket base
    int v = (tid < NBKT) ? rowsum : 0;
    int incl = v;
    #pragma unroll
    for (int off = 1; off < 64; off <<= 1) {
        int t = __shfl_up(incl, off, 64);
        if (lane >= off) incl += t;
    }
    if (lane == 63) wsum[wv] = incl;
    __syncthreads();
    if (tid == 0) {
        int run = 0;
        #pragma unroll
        for (int w = 0; w < 4; ++w) { int t = wsum[w]; wsum[w] = run; run += t; }
    }
    __syncthreads();
    int bexcl = wsum[wv] + incl - v;
    if (tid < NBKT) {
        base2[tid] = bexcl + myprefix;
        cur[tid] = 0;
        if (tile == 0) bbase_out[tid] = bexcl;
    }
    if (tile == 0 && tid == 0) bbase_out[NBKT] = E_UNI;
    __syncthreads();
    const int e0 = tile * EPB;
    #pragma unroll
    for (int u = 0; u < 16; ++u) {
        int e = e0 + u * 256 + tid;
        int d = -1, s = 0;
        if (e < E_PP)       { d = pp_dst[e];                 s = pp_src[e]; }
        else if (e < E_UNI) { d = N_PANO + pf_dst[e - E_PP]; s = pf_src[e - E_PP]; }
        if (d >= 0) {
            int b = d >> 8;
            int p = base2[b] + atomicAdd(&cur[b], 1);
            tmp[p] = make_int2(s, d);
        }
    }
}

// ---------------- merged launch: scatter (tiles 0..207) || layer-0 dual GEMM ----------------
__global__ __launch_bounds__(256, 2) void scatter_gemm0(
        const int* __restrict__ pp_src, const int* __restrict__ pp_dst,
        const int* __restrict__ pf_src, const int* __restrict__ pf_dst,
        const int* __restrict__ pcnt, int* __restrict__ bbase_out, int2* __restrict__ tmp,
        const float* __restrict__ x_pano,
        const ushort_t* __restrict__ s0, const ushort_t* __restrict__ l0,
        ushort_t* __restrict__ hsb, ushort_t* __restrict__ linb,
        const float* __restrict__ as0, float* __restrict__ es,
        const float* __restrict__ wed0, float* __restrict__ ed) {
    __shared__ __align__(16) char smem[(2 * NBKT + 4) * 4];
    if (blockIdx.x < NT_CNT)
        scatter_body(blockIdx.x, smem, pp_src, pp_dst, pf_src, pf_dst, pcnt, bbase_out, tmp);
    else
        gemm_body<128, true, true>(blockIdx.x - NT_CNT, x_pano, nullptr, s0, l0,
                                   hsb, linb, as0, es, wed0, ed, N_PANO);
}

// ---------------- standalone GEMM kernel (layers 1 and translate), barrier-free ----------------
template <int CN, bool DUAL, bool FP32IN>
__global__ __launch_bounds__(256, 2) void gemm_mfma(const float* __restrict__ Xf,
                                                 const ushort_t* __restrict__ Xh,
                                                 const ushort_t* __restrict__ W1, const ushort_t* __restrict__ W2,
                                                 ushort_t* __restrict__ Y1, ushort_t* __restrict__ Y2,
                                                 const float* __restrict__ avec, float* __restrict__ evec,
                                                 const float* __restrict__ wed, float* __restrict__ edv,
                                                 int N) {
    gemm_body<CN, DUAL, FP32IN>(blockIdx.x, Xf, Xh, W1, W2, Y1, Y2, avec, evec, wed, edv, N);
}

// ---------------- CSR stage 4: per-bucket counting sort in LDS -> P, col ----------------
__global__ __launch_bounds__(256) void csr_sort(const int2* __restrict__ tmp,
                                                const int* __restrict__ bbase,
                                                int* __restrict__ ptr, int* __restrict__ col) {
    __shared__ int hist[256];
    __shared__ int wsum[4];
    const int b = blockIdx.x, tid = threadIdx.x, lane = tid & 63, wv = tid >> 6;
    const int B0 = bbase[b], B1 = bbase[b + 1];
    hist[tid] = 0;
    __syncthreads();
    for (int e = B0 + tid; e < B1; e += 256) atomicAdd(&hist[tmp[e].y & 255], 1);
    __syncthreads();
    int v = hist[tid];
    int incl = v;
    #pragma unroll
    for (int off = 1; off < 64; off <<= 1) {
        int t = __shfl_up(incl, off, 64);
        if (lane >= off) incl += t;
    }
    if (lane == 63) wsum[wv] = incl;
    __syncthreads();
    if (tid == 0) {
        int run = 0;
        #pragma unroll
        for (int w = 0; w < 4; ++w) { int t = wsum[w]; wsum[w] = run; run += t; }
    }
    __syncthreads();
    int excl = wsum[wv] + incl - v;
    int dg = b * 256 + tid;
    if (dg < N_UNI) ptr[dg] = B0 + excl;
    if (b == NBKT - 1 && tid == 0) ptr[N_UNI] = E_UNI;
    hist[tid] = excl;
    __syncthreads();
    for (int e = B0 + tid; e < B1; e += 256) {
        int2 ed2 = tmp[e];
        int p = B0 + atomicAdd(&hist[ed2.y & 255], 1);
        col[p] = ed2.x;
    }
}

// ---------------- GAT aggregate (pano): two nodes per wave, pair-packed ----------------
__global__ __launch_bounds__(256) void agg_pano7(const int* __restrict__ ptr, const int* __restrict__ col,
                                                 const float* __restrict__ es, const float* __restrict__ ed,
                                                 const ushort_t* __restrict__ hsb, const ushort_t* __restrict__ linb,
                                                 const float* __restrict__ b, const float* __restrict__ Lb,
                                                 uint_t* __restrict__ hh, int N) {
    int lane = threadIdx.x & 63, wid = threadIdx.x >> 6;
    int nodeA = blockIdx.x * 8 + wid * 2;
    if (nodeA >= N) return;
    int nodeB = nodeA + 1;
    bool hasB = nodeB < N;
    int begA = ptr[nodeA], endA = ptr[nodeA + 1];
    int endB = hasB ? ptr[nodeB + 1] : endA;
    int begB = endA;   // contiguous CSR
    float ednA = ed[nodeA];
    float ednB = hasB ? ed[nodeB] : 0.f;
    const int half = lane >> 5, hl = lane & 31;
    float aA0 = 0.f, aA1 = 0.f, aA2 = 0.f, aA3 = 0.f, dA = 0.f;
    float aB0 = 0.f, aB1 = 0.f, aB2 = 0.f, aB3 = 0.f, dB = 0.f;
    int baseA = begA, baseB = begB;
    while (baseA < endA || baseB < endB) {
        int mA = endA - baseA; mA = mA < 0 ? 0 : (mA > 64 ? 64 : mA);
        int mB = endB - baseB; mB = mB < 0 ? 0 : (mB > 64 ? 64 : mB);
        int sA = 0, sB = 0;
        float wA = 0.f, wB = 0.f;
        if (lane < mA) {
            sA = col[baseA + lane];
            float e = es[sA] + ednA;
            e = fmaxf(e, 0.2f * e);
            wA = __expf(e);
        }
        if (lane < mB) {
            sB = col[baseB + lane];
            float e = es[sB] + ednB;
            e = fmaxf(e, 0.2f * e);
            wB = __expf(e);
        }
        dA += wA; dB += wB;
        {
            int mp = (mA + 1) & ~1;
            int t = 0;
            for (; t + 8 <= mp; t += 8) {
                int i0 = t + half, i1 = t + 2 + half, i2 = t + 4 + half, i3 = t + 6 + half;
                int s0 = __shfl(sA, i0, 64), s1 = __shfl(sA, i1, 64);
                int s2 = __shfl(sA, i2, 64), s3 = __shfl(sA, i3, 64);
                float w0 = __shfl(wA, i0, 64), w1 = __shfl(wA, i1, 64);
                float w2 = __shfl(wA, i2, 64), w3 = __shfl(wA, i3, 64);
                uint2 h0 = *(const uint2*)&hsb[(size_t)s0 * 128 + hl * 4];
                uint2 h1 = *(const uint2*)&hsb[(size_t)s1 * 128 + hl * 4];
                uint2 h2 = *(const uint2*)&hsb[(size_t)s2 * 128 + hl * 4];
                uint2 h3 = *(const uint2*)&hsb[(size_t)s3 * 128 + hl * 4];
                aA0 += w0 * bflo(h0.x) + w1 * bflo(h1.x) + w2 * bflo(h2.x) + w3 * bflo(h3.x);
                aA1 += w0 * bfhi(h0.x) + w1 * bfhi(h1.x) + w2 * bfhi(h2.x) + w3 * bfhi(h3.x);
                aA2 += w0 * bflo(h0.y) + w1 * bflo(h1.y) + w2 * bflo(h2.y) + w3 * bflo(h3.y);
                aA3 += w0 * bfhi(h0.y) + w1 * bfhi(h1.y) + w2 * bfhi(h2.y) + w3 * bfhi(h3.y);
            }
            for (; t < mp; t += 2) {
                int i0 = t + half;
                int s0 = __shfl(sA, i0, 64);
                float w0 = __shfl(wA, i0, 64);
                uint2 h0 = *(const uint2*)&hsb[(size_t)s0 * 128 + hl * 4];
                aA0 += w0 * bflo(h0.x);
                aA1 += w0 * bfhi(h0.x);
                aA2 += w0 * bflo(h0.y);
                aA3 += w0 * bfhi(h0.y);
            }
        }
        {
            int mp = (mB + 1) & ~1;
            int t = 0;
            for (; t + 8 <= mp; t += 8) {
                int i0 = t + half, i1 = t + 2 + half, i2 = t + 4 + half, i3 = t + 6 + half;
                int s0 = __shfl(sB, i0, 64), s1 = __shfl(sB, i1, 64);
                int s2 = __shfl(sB, i2, 64), s3 = __shfl(sB, i3, 64);
                float w0 = __shfl(wB, i0, 64), w1 = __shfl(wB, i1, 64);
                float w2 = __shfl(wB, i2, 64), w3 = __shfl(wB, i3, 64);
                uint2 h0 = *(const uint2*)&hsb[(size_t)s0 * 128 + hl * 4];
                uint2 h1 = *(const uint2*)&hsb[(size_t)s1 * 128 + hl * 4];
                uint2 h2 = *(const uint2*)&hsb[(size_t)s2 * 128 + hl * 4];
                uint2 h3 = *(const uint2*)&hsb[(size_t)s3 * 128 + hl * 4];
                aB0 += w0 * bflo(h0.x) + w1 * bflo(h1.x) + w2 * bflo(h2.x) + w3 * bflo(h3.x);
                aB1 += w0 * bfhi(h0.x) + w1 * bfhi(h1.x) + w2 * bfhi(h2.x) + w3 * bfhi(h3.x);
                aB2 += w0 * bflo(h0.y) + w1 * bflo(h1.y) + w2 * bflo(h2.y) + w3 * bflo(h3.y);
                aB3 += w0 * bfhi(h0.y) + w1 * bfhi(h1.y) + w2 * bfhi(h2.y) + w3 * bfhi(h3.y);
            }
            for (; t < mp; t += 2) {
                int i0 = t + half;
                int s0 = __shfl(sB, i0, 64);
                float w0 = __shfl(wB, i0, 64);
                uint2 h0 = *(const uint2*)&hsb[(size_t)s0 * 128 + hl * 4];
                aB0 += w0 * bflo(h0.x);
                aB1 += w0 * bfhi(h0.x);
                aB2 += w0 * bflo(h0.y);
                aB3 += w0 * bfhi(h0.y);
            }
        }
        baseA += 64; baseB += 64;
    }
    aA0 += __shfl_xor(aA0, 32, 64); aA1 += __shfl_xor(aA1, 32, 64);
    aA2 += __shfl_xor(aA2, 32, 64); aA3 += __shfl_xor(aA3, 32, 64);
    aB0 += __shfl_xor(aB0, 32, 64); aB1 += __shfl_xor(aB1, 32, 64);
    aB2 += __shfl_xor(aB2, 32, 64); aB3 += __shfl_xor(aB3, 32, 64);
    #pragma unroll
    for (int off = 1; off < 64; off <<= 1) dA += __shfl_xor(dA, off, 64);
    #pragma unroll
    for (int off = 1; off < 64; off <<= 1) dB += __shfl_xor(dB, off, 64);
    float invA = (endA > begA) ? (1.f / dA) : 0.f;
    float invB = (endB > begB) ? (1.f / dB) : 0.f;
    int node = half ? nodeB : nodeA;
    if (half == 0 || hasB) {
        float v0 = half ? aB0 : aA0, v1 = half ? aB1 : aA1;
        float v2 = half ? aB2 : aA2, v3 = half ? aB3 : aA3;
        float inv = half ? invB : invA;
        uint2 lv = *(const uint2*)&linb[(size_t)node * 128 + hl * 4];
        float4 bb = *(const float4*)&b[hl * 4];
        float4 lb4 = *(const float4*)&Lb[hl * 4];
        float o0 = fmaxf(v0 * inv + bb.x + bflo(lv.x) + lb4.x, 0.f);
        float o1 = fmaxf(v1 * inv + bb.y + bfhi(lv.x) + lb4.y, 0.f);
        float o2 = fmaxf(v2 * inv + bb.z + bflo(lv.y) + lb4.z, 0.f);
        float o3 = fmaxf(v3 * inv + bb.w + bfhi(lv.y) + lb4.w, 0.f);
        uint2 ov;
        ov.x = (uint_t)f2bf(o0) | ((uint_t)f2bf(o1) << 16);
        ov.y = (uint_t)f2bf(o2) | ((uint_t)f2bf(o3) << 16);
        *(uint2*)&hh[(size_t)node * 64 + hl * 2] = ov;
    }
}

// ---------------- translate aggregate (C=64), fused ed matvec ----------------
__global__ __launch_bounds__(256) void agg_fp5(const int* __restrict__ ptr, const int* __restrict__ col,
                                               const float* __restrict__ es, const float* __restrict__ x_fp,
                                               const float* __restrict__ wedt,
                                               const ushort_t* __restrict__ hsb, const float* __restrict__ bt,
                                               float* __restrict__ out, int N) {
    int lane = threadIdx.x & 63, wid = threadIdx.x >> 6;
    int node = blockIdx.x * 4 + wid;
    if (node >= N) return;
    int beg = ptr[node], end = ptr[node + 1];
    float edn = x_fp[(size_t)node * 64 + lane] * wedt[lane];
    #pragma unroll
    for (int off = 1; off < 64; off <<= 1) edn += __shfl_xor(edn, off, 64);
    float acc = 0.f, denp = 0.f;
    for (int base = beg; base < end; base += 64) {
        int m = min(64, end - base);
        int s = 0;
        float wgt = 0.f;
        if (lane < m) {
            s = col[base + lane];
            float e = es[s] + edn;
            e = fmaxf(e, 0.2f * e);
            wgt = __expf(e);
        }
        denp += wgt;
        int u = 0;
        for (; u + 4 <= m; u += 4) {
            int s0 = __shfl(s, u, 64), s1 = __shfl(s, u + 1, 64);
            int s2 = __shfl(s, u + 2, 64), s3 = __shfl(s, u + 3, 64);
            float w0 = __shfl(wgt, u, 64), w1 = __shfl(wgt, u + 1, 64);
            float w2 = __shfl(wgt, u + 2, 64), w3 = __shfl(wgt, u + 3, 64);
            float h0 = bfu2f(hsb[(size_t)s0 * 64 + lane]);
            float h1 = bfu2f(hsb[(size_t)s1 * 64 + lane]);
            float h2 = bfu2f(hsb[(size_t)s2 * 64 + lane]);
            float h3 = bfu2f(hsb[(size_t)s3 * 64 + lane]);
            acc += w0 * h0 + w1 * h1 + w2 * h2 + w3 * h3;
        }
        for (; u < m; ++u) {
            int su = __shfl(s, u, 64);
            float wu = __shfl(wgt, u, 64);
            acc += wu * bfu2f(hsb[(size_t)su * 64 + lane]);
        }
    }
    float den = denp;
    #pragma unroll
    for (int off = 1; off < 64; off <<= 1) den += __shfl_xor(den, off, 64);
    float inv = (end > beg) ? (1.f / den) : 0.f;
    out[(size_t)node * 64 + lane] = acc * inv + bt[lane];
}

extern "C" void kernel_launch(void* const* d_in, const int* in_sizes, int n_in,
                              void* d_out, int out_size, void* d_ws, size_t ws_size,
                              hipStream_t stream) {
    const float* x_pano = (const float*)d_in[0];
    const float* x_fp   = (const float*)d_in[1];
    const float* Ws0 = (const float*)d_in[2];
    const float* Wd0 = (const float*)d_in[3];
    const float* as0 = (const float*)d_in[4];
    const float* ad0 = (const float*)d_in[5];
    const float* b0  = (const float*)d_in[6];
    const float* Lw0 = (const float*)d_in[7];
    const float* Lb0 = (const float*)d_in[8];
    const float* Ws1 = (const float*)d_in[9];
    const float* Wd1 = (const float*)d_in[10];
    const float* as1 = (const float*)d_in[11];
    const float* ad1 = (const float*)d_in[12];
    const float* b1  = (const float*)d_in[13];
    const float* Lw1 = (const float*)d_in[14];
    const float* Lb1 = (const float*)d_in[15];
    const float* Wts = (const float*)d_in[16];
    const float* Wtd = (const float*)d_in[17];
    const float* ats = (const float*)d_in[18];
    const float* atd = (const float*)d_in[19];
    const float* bt  = (const float*)d_in[20];
    const int* pp_src = (const int*)d_in[21];
    const int* pp_dst = (const int*)d_in[21] + E_PP;
    const int* pf_src = (const int*)d_in[22];
    const int* pf_dst = (const int*)d_in[23];
    float* out = (float*)d_out;

    char* wsp = (char*)d_ws;
    size_t off = 0;
    auto alloc = [&](size_t bytes) -> char* {
        char* p = wsp + off;
        off += (bytes + 255) & ~(size_t)255;
        return p;
    };
    ushort_t* hsb  = (ushort_t*)alloc(sizeof(ushort_t) * N_PANO * HID);
    ushort_t* linb = (ushort_t*)alloc(sizeof(ushort_t) * N_PANO * HID);
    uint_t* hh     = (uint_t*)alloc(sizeof(uint_t) * N_PANO * 64);
    ushort_t* hstb = (ushort_t*)alloc(sizeof(ushort_t) * N_PANO * OUT_C);
    int2* tmp_e    = (int2*)alloc(sizeof(int2) * E_UNI);
    float* es   = (float*)alloc(sizeof(float) * N_PANO);
    float* ed   = (float*)alloc(sizeof(float) * N_PANO);
    float* wed0 = (float*)alloc(sizeof(float) * HID);
    float* wed1 = (float*)alloc(sizeof(float) * HID);
    float* wedt = (float*)alloc(sizeof(float) * OUT_C);
    ushort_t* s0 = (ushort_t*)alloc(sizeof(ushort_t) * 128 * 128);
    ushort_t* l0 = (ushort_t*)alloc(sizeof(ushort_t) * 128 * 128);
    ushort_t* s1 = (ushort_t*)alloc(sizeof(ushort_t) * 128 * 128);
    ushort_t* l1 = (ushort_t*)alloc(sizeof(ushort_t) * 128 * 128);
    ushort_t* ts = (ushort_t*)alloc(sizeof(ushort_t) * 64 * 128);
    int* pcnt  = (int*)alloc(sizeof(int) * NBKT * NT_CNT);
    int* bbase = (int*)alloc(sizeof(int) * (NBKT + 1));
    int* P     = (int*)alloc(sizeof(int) * (N_UNI + 1));
    int* col_u = (int*)alloc(sizeof(int) * E_UNI);

    // L1: per-tile bucket counts + weight fragment-permute + wed matvecs
    csr_count_prep<<<NT_CNT + 288 + 80, 256, 0, stream>>>(
        pp_dst, pf_dst, pcnt, Ws0, Lw0, Ws1, Lw1, Wts,
        Wd0, ad0, Wd1, ad1, Wtd, atd, s0, l0, s1, l1, ts, wed0, wed1, wedt);

    // L2: coarse scatter (inline 2D prefix) || layer-0 dual GEMM (64-row tiles)
    scatter_gemm0<<<NT_CNT + NT_GEMM, 256, 0, stream>>>(
        pp_src, pp_dst, pf_src, pf_dst, pcnt, bbase, tmp_e,
        x_pano, s0, l0, hsb, linb, as0, es, wed0, ed);

    // L3: per-bucket counting sort -> P, col
    csr_sort<<<NBKT, 256, 0, stream>>>(tmp_e, bbase, P, col_u);

    // L4: layer-0 aggregate
    agg_pano7<<<cdiv(N_PANO, 8), 256, 0, stream>>>(P, col_u, es, ed, hsb, linb, b0, Lb0, hh, N_PANO);

    // L5: layer-1 dual GEMM (bf16 input = hh)
    gemm_mfma<128, true, false><<<NT_GEMM, 256, 0, stream>>>(
        nullptr, (const ushort_t*)hh, s1, l1, hsb, linb, as1, es, wed1, ed, N_PANO);

    // L6: layer-1 aggregate
    agg_pano7<<<cdiv(N_PANO, 8), 256, 0, stream>>>(P, col_u, es, ed, hsb, linb, b1, Lb1, hh, N_PANO);

    // L7: translate GEMM (C=64)
    gemm_mfma<64, false, false><<<NT_GEMM, 256, 0, stream>>>(
        nullptr, (const ushort_t*)hh, ts, nullptr, hstb, nullptr, ats, es, nullptr, nullptr, N_PANO);

    // L8: translate aggregate (pf ptr = P+50000, absolute into col_u)
    agg_fp5<<<cdiv(N_FP, 4), 256, 0, stream>>>(P + N_PANO, col_u, es, x_fp, wedt, hstb, bt, out, N_FP);
}

// Round 6
// 254.715 us; speedup vs baseline: 1.1419x; 1.0173x over previous
//
#include <hip/hip_runtime.h>
#include <hip/hip_bf16.h>
#include <math.h>

#define N_PANO 50000
#define N_FP   10000
#define N_UNI  60000   // unified dst id-space: pano [0,50000), fp mapped to 50000+d
#define HID    128
#define OUT_C  64
#define E_PP   800000
#define E_PF   50000
#define E_UNI  850000
#define NBKT   235     // cdiv(N_UNI, 256) coarse buckets
#define EPB    4096    // edges per tile in count/scatter (measured-best)
#define NT_CNT 208     // cdiv(E_UNI, EPB)
#define NT_GEMM 782    // cdiv(N_PANO, 64) -- 64-row tiles (R5: occupancy win)

typedef unsigned short ushort_t;
typedef unsigned int uint_t;
typedef __attribute__((ext_vector_type(8))) short short8;
typedef __attribute__((ext_vector_type(4))) float f32x4;

static inline int cdiv(int a, int b) { return (a + b - 1) / b; }

__device__ inline ushort_t f2bf(float x) {
    __hip_bfloat16 h = __float2bfloat16(x);   // RNE
    return *reinterpret_cast<ushort_t*>(&h);
}
__device__ inline float bfu2f(ushort_t u) {
    return __uint_as_float(((uint_t)u) << 16);
}
__device__ inline float bflo(uint_t u) { return __uint_as_float((u & 0xffffu) << 16); }
__device__ inline float bfhi(uint_t u) { return __uint_as_float(u & 0xffff0000u); }
__device__ inline f32x4 mfma16(short8 a, short8 b, f32x4 c) {
    return __builtin_amdgcn_mfma_f32_16x16x32_bf16(a, b, c, 0, 0, 0);
}

// ---------------- CSR stage 1: per-tile partial counts + weight prep (merged) ----------------
__global__ __launch_bounds__(256, 4) void csr_count_prep(
        const int* __restrict__ pp_dst, const int* __restrict__ pf_dst,
        int* __restrict__ pcnt,
        const float* __restrict__ Ws0, const float* __restrict__ Lw0,
        const float* __restrict__ Ws1, const float* __restrict__ Lw1,
        const float* __restrict__ Wts,
        const float* __restrict__ Wd0, const float* __restrict__ ad0,
        const float* __restrict__ Wd1, const float* __restrict__ ad1,
        const float* __restrict__ Wtd, const float* __restrict__ atd,
        ushort_t* s0, ushort_t* l0, ushort_t* s1, ushort_t* l1, ushort_t* ts,
        float* wed0, float* wed1, float* wedt) {
    __shared__ int hist[NBKT];
    const int tile = blockIdx.x, tid = threadIdx.x;
    if (tile < NT_CNT) {
        for (int t = tid; t < NBKT; t += 256) hist[t] = 0;
        __syncthreads();
        const int e0 = tile * EPB;
        #pragma unroll
        for (int u = 0; u < 16; ++u) {
            int e = e0 + u * 256 + tid;
            int d = -1;
            if (e < E_PP) d = pp_dst[e];
            else if (e < E_UNI) d = N_PANO + pf_dst[e - E_PP];
            if (d >= 0) atomicAdd(&hist[d >> 8], 1);
        }
        __syncthreads();
        for (int t = tid; t < NBKT; t += 256) pcnt[tile * NBKT + t] = hist[t];
    } else if (tile < NT_CNT + 288) {
        int i = (tile - NT_CNT) * 256 + tid;
        const float* W; ushort_t* oh;
        int d, NIc, Cc;
        if (i < 65536) {
            int m = i >> 14; d = i & 16383;
            W = (m == 0) ? Ws0 : (m == 1) ? Lw0 : (m == 2) ? Ws1 : Lw1;
            oh = (m == 0) ? s0 : (m == 1) ? l0 : (m == 2) ? s1 : l1;
            NIc = 8; Cc = 128;
        } else if (i < 73728) {
            d = i - 65536; W = Wts; oh = ts;
            NIc = 4; Cc = 64;
        } else return;
        int j = d & 7, l = (d >> 3) & 63;
        int kcl = (d >> 9) & 1;
        int ni = (d >> 10) & (NIc - 1);
        int p = d >> (10 + (NIc == 8 ? 3 : 2));
        int kc = p * 2 + kcl;
        int n = ni * 16 + (l & 15);
        int k = kc * 32 + (l >> 4) * 8 + j;
        oh[d] = f2bf(W[k * Cc + n]);
    } else {
        int r = (tile - NT_CNT - 288) * 4 + (tid >> 6);
        int lane = tid & 63;
        const float* W; const float* a; float* o; int rr, C;
        if (r < 128)      { W = Wd0; a = ad0; o = wed0; rr = r;       C = 128; }
        else if (r < 256) { W = Wd1; a = ad1; o = wed1; rr = r - 128; C = 128; }
        else if (r < 320) { W = Wtd; a = atd; o = wedt; rr = r - 256; C = 64;  }
        else return;
        float s = 0.f;
        for (int j = lane; j < C; j += 64) s += W[rr * C + j] * a[j];
        #pragma unroll
        for (int off = 32; off; off >>= 1) s += __shfl_down(s, off, 64);
        if (lane == 0) o[rr] = s;
    }
}

// ---------------- GEMM body: 64-row tiles, one 16-row MFMA strip per wave, ----------------
// barrier-free (B fragments loaded straight from global in fragment order; L2-resident).
template <int CN, bool DUAL, bool FP32IN>
__device__ void gemm_body(int tile,
                          const float* __restrict__ Xf, const ushort_t* __restrict__ Xh,
                          const ushort_t* __restrict__ W1, const ushort_t* __restrict__ W2,
                          ushort_t* __restrict__ Y1, ushort_t* __restrict__ Y2,
                          const float* __restrict__ avec, float* __restrict__ evec,
                          const float* __restrict__ wed, float* __restrict__ edv, int N) {
    constexpr int NI = CN / 16;
    constexpr int SLAB = NI * 1024;
    const int tid = threadIdx.x;
    const int w = tid >> 6, l = tid & 63;
    const int col = l & 15, q = l >> 4;
    const int row0 = tile * 64 + w * 16;
    f32x4 acc1[NI];
    f32x4 acc2[DUAL ? NI : 1];
    #pragma unroll
    for (int ni = 0; ni < NI; ++ni)
        #pragma unroll
        for (int r = 0; r < 4; ++r) acc1[ni][r] = 0.f;
    if (DUAL) {
        #pragma unroll
        for (int ni = 0; ni < NI; ++ni)
            #pragma unroll
            for (int r = 0; r < 4; ++r) acc2[ni][r] = 0.f;
    }
    float ped = 0.f;

    #pragma unroll
    for (int p = 0; p < 2; ++p) {
        #pragma unroll
        for (int kcl = 0; kcl < 2; ++kcl) {
            const int kc = p * 2 + kcl;
            const int k0 = kc * 32 + q * 8;
            short8 Ah;
            const int arow = row0 + col;
            if (FP32IN) {
                float xv[8];
                if (arow < N) {
                    float4 a0 = *(const float4*)&Xf[(size_t)arow * 128 + k0];
                    float4 a1 = *(const float4*)&Xf[(size_t)arow * 128 + k0 + 4];
                    xv[0] = a0.x; xv[1] = a0.y; xv[2] = a0.z; xv[3] = a0.w;
                    xv[4] = a1.x; xv[5] = a1.y; xv[6] = a1.z; xv[7] = a1.w;
                } else {
                    #pragma unroll
                    for (int j = 0; j < 8; ++j) xv[j] = 0.f;
                }
                #pragma unroll
                for (int j = 0; j < 8; ++j) Ah[j] = (short)f2bf(xv[j]);
                if (wed) {
                    float4 w0 = *(const float4*)&wed[k0];
                    float4 w1 = *(const float4*)&wed[k0 + 4];
                    ped += xv[0] * w0.x + xv[1] * w0.y + xv[2] * w0.z + xv[3] * w0.w
                         + xv[4] * w1.x + xv[5] * w1.y + xv[6] * w1.z + xv[7] * w1.w;
                }
            } else {
                if (arow < N) {
                    Ah = *(const short8*)&Xh[(size_t)arow * 128 + k0];
                } else {
                    #pragma unroll
                    for (int j = 0; j < 8; ++j) Ah[j] = 0;
                }
                if (wed) {
                    float4 w0 = *(const float4*)&wed[k0];
                    float4 w1 = *(const float4*)&wed[k0 + 4];
                    float wv[8] = {w0.x, w0.y, w0.z, w0.w, w1.x, w1.y, w1.z, w1.w};
                    #pragma unroll
                    for (int j = 0; j < 8; ++j)
                        ped += bfu2f((ushort_t)Ah[j]) * wv[j];
                }
            }
            #pragma unroll
            for (int ni = 0; ni < NI; ++ni) {
                const int gb = p * SLAB + ((ni * 2 + kcl) * 64 + l) * 8;
                short8 B1 = *(const short8*)&W1[gb];
                acc1[ni] = mfma16(Ah, B1, acc1[ni]);
                if (DUAL) {
                    short8 B2 = *(const short8*)&W2[gb];
                    acc2[ni] = mfma16(Ah, B2, acc2[ni]);
                }
            }
        }
    }

    #pragma unroll
    for (int ni = 0; ni < NI; ++ni) {
        #pragma unroll
        for (int r = 0; r < 4; ++r) {
            int mrow = row0 + q * 4 + r;
            if (mrow < N) {
                Y1[(size_t)mrow * CN + ni * 16 + col] = f2bf(acc1[ni][r]);
                if (DUAL) Y2[(size_t)mrow * CN + ni * 16 + col] = f2bf(acc2[ni][r]);
            }
        }
    }
    float av[NI];
    #pragma unroll
    for (int ni = 0; ni < NI; ++ni) av[ni] = avec[ni * 16 + col];
    #pragma unroll
    for (int r = 0; r < 4; ++r) {
        float pp = 0.f;
        #pragma unroll
        for (int ni = 0; ni < NI; ++ni) pp += acc1[ni][r] * av[ni];
        pp += __shfl_xor(pp, 1, 64);
        pp += __shfl_xor(pp, 2, 64);
        pp += __shfl_xor(pp, 4, 64);
        pp += __shfl_xor(pp, 8, 64);
        int mrow = row0 + q * 4 + r;
        if (col == 0 && mrow < N) evec[mrow] = pp;
    }
    if (wed) {
        ped += __shfl_xor(ped, 16, 64);
        ped += __shfl_xor(ped, 32, 64);
        const int arow = row0 + col;
        if (q == 0 && arow < N) edv[arow] = ped;
    }
}

// ---------------- scatter body: inline 2D prefix, batch-8 ILP on the pcnt chain ----------------
__device__ void scatter_body(int tile, char* smem,
                             const int* __restrict__ pp_src, const int* __restrict__ pp_dst,
                             const int* __restrict__ pf_src, const int* __restrict__ pf_dst,
                             const int* __restrict__ pcnt, int* __restrict__ bbase_out,
                             int2* __restrict__ tmp) {
    int* base2 = (int*)smem;            // [NBKT]
    int* cur   = base2 + NBKT;          // [NBKT]
    int* wsum  = cur + NBKT;            // [4]
    const int tid = threadIdx.x, lane = tid & 63, wv = tid >> 6;
    int rowsum = 0, myprefix = 0;
    if (tid < NBKT) {
        const int* pb = pcnt + tid;
        int t = 0;
        for (; t + 8 <= NT_CNT; t += 8) {
            int c0 = pb[(t + 0) * NBKT], c1 = pb[(t + 1) * NBKT];
            int c2 = pb[(t + 2) * NBKT], c3 = pb[(t + 3) * NBKT];
            int c4 = pb[(t + 4) * NBKT], c5 = pb[(t + 5) * NBKT];
            int c6 = pb[(t + 6) * NBKT], c7 = pb[(t + 7) * NBKT];
            rowsum += c0 + c1 + c2 + c3 + c4 + c5 + c6 + c7;
            myprefix += ((t + 0 < tile) ? c0 : 0) + ((t + 1 < tile) ? c1 : 0)
                      + ((t + 2 < tile) ? c2 : 0) + ((t + 3 < tile) ? c3 : 0)
                      + ((t + 4 < tile) ? c4 : 0) + ((t + 5 < tile) ? c5 : 0)
                      + ((t + 6 < tile) ? c6 : 0) + ((t + 7 < tile) ? c7 : 0);
        }
        for (; t < NT_CNT; ++t) {
            int c = pb[t * NBKT];
            rowsum += c;
            if (t < tile) myprefix += c;
        }
    }
    // exclusive scan of rowsum over buckets -> bucket base
    int v = (tid < NBKT) ? rowsum : 0;
    int incl = v;
    #pragma unroll
    for (int off = 1; off < 64; off <<= 1) {
        int t = __shfl_up(incl, off, 64);
        if (lane >= off) incl += t;
    }
    if (lane == 63) wsum[wv] = incl;
    __syncthreads();
    if (tid == 0) {
        int run = 0;
        #pragma unroll
        for (int w = 0; w < 4; ++w) { int t = wsum[w]; wsum[w] = run; run += t; }
    }
    __syncthreads();
    int bexcl = wsum[wv] + incl - v;
    if (tid < NBKT) {
        base2[tid] = bexcl + myprefix;
        cur[tid] = 0;
        if (tile == 0) bbase_out[tid] = bexcl;
    }
    if (tile == 0 && tid == 0) bbase_out[NBKT] = E_UNI;
    __syncthreads();
    const int e0 = tile * EPB;
    #pragma unroll
    for (int u = 0; u < 16; ++u) {
        int e = e0 + u * 256 + tid;
        int d = -1, s = 0;
        if (e < E_PP)       { d = pp_dst[e];                 s = pp_src[e]; }
        else if (e < E_UNI) { d = N_PANO + pf_dst[e - E_PP]; s = pf_src[e - E_PP]; }
        if (d >= 0) {
            int b = d >> 8;
            int p = base2[b] + atomicAdd(&cur[b], 1);
            tmp[p] = make_int2(s, d);
        }
    }
}

// ---------------- merged launch: scatter (tiles 0..207) || layer-0 dual GEMM ----------------
__global__ __launch_bounds__(256, 4) void scatter_gemm0(
        const int* __restrict__ pp_src, const int* __restrict__ pp_dst,
        const int* __restrict__ pf_src, const int* __restrict__ pf_dst,
        const int* __restrict__ pcnt, int* __restrict__ bbase_out, int2* __restrict__ tmp,
        const float* __restrict__ x_pano,
        const ushort_t* __restrict__ s0, const ushort_t* __restrict__ l0,
        ushort_t* __restrict__ hsb, ushort_t* __restrict__ linb,
        const float* __restrict__ as0, float* __restrict__ es,
        const float* __restrict__ wed0, float* __restrict__ ed) {
    __shared__ __align__(16) char smem[(2 * NBKT + 4) * 4];
    if (blockIdx.x < NT_CNT)
        scatter_body(blockIdx.x, smem, pp_src, pp_dst, pf_src, pf_dst, pcnt, bbase_out, tmp);
    else
        gemm_body<128, true, true>(blockIdx.x - NT_CNT, x_pano, nullptr, s0, l0,
                                   hsb, linb, as0, es, wed0, ed, N_PANO);
}

// ---------------- standalone GEMM kernel (layers 1 and translate), barrier-free ----------------
template <int CN, bool DUAL, bool FP32IN>
__global__ __launch_bounds__(256, 4) void gemm_mfma(const float* __restrict__ Xf,
                                                 const ushort_t* __restrict__ Xh,
                                                 const ushort_t* __restrict__ W1, const ushort_t* __restrict__ W2,
                                                 ushort_t* __restrict__ Y1, ushort_t* __restrict__ Y2,
                                                 const float* __restrict__ avec, float* __restrict__ evec,
                                                 const float* __restrict__ wed, float* __restrict__ edv,
                                                 int N) {
    gemm_body<CN, DUAL, FP32IN>(blockIdx.x, Xf, Xh, W1, W2, Y1, Y2, avec, evec, wed, edv, N);
}

// ---------------- CSR stage 4: per-bucket counting sort in LDS -> P, col ----------------
// 1024 threads/block: csr_sort was 0.92 blocks/CU x 4 waves = the worst-occupancy kernel
// in the pipeline (two dependent passes, no cross-block latency hiding). 16 waves/CU now.
__global__ __launch_bounds__(1024, 1) void csr_sort(const int2* __restrict__ tmp,
                                                    const int* __restrict__ bbase,
                                                    int* __restrict__ ptr, int* __restrict__ col) {
    __shared__ int hist[256];
    __shared__ int wsum[4];
    const int b = blockIdx.x, tid = threadIdx.x, lane = tid & 63, wv = tid >> 6;
    const int B0 = bbase[b], B1 = bbase[b + 1];
    if (tid < 256) hist[tid] = 0;
    __syncthreads();
    for (int e = B0 + tid; e < B1; e += 1024) atomicAdd(&hist[tmp[e].y & 255], 1);
    __syncthreads();
    int v = (tid < 256) ? hist[tid] : 0;
    int incl = v;
    #pragma unroll
    for (int off = 1; off < 64; off <<= 1) {
        int t = __shfl_up(incl, off, 64);
        if (lane >= off) incl += t;
    }
    if (lane == 63 && tid < 256) wsum[wv] = incl;
    __syncthreads();
    if (tid == 0) {
        int run = 0;
        #pragma unroll
        for (int w = 0; w < 4; ++w) { int t = wsum[w]; wsum[w] = run; run += t; }
    }
    __syncthreads();
    if (tid < 256) {
        int excl = wsum[wv] + incl - v;
        int dg = b * 256 + tid;
        if (dg < N_UNI) ptr[dg] = B0 + excl;
        hist[tid] = excl;
    }
    if (b == NBKT - 1 && tid == 0) ptr[N_UNI] = E_UNI;
    __syncthreads();
    for (int e = B0 + tid; e < B1; e += 1024) {
        int2 ed2 = tmp[e];
        int p = B0 + atomicAdd(&hist[ed2.y & 255], 1);
        col[p] = ed2.x;
    }
}

// ---------------- GAT aggregate (pano): two nodes per wave, pair-packed ----------------
__global__ __launch_bounds__(256, 4) void agg_pano7(const int* __restrict__ ptr, const int* __restrict__ col,
                                                 const float* __restrict__ es, const float* __restrict__ ed,
                                                 const ushort_t* __restrict__ hsb, const ushort_t* __restrict__ linb,
                                                 const float* __restrict__ b, const float* __restrict__ Lb,
                                                 uint_t* __restrict__ hh, int N) {
    int lane = threadIdx.x & 63, wid = threadIdx.x >> 6;
    int nodeA = blockIdx.x * 8 + wid * 2;
    if (nodeA >= N) return;
    int nodeB = nodeA + 1;
    bool hasB = nodeB < N;
    int begA = ptr[nodeA], endA = ptr[nodeA + 1];
    int endB = hasB ? ptr[nodeB + 1] : endA;
    int begB = endA;   // contiguous CSR
    float ednA = ed[nodeA];
    float ednB = hasB ? ed[nodeB] : 0.f;
    const int half = lane >> 5, hl = lane & 31;
    float aA0 = 0.f, aA1 = 0.f, aA2 = 0.f, aA3 = 0.f, dA = 0.f;
    float aB0 = 0.f, aB1 = 0.f, aB2 = 0.f, aB3 = 0.f, dB = 0.f;
    int baseA = begA, baseB = begB;
    while (baseA < endA || baseB < endB) {
        int mA = endA - baseA; mA = mA < 0 ? 0 : (mA > 64 ? 64 : mA);
        int mB = endB - baseB; mB = mB < 0 ? 0 : (mB > 64 ? 64 : mB);
        int sA = 0, sB = 0;
        float wA = 0.f, wB = 0.f;
        if (lane < mA) {
            sA = col[baseA + lane];
            float e = es[sA] + ednA;
            e = fmaxf(e, 0.2f * e);
            wA = __expf(e);
        }
        if (lane < mB) {
            sB = col[baseB + lane];
            float e = es[sB] + ednB;
            e = fmaxf(e, 0.2f * e);
            wB = __expf(e);
        }
        dA += wA; dB += wB;
        {
            int mp = (mA + 1) & ~1;
            int t = 0;
            for (; t + 8 <= mp; t += 8) {
                int i0 = t + half, i1 = t + 2 + half, i2 = t + 4 + half, i3 = t + 6 + half;
                int s0 = __shfl(sA, i0, 64), s1 = __shfl(sA, i1, 64);
                int s2 = __shfl(sA, i2, 64), s3 = __shfl(sA, i3, 64);
                float w0 = __shfl(wA, i0, 64), w1 = __shfl(wA, i1, 64);
                float w2 = __shfl(wA, i2, 64), w3 = __shfl(wA, i3, 64);
                uint2 h0 = *(const uint2*)&hsb[(size_t)s0 * 128 + hl * 4];
                uint2 h1 = *(const uint2*)&hsb[(size_t)s1 * 128 + hl * 4];
                uint2 h2 = *(const uint2*)&hsb[(size_t)s2 * 128 + hl * 4];
                uint2 h3 = *(const uint2*)&hsb[(size_t)s3 * 128 + hl * 4];
                aA0 += w0 * bflo(h0.x) + w1 * bflo(h1.x) + w2 * bflo(h2.x) + w3 * bflo(h3.x);
                aA1 += w0 * bfhi(h0.x) + w1 * bfhi(h1.x) + w2 * bfhi(h2.x) + w3 * bfhi(h3.x);
                aA2 += w0 * bflo(h0.y) + w1 * bflo(h1.y) + w2 * bflo(h2.y) + w3 * bflo(h3.y);
                aA3 += w0 * bfhi(h0.y) + w1 * bfhi(h1.y) + w2 * bfhi(h2.y) + w3 * bfhi(h3.y);
            }
            for (; t < mp; t += 2) {
                int i0 = t + half;
                int s0 = __shfl(sA, i0, 64);
                float w0 = __shfl(wA, i0, 64);
                uint2 h0 = *(const uint2*)&hsb[(size_t)s0 * 128 + hl * 4];
                aA0 += w0 * bflo(h0.x);
                aA1 += w0 * bfhi(h0.x);
                aA2 += w0 * bflo(h0.y);
                aA3 += w0 * bfhi(h0.y);
            }
        }
        {
            int mp = (mB + 1) & ~1;
            int t = 0;
            for (; t + 8 <= mp; t += 8) {
                int i0 = t + half, i1 = t + 2 + half, i2 = t + 4 + half, i3 = t + 6 + half;
                int s0 = __shfl(sB, i0, 64), s1 = __shfl(sB, i1, 64);
                int s2 = __shfl(sB, i2, 64), s3 = __shfl(sB, i3, 64);
                float w0 = __shfl(wB, i0, 64), w1 = __shfl(wB, i1, 64);
                float w2 = __shfl(wB, i2, 64), w3 = __shfl(wB, i3, 64);
                uint2 h0 = *(const uint2*)&hsb[(size_t)s0 * 128 + hl * 4];
                uint2 h1 = *(const uint2*)&hsb[(size_t)s1 * 128 + hl * 4];
                uint2 h2 = *(const uint2*)&hsb[(size_t)s2 * 128 + hl * 4];
                uint2 h3 = *(const uint2*)&hsb[(size_t)s3 * 128 + hl * 4];
                aB0 += w0 * bflo(h0.x) + w1 * bflo(h1.x) + w2 * bflo(h2.x) + w3 * bflo(h3.x);
                aB1 += w0 * bfhi(h0.x) + w1 * bfhi(h1.x) + w2 * bfhi(h2.x) + w3 * bfhi(h3.x);
                aB2 += w0 * bflo(h0.y) + w1 * bflo(h1.y) + w2 * bflo(h2.y) + w3 * bflo(h3.y);
                aB3 += w0 * bfhi(h0.y) + w1 * bfhi(h1.y) + w2 * bfhi(h2.y) + w3 * bfhi(h3.y);
            }
            for (; t < mp; t += 2) {
                int i0 = t + half;
                int s0 = __shfl(sB, i0, 64);
                float w0 = __shfl(wB, i0, 64);
                uint2 h0 = *(const uint2*)&hsb[(size_t)s0 * 128 + hl * 4];
                aB0 += w0 * bflo(h0.x);
                aB1 += w0 * bfhi(h0.x);
                aB2 += w0 * bflo(h0.y);
                aB3 += w0 * bfhi(h0.y);
            }
        }
        baseA += 64; baseB += 64;
    }
    aA0 += __shfl_xor(aA0, 32, 64); aA1 += __shfl_xor(aA1, 32, 64);
    aA2 += __shfl_xor(aA2, 32, 64); aA3 += __shfl_xor(aA3, 32, 64);
    aB0 += __shfl_xor(aB0, 32, 64); aB1 += __shfl_xor(aB1, 32, 64);
    aB2 += __shfl_xor(aB2, 32, 64); aB3 += __shfl_xor(aB3, 32, 64);
    #pragma unroll
    for (int off = 1; off < 64; off <<= 1) dA += __shfl_xor(dA, off, 64);
    #pragma unroll
    for (int off = 1; off < 64; off <<= 1) dB += __shfl_xor(dB, off, 64);
    float invA = (endA > begA) ? (1.f / dA) : 0.f;
    float invB = (endB > begB) ? (1.f / dB) : 0.f;
    int node = half ? nodeB : nodeA;
    if (half == 0 || hasB) {
        float v0 = half ? aB0 : aA0, v1 = half ? aB1 : aA1;
        float v2 = half ? aB2 : aA2, v3 = half ? aB3 : aA3;
        float inv = half ? invB : invA;
        uint2 lv = *(const uint2*)&linb[(size_t)node * 128 + hl * 4];
        float4 bb = *(const float4*)&b[hl * 4];
        float4 lb4 = *(const float4*)&Lb[hl * 4];
        float o0 = fmaxf(v0 * inv + bb.x + bflo(lv.x) + lb4.x, 0.f);
        float o1 = fmaxf(v1 * inv + bb.y + bfhi(lv.x) + lb4.y, 0.f);
        float o2 = fmaxf(v2 * inv + bb.z + bflo(lv.y) + lb4.z, 0.f);
        float o3 = fmaxf(v3 * inv + bb.w + bfhi(lv.y) + lb4.w, 0.f);
        uint2 ov;
        ov.x = (uint_t)f2bf(o0) | ((uint_t)f2bf(o1) << 16);
        ov.y = (uint_t)f2bf(o2) | ((uint_t)f2bf(o3) << 16);
        *(uint2*)&hh[(size_t)node * 64 + hl * 2] = ov;
    }
}

// ---------------- translate aggregate (C=64), fused ed matvec ----------------
__global__ __launch_bounds__(256, 4) void agg_fp5(const int* __restrict__ ptr, const int* __restrict__ col,
                                               const float* __restrict__ es, const float* __restrict__ x_fp,
                                               const float* __restrict__ wedt,
                                               const ushort_t* __restrict__ hsb, const float* __restrict__ bt,
                                               float* __restrict__ out, int N) {
    int lane = threadIdx.x & 63, wid = threadIdx.x >> 6;
    int node = blockIdx.x * 4 + wid;
    if (node >= N) return;
    int beg = ptr[node], end = ptr[node + 1];
    float edn = x_fp[(size_t)node * 64 + lane] * wedt[lane];
    #pragma unroll
    for (int off = 1; off < 64; off <<= 1) edn += __shfl_xor(edn, off, 64);
    float acc = 0.f, denp = 0.f;
    for (int base = beg; base < end; base += 64) {
        int m = min(64, end - base);
        int s = 0;
        float wgt = 0.f;
        if (lane < m) {
            s = col[base + lane];
            float e = es[s] + edn;
            e = fmaxf(e, 0.2f * e);
            wgt = __expf(e);
        }
        denp += wgt;
        int u = 0;
        for (; u + 4 <= m; u += 4) {
            int s0 = __shfl(s, u, 64), s1 = __shfl(s, u + 1, 64);
            int s2 = __shfl(s, u + 2, 64), s3 = __shfl(s, u + 3, 64);
            float w0 = __shfl(wgt, u, 64), w1 = __shfl(wgt, u + 1, 64);
            float w2 = __shfl(wgt, u + 2, 64), w3 = __shfl(wgt, u + 3, 64);
            float h0 = bfu2f(hsb[(size_t)s0 * 64 + lane]);
            float h1 = bfu2f(hsb[(size_t)s1 * 64 + lane]);
            float h2 = bfu2f(hsb[(size_t)s2 * 64 + lane]);
            float h3 = bfu2f(hsb[(size_t)s3 * 64 + lane]);
            acc += w0 * h0 + w1 * h1 + w2 * h2 + w3 * h3;
        }
        for (; u < m; ++u) {
            int su = __shfl(s, u, 64);
            float wu = __shfl(wgt, u, 64);
            acc += wu * bfu2f(hsb[(size_t)su * 64 + lane]);
        }
    }
    float den = denp;
    #pragma unroll
    for (int off = 1; off < 64; off <<= 1) den += __shfl_xor(den, off, 64);
    float inv = (end > beg) ? (1.f / den) : 0.f;
    out[(size_t)node * 64 + lane] = acc * inv + bt[lane];
}

extern "C" void kernel_launch(void* const* d_in, const int* in_sizes, int n_in,
                              void* d_out, int out_size, void* d_ws, size_t ws_size,
                              hipStream_t stream) {
    const float* x_pano = (const float*)d_in[0];
    const float* x_fp   = (const float*)d_in[1];
    const float* Ws0 = (const float*)d_in[2];
    const float* Wd0 = (const float*)d_in[3];
    const float* as0 = (const float*)d_in[4];
    const float* ad0 = (const float*)d_in[5];
    const float* b0  = (const float*)d_in[6];
    const float* Lw0 = (const float*)d_in[7];
    const float* Lb0 = (const float*)d_in[8];
    const float* Ws1 = (const float*)d_in[9];
    const float* Wd1 = (const float*)d_in[10];
    const float* as1 = (const float*)d_in[11];
    const float* ad1 = (const float*)d_in[12];
    const float* b1  = (const float*)d_in[13];
    const float* Lw1 = (const float*)d_in[14];
    const float* Lb1 = (const float*)d_in[15];
    const float* Wts = (const float*)d_in[16];
    const float* Wtd = (const float*)d_in[17];
    const float* ats = (const float*)d_in[18];
    const float* atd = (const float*)d_in[19];
    const float* bt  = (const float*)d_in[20];
    const int* pp_src = (const int*)d_in[21];
    const int* pp_dst = (const int*)d_in[21] + E_PP;
    const int* pf_src = (const int*)d_in[22];
    const int* pf_dst = (const int*)d_in[23];
    float* out = (float*)d_out;

    char* wsp = (char*)d_ws;
    size_t off = 0;
    auto alloc = [&](size_t bytes) -> char* {
        char* p = wsp + off;
        off += (bytes + 255) & ~(size_t)255;
        return p;
    };
    ushort_t* hsb  = (ushort_t*)alloc(sizeof(ushort_t) * N_PANO * HID);
    ushort_t* linb = (ushort_t*)alloc(sizeof(ushort_t) * N_PANO * HID);
    uint_t* hh     = (uint_t*)alloc(sizeof(uint_t) * N_PANO * 64);
    ushort_t* hstb = (ushort_t*)alloc(sizeof(ushort_t) * N_PANO * OUT_C);
    int2* tmp_e    = (int2*)alloc(sizeof(int2) * E_UNI);
    float* es   = (float*)alloc(sizeof(float) * N_PANO);
    float* ed   = (float*)alloc(sizeof(float) * N_PANO);
    float* wed0 = (float*)alloc(sizeof(float) * HID);
    float* wed1 = (float*)alloc(sizeof(float) * HID);
    float* wedt = (float*)alloc(sizeof(float) * OUT_C);
    ushort_t* s0 = (ushort_t*)alloc(sizeof(ushort_t) * 128 * 128);
    ushort_t* l0 = (ushort_t*)alloc(sizeof(ushort_t) * 128 * 128);
    ushort_t* s1 = (ushort_t*)alloc(sizeof(ushort_t) * 128 * 128);
    ushort_t* l1 = (ushort_t*)alloc(sizeof(ushort_t) * 128 * 128);
    ushort_t* ts = (ushort_t*)alloc(sizeof(ushort_t) * 64 * 128);
    int* pcnt  = (int*)alloc(sizeof(int) * NBKT * NT_CNT);
    int* bbase = (int*)alloc(sizeof(int) * (NBKT + 1));
    int* P     = (int*)alloc(sizeof(int) * (N_UNI + 1));
    int* col_u = (int*)alloc(sizeof(int) * E_UNI);

    // L1: per-tile bucket counts + weight fragment-permute + wed matvecs
    csr_count_prep<<<NT_CNT + 288 + 80, 256, 0, stream>>>(
        pp_dst, pf_dst, pcnt, Ws0, Lw0, Ws1, Lw1, Wts,
        Wd0, ad0, Wd1, ad1, Wtd, atd, s0, l0, s1, l1, ts, wed0, wed1, wedt);

    // L2: coarse scatter (inline 2D prefix) || layer-0 dual GEMM (64-row tiles)
    scatter_gemm0<<<NT_CNT + NT_GEMM, 256, 0, stream>>>(
        pp_src, pp_dst, pf_src, pf_dst, pcnt, bbase, tmp_e,
        x_pano, s0, l0, hsb, linb, as0, es, wed0, ed);

    // L3: per-bucket counting sort -> P, col (1024 threads: 4x resident waves)
    csr_sort<<<NBKT, 1024, 0, stream>>>(tmp_e, bbase, P, col_u);

    // L4: layer-0 aggregate
    agg_pano7<<<cdiv(N_PANO, 8), 256, 0, stream>>>(P, col_u, es, ed, hsb, linb, b0, Lb0, hh, N_PANO);

    // L5: layer-1 dual GEMM (bf16 input = hh)
    gemm_mfma<128, true, false><<<NT_GEMM, 256, 0, stream>>>(
        nullptr, (const ushort_t*)hh, s1, l1, hsb, linb, as1, es, wed1, ed, N_PANO);

    // L6: layer-1 aggregate
    agg_pano7<<<cdiv(N_PANO, 8), 256, 0, stream>>>(P, col_u, es, ed, hsb, linb, b1, Lb1, hh, N_PANO);

    // L7: translate GEMM (C=64)
    gemm_mfma<64, false, false><<<NT_GEMM, 256, 0, stream>>>(
        nullptr, (const ushort_t*)hh, ts, nullptr, hstb, nullptr, ats, es, nullptr, nullptr, N_PANO);

    // L8: translate aggregate (pf ptr = P+50000, absolute into col_u)
    agg_fp5<<<cdiv(N_FP, 4), 256, 0, stream>>>(P + N_PANO, col_u, es, x_fp, wedt, hstb, bt, out, N_FP);
}

// Round 7
// 252.294 us; speedup vs baseline: 1.1529x; 1.0096x over previous
//
#include <hip/hip_runtime.h>
#include <hip/hip_bf16.h>
#include <math.h>

#define N_PANO 50000
#define N_FP   10000
#define N_UNI  60000   // unified dst id-space: pano [0,50000), fp mapped to 50000+d
#define HID    128
#define OUT_C  64
#define E_PP   800000
#define E_PF   50000
#define E_UNI  850000
#define NBKT   235     // cdiv(N_UNI, 256) coarse buckets
#define EPB    4096    // edges per tile in count/scatter (measured-best)
#define NT_CNT 208     // cdiv(E_UNI, EPB)
#define NT_GEMM 782    // cdiv(N_PANO, 64) -- 64-row tiles (R5: occupancy win)

typedef unsigned short ushort_t;
typedef unsigned int uint_t;
typedef __attribute__((ext_vector_type(8))) short short8;
typedef __attribute__((ext_vector_type(4))) float f32x4;

static inline int cdiv(int a, int b) { return (a + b - 1) / b; }

__device__ inline ushort_t f2bf(float x) {
    __hip_bfloat16 h = __float2bfloat16(x);   // RNE
    return *reinterpret_cast<ushort_t*>(&h);
}
__device__ inline float bfu2f(ushort_t u) {
    return __uint_as_float(((uint_t)u) << 16);
}
__device__ inline float bflo(uint_t u) { return __uint_as_float((u & 0xffffu) << 16); }
__device__ inline float bfhi(uint_t u) { return __uint_as_float(u & 0xffff0000u); }
__device__ inline f32x4 mfma16(short8 a, short8 b, f32x4 c) {
    return __builtin_amdgcn_mfma_f32_16x16x32_bf16(a, b, c, 0, 0, 0);
}

// ---------------- CSR stage 1: per-tile partial counts + weight prep (merged) ----------------
__global__ __launch_bounds__(256, 4) void csr_count_prep(
        const int* __restrict__ pp_dst, const int* __restrict__ pf_dst,
        int* __restrict__ pcnt,
        const float* __restrict__ Ws0, const float* __restrict__ Lw0,
        const float* __restrict__ Ws1, const float* __restrict__ Lw1,
        const float* __restrict__ Wts,
        const float* __restrict__ Wd0, const float* __restrict__ ad0,
        const float* __restrict__ Wd1, const float* __restrict__ ad1,
        const float* __restrict__ Wtd, const float* __restrict__ atd,
        ushort_t* s0, ushort_t* l0, ushort_t* s1, ushort_t* l1, ushort_t* ts,
        float* wed0, float* wed1, float* wedt) {
    __shared__ int hist[NBKT];
    const int tile = blockIdx.x, tid = threadIdx.x;
    if (tile < NT_CNT) {
        for (int t = tid; t < NBKT; t += 256) hist[t] = 0;
        __syncthreads();
        const int e0 = tile * EPB;
        #pragma unroll
        for (int u = 0; u < 16; ++u) {
            int e = e0 + u * 256 + tid;
            int d = -1;
            if (e < E_PP) d = pp_dst[e];
            else if (e < E_UNI) d = N_PANO + pf_dst[e - E_PP];
            if (d >= 0) atomicAdd(&hist[d >> 8], 1);
        }
        __syncthreads();
        for (int t = tid; t < NBKT; t += 256) pcnt[tile * NBKT + t] = hist[t];
    } else if (tile < NT_CNT + 288) {
        int i = (tile - NT_CNT) * 256 + tid;
        const float* W; ushort_t* oh;
        int d, NIc, Cc;
        if (i < 65536) {
            int m = i >> 14; d = i & 16383;
            W = (m == 0) ? Ws0 : (m == 1) ? Lw0 : (m == 2) ? Ws1 : Lw1;
            oh = (m == 0) ? s0 : (m == 1) ? l0 : (m == 2) ? s1 : l1;
            NIc = 8; Cc = 128;
        } else if (i < 73728) {
            d = i - 65536; W = Wts; oh = ts;
            NIc = 4; Cc = 64;
        } else return;
        int j = d & 7, l = (d >> 3) & 63;
        int kcl = (d >> 9) & 1;
        int ni = (d >> 10) & (NIc - 1);
        int p = d >> (10 + (NIc == 8 ? 3 : 2));
        int kc = p * 2 + kcl;
        int n = ni * 16 + (l & 15);
        int k = kc * 32 + (l >> 4) * 8 + j;
        oh[d] = f2bf(W[k * Cc + n]);
    } else {
        int r = (tile - NT_CNT - 288) * 4 + (tid >> 6);
        int lane = tid & 63;
        const float* W; const float* a; float* o; int rr, C;
        if (r < 128)      { W = Wd0; a = ad0; o = wed0; rr = r;       C = 128; }
        else if (r < 256) { W = Wd1; a = ad1; o = wed1; rr = r - 128; C = 128; }
        else if (r < 320) { W = Wtd; a = atd; o = wedt; rr = r - 256; C = 64;  }
        else return;
        float s = 0.f;
        for (int j = lane; j < C; j += 64) s += W[rr * C + j] * a[j];
        #pragma unroll
        for (int off = 32; off; off >>= 1) s += __shfl_down(s, off, 64);
        if (lane == 0) o[rr] = s;
    }
}

// ---------------- GEMM body: 64-row tiles, one 16-row MFMA strip per wave, ----------------
// barrier-free (B fragments loaded straight from global in fragment order; L2-resident).
template <int CN, bool DUAL, bool FP32IN>
__device__ void gemm_body(int tile,
                          const float* __restrict__ Xf, const ushort_t* __restrict__ Xh,
                          const ushort_t* __restrict__ W1, const ushort_t* __restrict__ W2,
                          ushort_t* __restrict__ Y1, ushort_t* __restrict__ Y2,
                          const float* __restrict__ avec, float* __restrict__ evec,
                          const float* __restrict__ wed, float* __restrict__ edv, int N) {
    constexpr int NI = CN / 16;
    constexpr int SLAB = NI * 1024;
    const int tid = threadIdx.x;
    const int w = tid >> 6, l = tid & 63;
    const int col = l & 15, q = l >> 4;
    const int row0 = tile * 64 + w * 16;
    f32x4 acc1[NI];
    f32x4 acc2[DUAL ? NI : 1];
    #pragma unroll
    for (int ni = 0; ni < NI; ++ni)
        #pragma unroll
        for (int r = 0; r < 4; ++r) acc1[ni][r] = 0.f;
    if (DUAL) {
        #pragma unroll
        for (int ni = 0; ni < NI; ++ni)
            #pragma unroll
            for (int r = 0; r < 4; ++r) acc2[ni][r] = 0.f;
    }
    float ped = 0.f;

    #pragma unroll
    for (int p = 0; p < 2; ++p) {
        #pragma unroll
        for (int kcl = 0; kcl < 2; ++kcl) {
            const int kc = p * 2 + kcl;
            const int k0 = kc * 32 + q * 8;
            short8 Ah;
            const int arow = row0 + col;
            if (FP32IN) {
                float xv[8];
                if (arow < N) {
                    float4 a0 = *(const float4*)&Xf[(size_t)arow * 128 + k0];
                    float4 a1 = *(const float4*)&Xf[(size_t)arow * 128 + k0 + 4];
                    xv[0] = a0.x; xv[1] = a0.y; xv[2] = a0.z; xv[3] = a0.w;
                    xv[4] = a1.x; xv[5] = a1.y; xv[6] = a1.z; xv[7] = a1.w;
                } else {
                    #pragma unroll
                    for (int j = 0; j < 8; ++j) xv[j] = 0.f;
                }
                #pragma unroll
                for (int j = 0; j < 8; ++j) Ah[j] = (short)f2bf(xv[j]);
                if (wed) {
                    float4 w0 = *(const float4*)&wed[k0];
                    float4 w1 = *(const float4*)&wed[k0 + 4];
                    ped += xv[0] * w0.x + xv[1] * w0.y + xv[2] * w0.z + xv[3] * w0.w
                         + xv[4] * w1.x + xv[5] * w1.y + xv[6] * w1.z + xv[7] * w1.w;
                }
            } else {
                if (arow < N) {
                    Ah = *(const short8*)&Xh[(size_t)arow * 128 + k0];
                } else {
                    #pragma unroll
                    for (int j = 0; j < 8; ++j) Ah[j] = 0;
                }
                if (wed) {
                    float4 w0 = *(const float4*)&wed[k0];
                    float4 w1 = *(const float4*)&wed[k0 + 4];
                    float wv[8] = {w0.x, w0.y, w0.z, w0.w, w1.x, w1.y, w1.z, w1.w};
                    #pragma unroll
                    for (int j = 0; j < 8; ++j)
                        ped += bfu2f((ushort_t)Ah[j]) * wv[j];
                }
            }
            #pragma unroll
            for (int ni = 0; ni < NI; ++ni) {
                const int gb = p * SLAB + ((ni * 2 + kcl) * 64 + l) * 8;
                short8 B1 = *(const short8*)&W1[gb];
                acc1[ni] = mfma16(Ah, B1, acc1[ni]);
                if (DUAL) {
                    short8 B2 = *(const short8*)&W2[gb];
                    acc2[ni] = mfma16(Ah, B2, acc2[ni]);
                }
            }
        }
    }

    #pragma unroll
    for (int ni = 0; ni < NI; ++ni) {
        #pragma unroll
        for (int r = 0; r < 4; ++r) {
            int mrow = row0 + q * 4 + r;
            if (mrow < N) {
                Y1[(size_t)mrow * CN + ni * 16 + col] = f2bf(acc1[ni][r]);
                if (DUAL) Y2[(size_t)mrow * CN + ni * 16 + col] = f2bf(acc2[ni][r]);
            }
        }
    }
    float av[NI];
    #pragma unroll
    for (int ni = 0; ni < NI; ++ni) av[ni] = avec[ni * 16 + col];
    #pragma unroll
    for (int r = 0; r < 4; ++r) {
        float pp = 0.f;
        #pragma unroll
        for (int ni = 0; ni < NI; ++ni) pp += acc1[ni][r] * av[ni];
        pp += __shfl_xor(pp, 1, 64);
        pp += __shfl_xor(pp, 2, 64);
        pp += __shfl_xor(pp, 4, 64);
        pp += __shfl_xor(pp, 8, 64);
        int mrow = row0 + q * 4 + r;
        if (col == 0 && mrow < N) evec[mrow] = pp;
    }
    if (wed) {
        ped += __shfl_xor(ped, 16, 64);
        ped += __shfl_xor(ped, 32, 64);
        const int arow = row0 + col;
        if (q == 0 && arow < N) edv[arow] = ped;
    }
}

// ---------------- scatter body: inline 2D prefix, batch-8 ILP on the pcnt chain ----------------
__device__ void scatter_body(int tile, char* smem,
                             const int* __restrict__ pp_src, const int* __restrict__ pp_dst,
                             const int* __restrict__ pf_src, const int* __restrict__ pf_dst,
                             const int* __restrict__ pcnt, int* __restrict__ bbase_out,
                             int2* __restrict__ tmp) {
    int* base2 = (int*)smem;            // [NBKT]
    int* cur   = base2 + NBKT;          // [NBKT]
    int* wsum  = cur + NBKT;            // [4]
    const int tid = threadIdx.x, lane = tid & 63, wv = tid >> 6;
    int rowsum = 0, myprefix = 0;
    if (tid < NBKT) {
        const int* pb = pcnt + tid;
        int t = 0;
        for (; t + 8 <= NT_CNT; t += 8) {
            int c0 = pb[(t + 0) * NBKT], c1 = pb[(t + 1) * NBKT];
            int c2 = pb[(t + 2) * NBKT], c3 = pb[(t + 3) * NBKT];
            int c4 = pb[(t + 4) * NBKT], c5 = pb[(t + 5) * NBKT];
            int c6 = pb[(t + 6) * NBKT], c7 = pb[(t + 7) * NBKT];
            rowsum += c0 + c1 + c2 + c3 + c4 + c5 + c6 + c7;
            myprefix += ((t + 0 < tile) ? c0 : 0) + ((t + 1 < tile) ? c1 : 0)
                      + ((t + 2 < tile) ? c2 : 0) + ((t + 3 < tile) ? c3 : 0)
                      + ((t + 4 < tile) ? c4 : 0) + ((t + 5 < tile) ? c5 : 0)
                      + ((t + 6 < tile) ? c6 : 0) + ((t + 7 < tile) ? c7 : 0);
        }
        for (; t < NT_CNT; ++t) {
            int c = pb[t * NBKT];
            rowsum += c;
            if (t < tile) myprefix += c;
        }
    }
    // exclusive scan of rowsum over buckets -> bucket base
    int v = (tid < NBKT) ? rowsum : 0;
    int incl = v;
    #pragma unroll
    for (int off = 1; off < 64; off <<= 1) {
        int t = __shfl_up(incl, off, 64);
        if (lane >= off) incl += t;
    }
    if (lane == 63) wsum[wv] = incl;
    __syncthreads();
    if (tid == 0) {
        int run = 0;
        #pragma unroll
        for (int w = 0; w < 4; ++w) { int t = wsum[w]; wsum[w] = run; run += t; }
    }
    __syncthreads();
    int bexcl = wsum[wv] + incl - v;
    if (tid < NBKT) {
        base2[tid] = bexcl + myprefix;
        cur[tid] = 0;
        if (tile == 0) bbase_out[tid] = bexcl;
    }
    if (tile == 0 && tid == 0) bbase_out[NBKT] = E_UNI;
    __syncthreads();
    const int e0 = tile * EPB;
    #pragma unroll
    for (int u = 0; u < 16; ++u) {
        int e = e0 + u * 256 + tid;
        int d = -1, s = 0;
        if (e < E_PP)       { d = pp_dst[e];                 s = pp_src[e]; }
        else if (e < E_UNI) { d = N_PANO + pf_dst[e - E_PP]; s = pf_src[e - E_PP]; }
        if (d >= 0) {
            int b = d >> 8;
            int p = base2[b] + atomicAdd(&cur[b], 1);
            tmp[p] = make_int2(s, d);
        }
    }
}

// ---------------- merged launch: scatter (tiles 0..207) || layer-0 dual GEMM ----------------
__global__ __launch_bounds__(256, 4) void scatter_gemm0(
        const int* __restrict__ pp_src, const int* __restrict__ pp_dst,
        const int* __restrict__ pf_src, const int* __restrict__ pf_dst,
        const int* __restrict__ pcnt, int* __restrict__ bbase_out, int2* __restrict__ tmp,
        const float* __restrict__ x_pano,
        const ushort_t* __restrict__ s0, const ushort_t* __restrict__ l0,
        ushort_t* __restrict__ hsb, ushort_t* __restrict__ linb,
        const float* __restrict__ as0, float* __restrict__ es,
        const float* __restrict__ wed0, float* __restrict__ ed) {
    __shared__ __align__(16) char smem[(2 * NBKT + 4) * 4];
    if (blockIdx.x < NT_CNT)
        scatter_body(blockIdx.x, smem, pp_src, pp_dst, pf_src, pf_dst, pcnt, bbase_out, tmp);
    else
        gemm_body<128, true, true>(blockIdx.x - NT_CNT, x_pano, nullptr, s0, l0,
                                   hsb, linb, as0, es, wed0, ed, N_PANO);
}

// ---------------- standalone GEMM kernel (layers 1 and translate), barrier-free ----------------
template <int CN, bool DUAL, bool FP32IN>
__global__ __launch_bounds__(256, 4) void gemm_mfma(const float* __restrict__ Xf,
                                                 const ushort_t* __restrict__ Xh,
                                                 const ushort_t* __restrict__ W1, const ushort_t* __restrict__ W2,
                                                 ushort_t* __restrict__ Y1, ushort_t* __restrict__ Y2,
                                                 const float* __restrict__ avec, float* __restrict__ evec,
                                                 const float* __restrict__ wed, float* __restrict__ edv,
                                                 int N) {
    gemm_body<CN, DUAL, FP32IN>(blockIdx.x, Xf, Xh, W1, W2, Y1, Y2, avec, evec, wed, edv, N);
}

// ---------------- CSR stage 4: per-bucket counting sort in LDS -> P, col ----------------
__global__ __launch_bounds__(1024, 1) void csr_sort(const int2* __restrict__ tmp,
                                                    const int* __restrict__ bbase,
                                                    int* __restrict__ ptr, int* __restrict__ col) {
    __shared__ int hist[256];
    __shared__ int wsum[4];
    const int b = blockIdx.x, tid = threadIdx.x, lane = tid & 63, wv = tid >> 6;
    const int B0 = bbase[b], B1 = bbase[b + 1];
    if (tid < 256) hist[tid] = 0;
    __syncthreads();
    for (int e = B0 + tid; e < B1; e += 1024) atomicAdd(&hist[tmp[e].y & 255], 1);
    __syncthreads();
    int v = (tid < 256) ? hist[tid] : 0;
    int incl = v;
    #pragma unroll
    for (int off = 1; off < 64; off <<= 1) {
        int t = __shfl_up(incl, off, 64);
        if (lane >= off) incl += t;
    }
    if (lane == 63 && tid < 256) wsum[wv] = incl;
    __syncthreads();
    if (tid == 0) {
        int run = 0;
        #pragma unroll
        for (int w = 0; w < 4; ++w) { int t = wsum[w]; wsum[w] = run; run += t; }
    }
    __syncthreads();
    if (tid < 256) {
        int excl = wsum[wv] + incl - v;
        int dg = b * 256 + tid;
        if (dg < N_UNI) ptr[dg] = B0 + excl;
        hist[tid] = excl;
    }
    if (b == NBKT - 1 && tid == 0) ptr[N_UNI] = E_UNI;
    __syncthreads();
    for (int e = B0 + tid; e < B1; e += 1024) {
        int2 ed2 = tmp[e];
        int p = B0 + atomicAdd(&hist[ed2.y & 255], 1);
        col[p] = ed2.x;
    }
}

// ---------------- GAT aggregate (pano): ONE node per wave ----------------
// R5/R6 proved this pipeline is latency-bound and responds to wave count. 2-nodes/wave
// meant each wave ran two serial accumulation phases; 1-node/wave doubles resident
// parallelism (25K -> 50K waves), halves the per-wave latency chain, and drops the
// B-side registers.
__global__ __launch_bounds__(256, 4) void agg_pano8(const int* __restrict__ ptr, const int* __restrict__ col,
                                                    const float* __restrict__ es, const float* __restrict__ ed,
                                                    const ushort_t* __restrict__ hsb, const ushort_t* __restrict__ linb,
                                                    const float* __restrict__ b, const float* __restrict__ Lb,
                                                    uint_t* __restrict__ hh, int N) {
    int lane = threadIdx.x & 63, wid = threadIdx.x >> 6;
    int node = blockIdx.x * 4 + wid;
    if (node >= N) return;
    int beg = ptr[node], end = ptr[node + 1];
    float edn = ed[node];
    const int half = lane >> 5, hl = lane & 31;
    float a0 = 0.f, a1 = 0.f, a2 = 0.f, a3 = 0.f, den = 0.f;
    for (int base = beg; base < end; base += 64) {
        int m = end - base; m = m > 64 ? 64 : m;
        int s = 0;
        float w = 0.f;
        if (lane < m) {
            s = col[base + lane];
            float e = es[s] + edn;
            e = fmaxf(e, 0.2f * e);
            w = __expf(e);
        }
        den += w;
        int mp = (m + 1) & ~1;
        int t = 0;
        for (; t + 8 <= mp; t += 8) {
            int i0 = t + half, i1 = t + 2 + half, i2 = t + 4 + half, i3 = t + 6 + half;
            int s0 = __shfl(s, i0, 64), s1 = __shfl(s, i1, 64);
            int s2 = __shfl(s, i2, 64), s3 = __shfl(s, i3, 64);
            float w0 = __shfl(w, i0, 64), w1 = __shfl(w, i1, 64);
            float w2 = __shfl(w, i2, 64), w3 = __shfl(w, i3, 64);
            uint2 h0 = *(const uint2*)&hsb[(size_t)s0 * 128 + hl * 4];
            uint2 h1 = *(const uint2*)&hsb[(size_t)s1 * 128 + hl * 4];
            uint2 h2 = *(const uint2*)&hsb[(size_t)s2 * 128 + hl * 4];
            uint2 h3 = *(const uint2*)&hsb[(size_t)s3 * 128 + hl * 4];
            a0 += w0 * bflo(h0.x) + w1 * bflo(h1.x) + w2 * bflo(h2.x) + w3 * bflo(h3.x);
            a1 += w0 * bfhi(h0.x) + w1 * bfhi(h1.x) + w2 * bfhi(h2.x) + w3 * bfhi(h3.x);
            a2 += w0 * bflo(h0.y) + w1 * bflo(h1.y) + w2 * bflo(h2.y) + w3 * bflo(h3.y);
            a3 += w0 * bfhi(h0.y) + w1 * bfhi(h1.y) + w2 * bfhi(h2.y) + w3 * bfhi(h3.y);
        }
        for (; t < mp; t += 2) {
            int i0 = t + half;
            int s0 = __shfl(s, i0, 64);
            float w0 = __shfl(w, i0, 64);
            uint2 h0 = *(const uint2*)&hsb[(size_t)s0 * 128 + hl * 4];
            a0 += w0 * bflo(h0.x);
            a1 += w0 * bfhi(h0.x);
            a2 += w0 * bflo(h0.y);
            a3 += w0 * bfhi(h0.y);
        }
    }
    a0 += __shfl_xor(a0, 32, 64); a1 += __shfl_xor(a1, 32, 64);
    a2 += __shfl_xor(a2, 32, 64); a3 += __shfl_xor(a3, 32, 64);
    #pragma unroll
    for (int off = 1; off < 64; off <<= 1) den += __shfl_xor(den, off, 64);
    float inv = (end > beg) ? (1.f / den) : 0.f;
    if (half == 0) {
        uint2 lv = *(const uint2*)&linb[(size_t)node * 128 + hl * 4];
        float4 bb = *(const float4*)&b[hl * 4];
        float4 lb4 = *(const float4*)&Lb[hl * 4];
        float o0 = fmaxf(a0 * inv + bb.x + bflo(lv.x) + lb4.x, 0.f);
        float o1 = fmaxf(a1 * inv + bb.y + bfhi(lv.x) + lb4.y, 0.f);
        float o2 = fmaxf(a2 * inv + bb.z + bflo(lv.y) + lb4.z, 0.f);
        float o3 = fmaxf(a3 * inv + bb.w + bfhi(lv.y) + lb4.w, 0.f);
        uint2 ov;
        ov.x = (uint_t)f2bf(o0) | ((uint_t)f2bf(o1) << 16);
        ov.y = (uint_t)f2bf(o2) | ((uint_t)f2bf(o3) << 16);
        *(uint2*)&hh[(size_t)node * 64 + hl * 2] = ov;
    }
}

// ---------------- translate aggregate (C=64), fused ed matvec ----------------
__global__ __launch_bounds__(256, 4) void agg_fp5(const int* __restrict__ ptr, const int* __restrict__ col,
                                               const float* __restrict__ es, const float* __restrict__ x_fp,
                                               const float* __restrict__ wedt,
                                               const ushort_t* __restrict__ hsb, const float* __restrict__ bt,
                                               float* __restrict__ out, int N) {
    int lane = threadIdx.x & 63, wid = threadIdx.x >> 6;
    int node = blockIdx.x * 4 + wid;
    if (node >= N) return;
    int beg = ptr[node], end = ptr[node + 1];
    float edn = x_fp[(size_t)node * 64 + lane] * wedt[lane];
    #pragma unroll
    for (int off = 1; off < 64; off <<= 1) edn += __shfl_xor(edn, off, 64);
    float acc = 0.f, denp = 0.f;
    for (int base = beg; base < end; base += 64) {
        int m = min(64, end - base);
        int s = 0;
        float wgt = 0.f;
        if (lane < m) {
            s = col[base + lane];
            float e = es[s] + edn;
            e = fmaxf(e, 0.2f * e);
            wgt = __expf(e);
        }
        denp += wgt;
        int u = 0;
        for (; u + 4 <= m; u += 4) {
            int s0 = __shfl(s, u, 64), s1 = __shfl(s, u + 1, 64);
            int s2 = __shfl(s, u + 2, 64), s3 = __shfl(s, u + 3, 64);
            float w0 = __shfl(wgt, u, 64), w1 = __shfl(wgt, u + 1, 64);
            float w2 = __shfl(wgt, u + 2, 64), w3 = __shfl(wgt, u + 3, 64);
            float h0 = bfu2f(hsb[(size_t)s0 * 64 + lane]);
            float h1 = bfu2f(hsb[(size_t)s1 * 64 + lane]);
            float h2 = bfu2f(hsb[(size_t)s2 * 64 + lane]);
            float h3 = bfu2f(hsb[(size_t)s3 * 64 + lane]);
            acc += w0 * h0 + w1 * h1 + w2 * h2 + w3 * h3;
        }
        for (; u < m; ++u) {
            int su = __shfl(s, u, 64);
            float wu = __shfl(wgt, u, 64);
            acc += wu * bfu2f(hsb[(size_t)su * 64 + lane]);
        }
    }
    float den = denp;
    #pragma unroll
    for (int off = 1; off < 64; off <<= 1) den += __shfl_xor(den, off, 64);
    float inv = (end > beg) ? (1.f / den) : 0.f;
    out[(size_t)node * 64 + lane] = acc * inv + bt[lane];
}

extern "C" void kernel_launch(void* const* d_in, const int* in_sizes, int n_in,
                              void* d_out, int out_size, void* d_ws, size_t ws_size,
                              hipStream_t stream) {
    const float* x_pano = (const float*)d_in[0];
    const float* x_fp   = (const float*)d_in[1];
    const float* Ws0 = (const float*)d_in[2];
    const float* Wd0 = (const float*)d_in[3];
    const float* as0 = (const float*)d_in[4];
    const float* ad0 = (const float*)d_in[5];
    const float* b0  = (const float*)d_in[6];
    const float* Lw0 = (const float*)d_in[7];
    const float* Lb0 = (const float*)d_in[8];
    const float* Ws1 = (const float*)d_in[9];
    const float* Wd1 = (const float*)d_in[10];
    const float* as1 = (const float*)d_in[11];
    const float* ad1 = (const float*)d_in[12];
    const float* b1  = (const float*)d_in[13];
    const float* Lw1 = (const float*)d_in[14];
    const float* Lb1 = (const float*)d_in[15];
    const float* Wts = (const float*)d_in[16];
    const float* Wtd = (const float*)d_in[17];
    const float* ats = (const float*)d_in[18];
    const float* atd = (const float*)d_in[19];
    const float* bt  = (const float*)d_in[20];
    const int* pp_src = (const int*)d_in[21];
    const int* pp_dst = (const int*)d_in[21] + E_PP;
    const int* pf_src = (const int*)d_in[22];
    const int* pf_dst = (const int*)d_in[23];
    float* out = (float*)d_out;

    char* wsp = (char*)d_ws;
    size_t off = 0;
    auto alloc = [&](size_t bytes) -> char* {
        char* p = wsp + off;
        off += (bytes + 255) & ~(size_t)255;
        return p;
    };
    ushort_t* hsb  = (ushort_t*)alloc(sizeof(ushort_t) * N_PANO * HID);
    ushort_t* linb = (ushort_t*)alloc(sizeof(ushort_t) * N_PANO * HID);
    uint_t* hh     = (uint_t*)alloc(sizeof(uint_t) * N_PANO * 64);
    ushort_t* hstb = (ushort_t*)alloc(sizeof(ushort_t) * N_PANO * OUT_C);
    int2* tmp_e    = (int2*)alloc(sizeof(int2) * E_UNI);
    float* es   = (float*)alloc(sizeof(float) * N_PANO);
    float* ed   = (float*)alloc(sizeof(float) * N_PANO);
    float* wed0 = (float*)alloc(sizeof(float) * HID);
    float* wed1 = (float*)alloc(sizeof(float) * HID);
    float* wedt = (float*)alloc(sizeof(float) * OUT_C);
    ushort_t* s0 = (ushort_t*)alloc(sizeof(ushort_t) * 128 * 128);
    ushort_t* l0 = (ushort_t*)alloc(sizeof(ushort_t) * 128 * 128);
    ushort_t* s1 = (ushort_t*)alloc(sizeof(ushort_t) * 128 * 128);
    ushort_t* l1 = (ushort_t*)alloc(sizeof(ushort_t) * 128 * 128);
    ushort_t* ts = (ushort_t*)alloc(sizeof(ushort_t) * 64 * 128);
    int* pcnt  = (int*)alloc(sizeof(int) * NBKT * NT_CNT);
    int* bbase = (int*)alloc(sizeof(int) * (NBKT + 1));
    int* P     = (int*)alloc(sizeof(int) * (N_UNI + 1));
    int* col_u = (int*)alloc(sizeof(int) * E_UNI);

    // L1: per-tile bucket counts + weight fragment-permute + wed matvecs
    csr_count_prep<<<NT_CNT + 288 + 80, 256, 0, stream>>>(
        pp_dst, pf_dst, pcnt, Ws0, Lw0, Ws1, Lw1, Wts,
        Wd0, ad0, Wd1, ad1, Wtd, atd, s0, l0, s1, l1, ts, wed0, wed1, wedt);

    // L2: coarse scatter (inline 2D prefix) || layer-0 dual GEMM (64-row tiles)
    scatter_gemm0<<<NT_CNT + NT_GEMM, 256, 0, stream>>>(
        pp_src, pp_dst, pf_src, pf_dst, pcnt, bbase, tmp_e,
        x_pano, s0, l0, hsb, linb, as0, es, wed0, ed);

    // L3: per-bucket counting sort -> P, col (1024 threads: 4x resident waves)
    csr_sort<<<NBKT, 1024, 0, stream>>>(tmp_e, bbase, P, col_u);

    // L4: layer-0 aggregate (1 node per wave)
    agg_pano8<<<cdiv(N_PANO, 4), 256, 0, stream>>>(P, col_u, es, ed, hsb, linb, b0, Lb0, hh, N_PANO);

    // L5: layer-1 dual GEMM (bf16 input = hh)
    gemm_mfma<128, true, false><<<NT_GEMM, 256, 0, stream>>>(
        nullptr, (const ushort_t*)hh, s1, l1, hsb, linb, as1, es, wed1, ed, N_PANO);

    // L6: layer-1 aggregate (1 node per wave)
    agg_pano8<<<cdiv(N_PANO, 4), 256, 0, stream>>>(P, col_u, es, ed, hsb, linb, b1, Lb1, hh, N_PANO);

    // L7: translate GEMM (C=64)
    gemm_mfma<64, false, false><<<NT_GEMM, 256, 0, stream>>>(
        nullptr, (const ushort_t*)hh, ts, nullptr, hstb, nullptr, ats, es, nullptr, nullptr, N_PANO);

    // L8: translate aggregate (pf ptr = P+50000, absolute into col_u)
    agg_fp5<<<cdiv(N_FP, 4), 256, 0, stream>>>(P + N_PANO, col_u, es, x_fp, wedt, hstb, bt, out, N_FP);
}

// Round 8
// 250.062 us; speedup vs baseline: 1.1632x; 1.0089x over previous
//
#include <hip/hip_runtime.h>
#include <hip/hip_bf16.h>
#include <math.h>

#define N_PANO 50000
#define N_FP   10000
#define N_UNI  60000   // unified dst id-space: pano [0,50000), fp mapped to 50000+d
#define HID    128
#define OUT_C  64
#define E_PP   800000
#define E_PF   50000
#define E_UNI  850000
#define NBKT   235     // cdiv(N_UNI, 256) coarse buckets
#define EPB    4096    // edges per tile in count/scatter (measured-best)
#define NT_CNT 208     // cdiv(E_UNI, EPB)
#define NT_GEMM 782    // cdiv(N_PANO, 64) -- 64-row tiles (R5: occupancy win)

typedef unsigned short ushort_t;
typedef unsigned int uint_t;
typedef __attribute__((ext_vector_type(8))) short short8;
typedef __attribute__((ext_vector_type(4))) float f32x4;

static inline int cdiv(int a, int b) { return (a + b - 1) / b; }

__device__ inline ushort_t f2bf(float x) {
    __hip_bfloat16 h = __float2bfloat16(x);   // RNE
    return *reinterpret_cast<ushort_t*>(&h);
}
__device__ inline float bfu2f(ushort_t u) {
    return __uint_as_float(((uint_t)u) << 16);
}
__device__ inline float bflo(uint_t u) { return __uint_as_float((u & 0xffffu) << 16); }
__device__ inline float bfhi(uint_t u) { return __uint_as_float(u & 0xffff0000u); }
__device__ inline f32x4 mfma16(short8 a, short8 b, f32x4 c) {
    return __builtin_amdgcn_mfma_f32_16x16x32_bf16(a, b, c, 0, 0, 0);
}

// ---------------- CSR stage 1: per-tile partial counts + weight prep (merged) ----------------
__global__ __launch_bounds__(256, 4) void csr_count_prep(
        const int* __restrict__ pp_dst, const int* __restrict__ pf_dst,
        int* __restrict__ pcnt,
        const float* __restrict__ Ws0, const float* __restrict__ Lw0,
        const float* __restrict__ Ws1, const float* __restrict__ Lw1,
        const float* __restrict__ Wts,
        const float* __restrict__ Wd0, const float* __restrict__ ad0,
        const float* __restrict__ Wd1, const float* __restrict__ ad1,
        const float* __restrict__ Wtd, const float* __restrict__ atd,
        ushort_t* s0, ushort_t* l0, ushort_t* s1, ushort_t* l1, ushort_t* ts,
        float* wed0, float* wed1, float* wedt) {
    __shared__ int hist[NBKT];
    const int tile = blockIdx.x, tid = threadIdx.x;
    if (tile < NT_CNT) {
        for (int t = tid; t < NBKT; t += 256) hist[t] = 0;
        __syncthreads();
        const int e0 = tile * EPB;
        #pragma unroll
        for (int u = 0; u < 16; ++u) {
            int e = e0 + u * 256 + tid;
            int d = -1;
            if (e < E_PP) d = pp_dst[e];
            else if (e < E_UNI) d = N_PANO + pf_dst[e - E_PP];
            if (d >= 0) atomicAdd(&hist[d >> 8], 1);
        }
        __syncthreads();
        for (int t = tid; t < NBKT; t += 256) pcnt[tile * NBKT + t] = hist[t];
    } else if (tile < NT_CNT + 288) {
        int i = (tile - NT_CNT) * 256 + tid;
        const float* W; ushort_t* oh;
        int d, NIc, Cc;
        if (i < 65536) {
            int m = i >> 14; d = i & 16383;
            W = (m == 0) ? Ws0 : (m == 1) ? Lw0 : (m == 2) ? Ws1 : Lw1;
            oh = (m == 0) ? s0 : (m == 1) ? l0 : (m == 2) ? s1 : l1;
            NIc = 8; Cc = 128;
        } else if (i < 73728) {
            d = i - 65536; W = Wts; oh = ts;
            NIc = 4; Cc = 64;
        } else return;
        int j = d & 7, l = (d >> 3) & 63;
        int kcl = (d >> 9) & 1;
        int ni = (d >> 10) & (NIc - 1);
        int p = d >> (10 + (NIc == 8 ? 3 : 2));
        int kc = p * 2 + kcl;
        int n = ni * 16 + (l & 15);
        int k = kc * 32 + (l >> 4) * 8 + j;
        oh[d] = f2bf(W[k * Cc + n]);
    } else {
        int r = (tile - NT_CNT - 288) * 4 + (tid >> 6);
        int lane = tid & 63;
        const float* W; const float* a; float* o; int rr, C;
        if (r < 128)      { W = Wd0; a = ad0; o = wed0; rr = r;       C = 128; }
        else if (r < 256) { W = Wd1; a = ad1; o = wed1; rr = r - 128; C = 128; }
        else if (r < 320) { W = Wtd; a = atd; o = wedt; rr = r - 256; C = 64;  }
        else return;
        float s = 0.f;
        for (int j = lane; j < C; j += 64) s += W[rr * C + j] * a[j];
        #pragma unroll
        for (int off = 32; off; off >>= 1) s += __shfl_down(s, off, 64);
        if (lane == 0) o[rr] = s;
    }
}

// ---------------- GEMM body: 64-row tiles, one 16-row MFMA strip per wave, ----------------
// barrier-free (B fragments loaded straight from global in fragment order; L2-resident).
template <int CN, bool DUAL, bool FP32IN>
__device__ void gemm_body(int tile,
                          const float* __restrict__ Xf, const ushort_t* __restrict__ Xh,
                          const ushort_t* __restrict__ W1, const ushort_t* __restrict__ W2,
                          ushort_t* __restrict__ Y1, ushort_t* __restrict__ Y2,
                          const float* __restrict__ avec, float* __restrict__ evec,
                          const float* __restrict__ wed, float* __restrict__ edv, int N) {
    constexpr int NI = CN / 16;
    constexpr int SLAB = NI * 1024;
    const int tid = threadIdx.x;
    const int w = tid >> 6, l = tid & 63;
    const int col = l & 15, q = l >> 4;
    const int row0 = tile * 64 + w * 16;
    f32x4 acc1[NI];
    f32x4 acc2[DUAL ? NI : 1];
    #pragma unroll
    for (int ni = 0; ni < NI; ++ni)
        #pragma unroll
        for (int r = 0; r < 4; ++r) acc1[ni][r] = 0.f;
    if (DUAL) {
        #pragma unroll
        for (int ni = 0; ni < NI; ++ni)
            #pragma unroll
            for (int r = 0; r < 4; ++r) acc2[ni][r] = 0.f;
    }
    float ped = 0.f;

    #pragma unroll
    for (int p = 0; p < 2; ++p) {
        #pragma unroll
        for (int kcl = 0; kcl < 2; ++kcl) {
            const int kc = p * 2 + kcl;
            const int k0 = kc * 32 + q * 8;
            short8 Ah;
            const int arow = row0 + col;
            if (FP32IN) {
                float xv[8];
                if (arow < N) {
                    float4 a0 = *(const float4*)&Xf[(size_t)arow * 128 + k0];
                    float4 a1 = *(const float4*)&Xf[(size_t)arow * 128 + k0 + 4];
                    xv[0] = a0.x; xv[1] = a0.y; xv[2] = a0.z; xv[3] = a0.w;
                    xv[4] = a1.x; xv[5] = a1.y; xv[6] = a1.z; xv[7] = a1.w;
                } else {
                    #pragma unroll
                    for (int j = 0; j < 8; ++j) xv[j] = 0.f;
                }
                #pragma unroll
                for (int j = 0; j < 8; ++j) Ah[j] = (short)f2bf(xv[j]);
                if (wed) {
                    float4 w0 = *(const float4*)&wed[k0];
                    float4 w1 = *(const float4*)&wed[k0 + 4];
                    ped += xv[0] * w0.x + xv[1] * w0.y + xv[2] * w0.z + xv[3] * w0.w
                         + xv[4] * w1.x + xv[5] * w1.y + xv[6] * w1.z + xv[7] * w1.w;
                }
            } else {
                if (arow < N) {
                    Ah = *(const short8*)&Xh[(size_t)arow * 128 + k0];
                } else {
                    #pragma unroll
                    for (int j = 0; j < 8; ++j) Ah[j] = 0;
                }
                if (wed) {
                    float4 w0 = *(const float4*)&wed[k0];
                    float4 w1 = *(const float4*)&wed[k0 + 4];
                    float wv[8] = {w0.x, w0.y, w0.z, w0.w, w1.x, w1.y, w1.z, w1.w};
                    #pragma unroll
                    for (int j = 0; j < 8; ++j)
                        ped += bfu2f((ushort_t)Ah[j]) * wv[j];
                }
            }
            #pragma unroll
            for (int ni = 0; ni < NI; ++ni) {
                const int gb = p * SLAB + ((ni * 2 + kcl) * 64 + l) * 8;
                short8 B1 = *(const short8*)&W1[gb];
                acc1[ni] = mfma16(Ah, B1, acc1[ni]);
                if (DUAL) {
                    short8 B2 = *(const short8*)&W2[gb];
                    acc2[ni] = mfma16(Ah, B2, acc2[ni]);
                }
            }
        }
    }

    #pragma unroll
    for (int ni = 0; ni < NI; ++ni) {
        #pragma unroll
        for (int r = 0; r < 4; ++r) {
            int mrow = row0 + q * 4 + r;
            if (mrow < N) {
                Y1[(size_t)mrow * CN + ni * 16 + col] = f2bf(acc1[ni][r]);
                if (DUAL) Y2[(size_t)mrow * CN + ni * 16 + col] = f2bf(acc2[ni][r]);
            }
        }
    }
    float av[NI];
    #pragma unroll
    for (int ni = 0; ni < NI; ++ni) av[ni] = avec[ni * 16 + col];
    #pragma unroll
    for (int r = 0; r < 4; ++r) {
        float pp = 0.f;
        #pragma unroll
        for (int ni = 0; ni < NI; ++ni) pp += acc1[ni][r] * av[ni];
        pp += __shfl_xor(pp, 1, 64);
        pp += __shfl_xor(pp, 2, 64);
        pp += __shfl_xor(pp, 4, 64);
        pp += __shfl_xor(pp, 8, 64);
        int mrow = row0 + q * 4 + r;
        if (col == 0 && mrow < N) evec[mrow] = pp;
    }
    if (wed) {
        ped += __shfl_xor(ped, 16, 64);
        ped += __shfl_xor(ped, 32, 64);
        const int arow = row0 + col;
        if (q == 0 && arow < N) edv[arow] = ped;
    }
}

// ---------------- scatter body: inline 2D prefix, batch-8 ILP on the pcnt chain ----------------
__device__ void scatter_body(int tile, char* smem,
                             const int* __restrict__ pp_src, const int* __restrict__ pp_dst,
                             const int* __restrict__ pf_src, const int* __restrict__ pf_dst,
                             const int* __restrict__ pcnt, int* __restrict__ bbase_out,
                             int2* __restrict__ tmp) {
    int* base2 = (int*)smem;            // [NBKT]
    int* cur   = base2 + NBKT;          // [NBKT]
    int* wsum  = cur + NBKT;            // [4]
    const int tid = threadIdx.x, lane = tid & 63, wv = tid >> 6;
    int rowsum = 0, myprefix = 0;
    if (tid < NBKT) {
        const int* pb = pcnt + tid;
        int t = 0;
        for (; t + 8 <= NT_CNT; t += 8) {
            int c0 = pb[(t + 0) * NBKT], c1 = pb[(t + 1) * NBKT];
            int c2 = pb[(t + 2) * NBKT], c3 = pb[(t + 3) * NBKT];
            int c4 = pb[(t + 4) * NBKT], c5 = pb[(t + 5) * NBKT];
            int c6 = pb[(t + 6) * NBKT], c7 = pb[(t + 7) * NBKT];
            rowsum += c0 + c1 + c2 + c3 + c4 + c5 + c6 + c7;
            myprefix += ((t + 0 < tile) ? c0 : 0) + ((t + 1 < tile) ? c1 : 0)
                      + ((t + 2 < tile) ? c2 : 0) + ((t + 3 < tile) ? c3 : 0)
                      + ((t + 4 < tile) ? c4 : 0) + ((t + 5 < tile) ? c5 : 0)
                      + ((t + 6 < tile) ? c6 : 0) + ((t + 7 < tile) ? c7 : 0);
        }
        for (; t < NT_CNT; ++t) {
            int c = pb[t * NBKT];
            rowsum += c;
            if (t < tile) myprefix += c;
        }
    }
    // exclusive scan of rowsum over buckets -> bucket base
    int v = (tid < NBKT) ? rowsum : 0;
    int incl = v;
    #pragma unroll
    for (int off = 1; off < 64; off <<= 1) {
        int t = __shfl_up(incl, off, 64);
        if (lane >= off) incl += t;
    }
    if (lane == 63) wsum[wv] = incl;
    __syncthreads();
    if (tid == 0) {
        int run = 0;
        #pragma unroll
        for (int w = 0; w < 4; ++w) { int t = wsum[w]; wsum[w] = run; run += t; }
    }
    __syncthreads();
    int bexcl = wsum[wv] + incl - v;
    if (tid < NBKT) {
        base2[tid] = bexcl + myprefix;
        cur[tid] = 0;
        if (tile == 0) bbase_out[tid] = bexcl;
    }
    if (tile == 0 && tid == 0) bbase_out[NBKT] = E_UNI;
    __syncthreads();
    const int e0 = tile * EPB;
    #pragma unroll
    for (int u = 0; u < 16; ++u) {
        int e = e0 + u * 256 + tid;
        int d = -1, s = 0;
        if (e < E_PP)       { d = pp_dst[e];                 s = pp_src[e]; }
        else if (e < E_UNI) { d = N_PANO + pf_dst[e - E_PP]; s = pf_src[e - E_PP]; }
        if (d >= 0) {
            int b = d >> 8;
            int p = base2[b] + atomicAdd(&cur[b], 1);
            tmp[p] = make_int2(s, d);
        }
    }
}

// ---------------- merged launch: scatter (tiles 0..207) || layer-0 dual GEMM ----------------
__global__ __launch_bounds__(256, 4) void scatter_gemm0(
        const int* __restrict__ pp_src, const int* __restrict__ pp_dst,
        const int* __restrict__ pf_src, const int* __restrict__ pf_dst,
        const int* __restrict__ pcnt, int* __restrict__ bbase_out, int2* __restrict__ tmp,
        const float* __restrict__ x_pano,
        const ushort_t* __restrict__ s0, const ushort_t* __restrict__ l0,
        ushort_t* __restrict__ hsb, ushort_t* __restrict__ linb,
        const float* __restrict__ as0, float* __restrict__ es,
        const float* __restrict__ wed0, float* __restrict__ ed) {
    __shared__ __align__(16) char smem[(2 * NBKT + 4) * 4];
    if (blockIdx.x < NT_CNT)
        scatter_body(blockIdx.x, smem, pp_src, pp_dst, pf_src, pf_dst, pcnt, bbase_out, tmp);
    else
        gemm_body<128, true, true>(blockIdx.x - NT_CNT, x_pano, nullptr, s0, l0,
                                   hsb, linb, as0, es, wed0, ed, N_PANO);
}

// ---------------- standalone GEMM kernel (layers 1 and translate), barrier-free ----------------
template <int CN, bool DUAL, bool FP32IN>
__global__ __launch_bounds__(256, 4) void gemm_mfma(const float* __restrict__ Xf,
                                                 const ushort_t* __restrict__ Xh,
                                                 const ushort_t* __restrict__ W1, const ushort_t* __restrict__ W2,
                                                 ushort_t* __restrict__ Y1, ushort_t* __restrict__ Y2,
                                                 const float* __restrict__ avec, float* __restrict__ evec,
                                                 const float* __restrict__ wed, float* __restrict__ edv,
                                                 int N) {
    gemm_body<CN, DUAL, FP32IN>(blockIdx.x, Xf, Xh, W1, W2, Y1, Y2, avec, evec, wed, edv, N);
}

// ---------------- CSR stage 4: per-bucket counting sort in LDS -> P, col ----------------
__global__ __launch_bounds__(1024, 1) void csr_sort(const int2* __restrict__ tmp,
                                                    const int* __restrict__ bbase,
                                                    int* __restrict__ ptr, int* __restrict__ col) {
    __shared__ int hist[256];
    __shared__ int wsum[4];
    const int b = blockIdx.x, tid = threadIdx.x, lane = tid & 63, wv = tid >> 6;
    const int B0 = bbase[b], B1 = bbase[b + 1];
    if (tid < 256) hist[tid] = 0;
    __syncthreads();
    for (int e = B0 + tid; e < B1; e += 1024) atomicAdd(&hist[tmp[e].y & 255], 1);
    __syncthreads();
    int v = (tid < 256) ? hist[tid] : 0;
    int incl = v;
    #pragma unroll
    for (int off = 1; off < 64; off <<= 1) {
        int t = __shfl_up(incl, off, 64);
        if (lane >= off) incl += t;
    }
    if (lane == 63 && tid < 256) wsum[wv] = incl;
    __syncthreads();
    if (tid == 0) {
        int run = 0;
        #pragma unroll
        for (int w = 0; w < 4; ++w) { int t = wsum[w]; wsum[w] = run; run += t; }
    }
    __syncthreads();
    if (tid < 256) {
        int excl = wsum[wv] + incl - v;
        int dg = b * 256 + tid;
        if (dg < N_UNI) ptr[dg] = B0 + excl;
        hist[tid] = excl;
    }
    if (b == NBKT - 1 && tid == 0) ptr[N_UNI] = E_UNI;
    __syncthreads();
    for (int e = B0 + tid; e < B1; e += 1024) {
        int2 ed2 = tmp[e];
        int p = B0 + atomicAdd(&hist[ed2.y & 255], 1);
        col[p] = ed2.x;
    }
}

// ---------------- GAT aggregate (pano): 1 node/wave, 16 lanes/edge (uint4) ----------------
// R7's inner loop was 32 lanes/edge (uint2), 8 edges in flight per waitcnt group: a
// degree-16 node needed 2-3 serial L2 round-trips. 16 lanes/edge (uint4) puts 16 edges
// in flight per group -> one round-trip for the mean degree. Each lane owns 8 channels.
__global__ __launch_bounds__(256, 4) void agg_pano9(const int* __restrict__ ptr, const int* __restrict__ col,
                                                    const float* __restrict__ es, const float* __restrict__ ed,
                                                    const ushort_t* __restrict__ hsb, const ushort_t* __restrict__ linb,
                                                    const float* __restrict__ b, const float* __restrict__ Lb,
                                                    uint_t* __restrict__ hh, int N) {
    int lane = threadIdx.x & 63, wid = threadIdx.x >> 6;
    int node = blockIdx.x * 4 + wid;
    if (node >= N) return;
    int beg = ptr[node], end = ptr[node + 1];
    float edn = ed[node];
    const int quarter = lane >> 4, hl4 = lane & 15;
    float a0 = 0.f, a1 = 0.f, a2 = 0.f, a3 = 0.f;
    float a4 = 0.f, a5 = 0.f, a6 = 0.f, a7 = 0.f;
    float den = 0.f;
    for (int base = beg; base < end; base += 64) {
        int m = end - base; m = m > 64 ? 64 : m;
        int s = 0;
        float w = 0.f;
        if (lane < m) {
            s = col[base + lane];
            float e = es[s] + edn;
            e = fmaxf(e, 0.2f * e);
            w = __expf(e);
        }
        den += w;
        int mp = (m + 3) & ~3;
        int t = 0;
        for (; t + 16 <= mp; t += 16) {
            int i0 = t + quarter, i1 = t + 4 + quarter, i2 = t + 8 + quarter, i3 = t + 12 + quarter;
            int s0 = __shfl(s, i0, 64), s1 = __shfl(s, i1, 64);
            int s2 = __shfl(s, i2, 64), s3 = __shfl(s, i3, 64);
            float w0 = __shfl(w, i0, 64), w1 = __shfl(w, i1, 64);
            float w2 = __shfl(w, i2, 64), w3 = __shfl(w, i3, 64);
            uint4 h0 = *(const uint4*)&hsb[(size_t)s0 * 128 + hl4 * 8];
            uint4 h1 = *(const uint4*)&hsb[(size_t)s1 * 128 + hl4 * 8];
            uint4 h2 = *(const uint4*)&hsb[(size_t)s2 * 128 + hl4 * 8];
            uint4 h3 = *(const uint4*)&hsb[(size_t)s3 * 128 + hl4 * 8];
            a0 += w0 * bflo(h0.x) + w1 * bflo(h1.x) + w2 * bflo(h2.x) + w3 * bflo(h3.x);
            a1 += w0 * bfhi(h0.x) + w1 * bfhi(h1.x) + w2 * bfhi(h2.x) + w3 * bfhi(h3.x);
            a2 += w0 * bflo(h0.y) + w1 * bflo(h1.y) + w2 * bflo(h2.y) + w3 * bflo(h3.y);
            a3 += w0 * bfhi(h0.y) + w1 * bfhi(h1.y) + w2 * bfhi(h2.y) + w3 * bfhi(h3.y);
            a4 += w0 * bflo(h0.z) + w1 * bflo(h1.z) + w2 * bflo(h2.z) + w3 * bflo(h3.z);
            a5 += w0 * bfhi(h0.z) + w1 * bfhi(h1.z) + w2 * bfhi(h2.z) + w3 * bfhi(h3.z);
            a6 += w0 * bflo(h0.w) + w1 * bflo(h1.w) + w2 * bflo(h2.w) + w3 * bflo(h3.w);
            a7 += w0 * bfhi(h0.w) + w1 * bfhi(h1.w) + w2 * bfhi(h2.w) + w3 * bfhi(h3.w);
        }
        for (; t < mp; t += 4) {
            int i0 = t + quarter;
            int s0 = __shfl(s, i0, 64);
            float w0 = __shfl(w, i0, 64);
            uint4 h0 = *(const uint4*)&hsb[(size_t)s0 * 128 + hl4 * 8];
            a0 += w0 * bflo(h0.x); a1 += w0 * bfhi(h0.x);
            a2 += w0 * bflo(h0.y); a3 += w0 * bfhi(h0.y);
            a4 += w0 * bflo(h0.z); a5 += w0 * bfhi(h0.z);
            a6 += w0 * bflo(h0.w); a7 += w0 * bfhi(h0.w);
        }
    }
    // reduce across the 4 quarter-groups (lane bits 4,5)
    a0 += __shfl_xor(a0, 16, 64); a0 += __shfl_xor(a0, 32, 64);
    a1 += __shfl_xor(a1, 16, 64); a1 += __shfl_xor(a1, 32, 64);
    a2 += __shfl_xor(a2, 16, 64); a2 += __shfl_xor(a2, 32, 64);
    a3 += __shfl_xor(a3, 16, 64); a3 += __shfl_xor(a3, 32, 64);
    a4 += __shfl_xor(a4, 16, 64); a4 += __shfl_xor(a4, 32, 64);
    a5 += __shfl_xor(a5, 16, 64); a5 += __shfl_xor(a5, 32, 64);
    a6 += __shfl_xor(a6, 16, 64); a6 += __shfl_xor(a6, 32, 64);
    a7 += __shfl_xor(a7, 16, 64); a7 += __shfl_xor(a7, 32, 64);
    #pragma unroll
    for (int off = 1; off < 64; off <<= 1) den += __shfl_xor(den, off, 64);
    float inv = (end > beg) ? (1.f / den) : 0.f;
    if (quarter == 0) {
        // lane hl4 owns channels [hl4*8, hl4*8+8)
        uint4 lv = *(const uint4*)&linb[(size_t)node * 128 + hl4 * 8];
        float4 bb0 = *(const float4*)&b[hl4 * 8];
        float4 bb1 = *(const float4*)&b[hl4 * 8 + 4];
        float4 lb0 = *(const float4*)&Lb[hl4 * 8];
        float4 lb1 = *(const float4*)&Lb[hl4 * 8 + 4];
        float o0 = fmaxf(a0 * inv + bb0.x + bflo(lv.x) + lb0.x, 0.f);
        float o1 = fmaxf(a1 * inv + bb0.y + bfhi(lv.x) + lb0.y, 0.f);
        float o2 = fmaxf(a2 * inv + bb0.z + bflo(lv.y) + lb0.z, 0.f);
        float o3 = fmaxf(a3 * inv + bb0.w + bfhi(lv.y) + lb0.w, 0.f);
        float o4 = fmaxf(a4 * inv + bb1.x + bflo(lv.z) + lb1.x, 0.f);
        float o5 = fmaxf(a5 * inv + bb1.y + bfhi(lv.z) + lb1.y, 0.f);
        float o6 = fmaxf(a6 * inv + bb1.z + bflo(lv.w) + lb1.z, 0.f);
        float o7 = fmaxf(a7 * inv + bb1.w + bfhi(lv.w) + lb1.w, 0.f);
        uint4 ov;
        ov.x = (uint_t)f2bf(o0) | ((uint_t)f2bf(o1) << 16);
        ov.y = (uint_t)f2bf(o2) | ((uint_t)f2bf(o3) << 16);
        ov.z = (uint_t)f2bf(o4) | ((uint_t)f2bf(o5) << 16);
        ov.w = (uint_t)f2bf(o6) | ((uint_t)f2bf(o7) << 16);
        *(uint4*)&hh[(size_t)node * 64 + hl4 * 4] = ov;
    }
}

// ---------------- translate aggregate (C=64), fused ed matvec ----------------
__global__ __launch_bounds__(256, 4) void agg_fp5(const int* __restrict__ ptr, const int* __restrict__ col,
                                               const float* __restrict__ es, const float* __restrict__ x_fp,
                                               const float* __restrict__ wedt,
                                               const ushort_t* __restrict__ hsb, const float* __restrict__ bt,
                                               float* __restrict__ out, int N) {
    int lane = threadIdx.x & 63, wid = threadIdx.x >> 6;
    int node = blockIdx.x * 4 + wid;
    if (node >= N) return;
    int beg = ptr[node], end = ptr[node + 1];
    float edn = x_fp[(size_t)node * 64 + lane] * wedt[lane];
    #pragma unroll
    for (int off = 1; off < 64; off <<= 1) edn += __shfl_xor(edn, off, 64);
    float acc = 0.f, denp = 0.f;
    for (int base = beg; base < end; base += 64) {
        int m = min(64, end - base);
        int s = 0;
        float wgt = 0.f;
        if (lane < m) {
            s = col[base + lane];
            float e = es[s] + edn;
            e = fmaxf(e, 0.2f * e);
            wgt = __expf(e);
        }
        denp += wgt;
        int u = 0;
        for (; u + 4 <= m; u += 4) {
            int s0 = __shfl(s, u, 64), s1 = __shfl(s, u + 1, 64);
            int s2 = __shfl(s, u + 2, 64), s3 = __shfl(s, u + 3, 64);
            float w0 = __shfl(wgt, u, 64), w1 = __shfl(wgt, u + 1, 64);
            float w2 = __shfl(wgt, u + 2, 64), w3 = __shfl(wgt, u + 3, 64);
            float h0 = bfu2f(hsb[(size_t)s0 * 64 + lane]);
            float h1 = bfu2f(hsb[(size_t)s1 * 64 + lane]);
            float h2 = bfu2f(hsb[(size_t)s2 * 64 + lane]);
            float h3 = bfu2f(hsb[(size_t)s3 * 64 + lane]);
            acc += w0 * h0 + w1 * h1 + w2 * h2 + w3 * h3;
        }
        for (; u < m; ++u) {
            int su = __shfl(s, u, 64);
            float wu = __shfl(wgt, u, 64);
            acc += wu * bfu2f(hsb[(size_t)su * 64 + lane]);
        }
    }
    float den = denp;
    #pragma unroll
    for (int off = 1; off < 64; off <<= 1) den += __shfl_xor(den, off, 64);
    float inv = (end > beg) ? (1.f / den) : 0.f;
    out[(size_t)node * 64 + lane] = acc * inv + bt[lane];
}

extern "C" void kernel_launch(void* const* d_in, const int* in_sizes, int n_in,
                              void* d_out, int out_size, void* d_ws, size_t ws_size,
                              hipStream_t stream) {
    const float* x_pano = (const float*)d_in[0];
    const float* x_fp   = (const float*)d_in[1];
    const float* Ws0 = (const float*)d_in[2];
    const float* Wd0 = (const float*)d_in[3];
    const float* as0 = (const float*)d_in[4];
    const float* ad0 = (const float*)d_in[5];
    const float* b0  = (const float*)d_in[6];
    const float* Lw0 = (const float*)d_in[7];
    const float* Lb0 = (const float*)d_in[8];
    const float* Ws1 = (const float*)d_in[9];
    const float* Wd1 = (const float*)d_in[10];
    const float* as1 = (const float*)d_in[11];
    const float* ad1 = (const float*)d_in[12];
    const float* b1  = (const float*)d_in[13];
    const float* Lw1 = (const float*)d_in[14];
    const float* Lb1 = (const float*)d_in[15];
    const float* Wts = (const float*)d_in[16];
    const float* Wtd = (const float*)d_in[17];
    const float* ats = (const float*)d_in[18];
    const float* atd = (const float*)d_in[19];
    const float* bt  = (const float*)d_in[20];
    const int* pp_src = (const int*)d_in[21];
    const int* pp_dst = (const int*)d_in[21] + E_PP;
    const int* pf_src = (const int*)d_in[22];
    const int* pf_dst = (const int*)d_in[23];
    float* out = (float*)d_out;

    char* wsp = (char*)d_ws;
    size_t off = 0;
    auto alloc = [&](size_t bytes) -> char* {
        char* p = wsp + off;
        off += (bytes + 255) & ~(size_t)255;
        return p;
    };
    ushort_t* hsb  = (ushort_t*)alloc(sizeof(ushort_t) * N_PANO * HID);
    ushort_t* linb = (ushort_t*)alloc(sizeof(ushort_t) * N_PANO * HID);
    uint_t* hh     = (uint_t*)alloc(sizeof(uint_t) * N_PANO * 64);
    ushort_t* hstb = (ushort_t*)alloc(sizeof(ushort_t) * N_PANO * OUT_C);
    int2* tmp_e    = (int2*)alloc(sizeof(int2) * E_UNI);
    float* es   = (float*)alloc(sizeof(float) * N_PANO);
    float* ed   = (float*)alloc(sizeof(float) * N_PANO);
    float* wed0 = (float*)alloc(sizeof(float) * HID);
    float* wed1 = (float*)alloc(sizeof(float) * HID);
    float* wedt = (float*)alloc(sizeof(float) * OUT_C);
    ushort_t* s0 = (ushort_t*)alloc(sizeof(ushort_t) * 128 * 128);
    ushort_t* l0 = (ushort_t*)alloc(sizeof(ushort_t) * 128 * 128);
    ushort_t* s1 = (ushort_t*)alloc(sizeof(ushort_t) * 128 * 128);
    ushort_t* l1 = (ushort_t*)alloc(sizeof(ushort_t) * 128 * 128);
    ushort_t* ts = (ushort_t*)alloc(sizeof(ushort_t) * 64 * 128);
    int* pcnt  = (int*)alloc(sizeof(int) * NBKT * NT_CNT);
    int* bbase = (int*)alloc(sizeof(int) * (NBKT + 1));
    int* P     = (int*)alloc(sizeof(int) * (N_UNI + 1));
    int* col_u = (int*)alloc(sizeof(int) * E_UNI);

    // L1: per-tile bucket counts + weight fragment-permute + wed matvecs
    csr_count_prep<<<NT_CNT + 288 + 80, 256, 0, stream>>>(
        pp_dst, pf_dst, pcnt, Ws0, Lw0, Ws1, Lw1, Wts,
        Wd0, ad0, Wd1, ad1, Wtd, atd, s0, l0, s1, l1, ts, wed0, wed1, wedt);

    // L2: coarse scatter (inline 2D prefix) || layer-0 dual GEMM (64-row tiles)
    scatter_gemm0<<<NT_CNT + NT_GEMM, 256, 0, stream>>>(
        pp_src, pp_dst, pf_src, pf_dst, pcnt, bbase, tmp_e,
        x_pano, s0, l0, hsb, linb, as0, es, wed0, ed);

    // L3: per-bucket counting sort -> P, col (1024 threads: 4x resident waves)
    csr_sort<<<NBKT, 1024, 0, stream>>>(tmp_e, bbase, P, col_u);

    // L4: layer-0 aggregate (1 node/wave, 16-edges-in-flight gather)
    agg_pano9<<<cdiv(N_PANO, 4), 256, 0, stream>>>(P, col_u, es, ed, hsb, linb, b0, Lb0, hh, N_PANO);

    // L5: layer-1 dual GEMM (bf16 input = hh)
    gemm_mfma<128, true, false><<<NT_GEMM, 256, 0, stream>>>(
        nullptr, (const ushort_t*)hh, s1, l1, hsb, linb, as1, es, wed1, ed, N_PANO);

    // L6: layer-1 aggregate
    agg_pano9<<<cdiv(N_PANO, 4), 256, 0, stream>>>(P, col_u, es, ed, hsb, linb, b1, Lb1, hh, N_PANO);

    // L7: translate GEMM (C=64)
    gemm_mfma<64, false, false><<<NT_GEMM, 256, 0, stream>>>(
        nullptr, (const ushort_t*)hh, ts, nullptr, hstb, nullptr, ats, es, nullptr, nullptr, N_PANO);

    // L8: translate aggregate (pf ptr = P+50000, absolute into col_u)
    agg_fp5<<<cdiv(N_FP, 4), 256, 0, stream>>>(P + N_PANO, col_u, es, x_fp, wedt, hstb, bt, out, N_FP);
}